// Round 4
// baseline (1221.280 us; speedup 1.0000x reference)
//
#include <hip/hip_runtime.h>

#define B_    64
#define CIN_  3
#define HW_   64
#define HID_  128
#define K_    1024
#define H1_   31      // after conv1 (stride2 k4)
#define H2_   30      // after conv2 (stride1 k2)
#define NROWS_ 57600  // B_*H2_*H2_
#define NELEM_ 7372800

// ---------------- conv1: x[64,3,64,64] -> relu -> z1p[64,128,32,32] (padded)
__global__ __launch_bounds__(256) void conv1_k(const float* __restrict__ x,
    const float* __restrict__ w, const float* __restrict__ bias,
    float* __restrict__ z1p) {
  int blk = blockIdx.x, b = blk >> 7, co = blk & 127;     // grid = 64*128
  const float* wp = w + co * 48;                          // [co][ci][4][4]
  float wr[48];
  #pragma unroll
  for (int i = 0; i < 48; ++i) wr[i] = wp[i];             // uniform -> SGPRs
  const float* xb = x + (size_t)b * CIN_ * HW_ * HW_;
  float* zb = z1p + ((size_t)blk << 10);                  // 32x32 padded plane
  float bv = bias[co];
  for (int j = threadIdx.x; j < H1_ * H1_; j += 256) {
    int oh = j / H1_, ow = j % H1_;
    float acc = bv;
    #pragma unroll
    for (int ci = 0; ci < CIN_; ++ci) {
      const float* xp = xb + ci * HW_ * HW_ + (oh * 2) * HW_ + ow * 2;
      #pragma unroll
      for (int kh = 0; kh < 4; ++kh)
        #pragma unroll
        for (int kw = 0; kw < 4; ++kw)
          acc += xp[kh * HW_ + kw] * wr[ci * 16 + kh * 4 + kw];
    }
    zb[(oh << 5) + ow] = fmaxf(acc, 0.f);                 // pad never read
  }
}

// ---------------- conv2: z1p -> relu -> z[64,128,30,30] (compact) -----------
// block = (b, 32-co group, pos quarter); 1 pos/thread, acc[32].
// 4 blocks/CU (32KB LDS, ~90 VGPR); register-prefetch next ci-chunk.
__global__ __launch_bounds__(256, 4) void conv2_k(const float* __restrict__ z1p,
    const float* __restrict__ w, const float* __restrict__ bias,
    float* __restrict__ z) {
  __shared__ __align__(16) float qs[8 * 1024];            // 32 KB
  int blk = blockIdx.x;                                   // 64*4*4 = 1024
  int b = blk >> 4, cg = (blk >> 2) & 3, q = blk & 3;
  int co0 = cg * 32;
  int tid = threadIdx.x;
  int pos = q * 256 + tid;
  bool act = pos < 900;
  int bp = act ? (pos / 30) * 32 + (pos % 30) : 0;
  float acc[32];
  #pragma unroll
  for (int c = 0; c < 32; ++c) acc[c] = 0.f;
  const float4* src4 = (const float4*)(z1p + ((size_t)(b * HID_) << 10));
  const float4* w4 = (const float4*)w;                    // [co][ci] float4
  float4 pre[8];
  #pragma unroll
  for (int s = 0; s < 8; ++s) pre[s] = src4[s * 256 + tid];
  for (int ch = 0; ch < 16; ++ch) {
    __syncthreads();
    #pragma unroll
    for (int s = 0; s < 8; ++s) ((float4*)qs)[s * 256 + tid] = pre[s];
    __syncthreads();
    if (ch < 15) {
      #pragma unroll
      for (int s = 0; s < 8; ++s)
        pre[s] = src4[(ch + 1) * 2048 + s * 256 + tid];   // overlap w/ compute
    }
    #pragma unroll
    for (int cl = 0; cl < 8; ++cl) {
      const float* qq = &qs[cl * 1024 + bp];
      float t0 = qq[0], t1 = qq[1], t2 = qq[32], t3 = qq[33];
      #pragma unroll
      for (int c = 0; c < 32; ++c) {
        float4 wv = w4[(co0 + c) * HID_ + ch * 8 + cl];   // uniform s_load
        acc[c] = fmaf(t0, wv.x, fmaf(t1, wv.y, fmaf(t2, wv.z,
                 fmaf(t3, wv.w, acc[c]))));
      }
    }
  }
  if (act) {
    #pragma unroll
    for (int c = 0; c < 32; ++c)
      z[(size_t)(b * HID_ + co0 + c) * 900 + pos] =
          fmaxf(acc[c] + bias[co0 + c], 0.f);
  }
}

// ---------------- prep: codebook norms, zero hist/sse -----------------------
__global__ __launch_bounds__(256) void prep_k(const float* __restrict__ cb,
    float* __restrict__ cnorm, unsigned* __restrict__ hist,
    float* __restrict__ sse) {
  int k = blockIdx.x * 256 + threadIdx.x;
  if (k < K_) {
    float s0 = 0.f;
    #pragma unroll 4
    for (int d = 0; d < HID_; ++d) { float v = cb[k * HID_ + d]; s0 += v * v; }
    cnorm[k] = s0;
    hist[k] = 0u;
  }
  if (k == 0 && blockIdx.x == 0) *sse = 0.f;
}

__global__ __launch_bounds__(256) void zero_k(float4* __restrict__ p, int n4) {
  int i = blockIdx.x * 256 + threadIdx.x;
  if (i < n4) p[i] = make_float4(0.f, 0.f, 0.f, 0.f);
}

// ---------------- transpose: in[N][128] -> out[128][N], N % 64 == 0 ---------
__global__ __launch_bounds__(256) void tr_k(const float* __restrict__ in,
    float* __restrict__ out, int N) {
  __shared__ float t[64 * 133];
  int n0 = blockIdx.x * 64;
  int tid = threadIdx.x;
  const float4* in4 = (const float4*)in;
  #pragma unroll
  for (int s = 0; s < 8; ++s) {
    int flat = s * 256 + tid;          // 0..2047 float4s of the 64x128 tile
    int r = flat >> 5, c4 = flat & 31;
    float4 v = in4[n0 * 32 + flat];    // coalesced
    float* p = &t[r * 133 + c4 * 4];
    p[0] = v.x; p[1] = v.y; p[2] = v.z; p[3] = v.w;
  }
  __syncthreads();
  int w = tid >> 6, n_off = tid & 63;  // wave-uniform d, coalesced n
  #pragma unroll
  for (int s = 0; s < 32; ++s) {
    int d = s * 4 + w;
    out[d * N + n0 + n_off] = t[n_off * 133 + d];
  }
}

// ---------------- VQ phase 1: tiled GEMM-argmin over a 128-code chunk -------
__global__ __launch_bounds__(256, 2) void vq1_k(const float* __restrict__ zt,
    const float* __restrict__ cbt, const float* __restrict__ cnorm,
    unsigned long long* __restrict__ partial) {
  __shared__ __align__(16) float cbs[128 * 128];   // 64 KB -> 2 blocks/CU
  int chunk = blockIdx.x;          // 0..7
  int n0 = blockIdx.y * 128;
  int k0 = chunk * 128;
  int tid = threadIdx.x;
  {
    const float4* cbt4 = (const float4*)cbt;
    #pragma unroll
    for (int s = 0; s < 16; ++s) {
      int flat = s * 256 + tid;            // 0..4095
      int d = flat >> 5, c4 = flat & 31;
      float4 v = cbt4[d * 256 + (k0 >> 2) + c4];   // coalesced
      int pg = (c4 >> 1) ^ (d & 15);
      *(float4*)&cbs[d * 128 + pg * 8 + (c4 & 1) * 4] = v;
    }
  }
  __syncthreads();
  int rg = tid & 15, cg = tid >> 4;        // 16 row-groups x 16 code-groups
  float acc[8][8];
  #pragma unroll
  for (int i = 0; i < 8; ++i)
    #pragma unroll
    for (int j = 0; j < 8; ++j) acc[i][j] = 0.f;
  const float4* zt4 = (const float4*)zt;
  int zbase = (n0 >> 2) + rg * 2;
  #pragma unroll 2
  for (int d = 0; d < 128; ++d) {
    float4 a0 = zt4[d * 14400 + zbase];            // rows (global, coalesced)
    float4 a1 = zt4[d * 14400 + zbase + 1];
    const float4* cp = (const float4*)&cbs[d * 128 + (cg ^ (d & 15)) * 8];
    float4 b0 = cp[0], b1 = cp[1];                 // LDS broadcast, no conflict
    float r_[8] = {a0.x, a0.y, a0.z, a0.w, a1.x, a1.y, a1.z, a1.w};
    float c_[8] = {b0.x, b0.y, b0.z, b0.w, b1.x, b1.y, b1.z, b1.w};
    #pragma unroll
    for (int i = 0; i < 8; ++i)
      #pragma unroll
      for (int j = 0; j < 8; ++j)
        acc[i][j] += r_[i] * c_[j];
  }
  float cn[8];
  {
    const float4* cn4 = (const float4*)cnorm;
    float4 c0 = cn4[(k0 >> 2) + cg * 2];
    float4 c1 = cn4[(k0 >> 2) + cg * 2 + 1];
    cn[0] = c0.x; cn[1] = c0.y; cn[2] = c0.z; cn[3] = c0.w;
    cn[4] = c1.x; cn[5] = c1.y; cn[6] = c1.z; cn[7] = c1.w;
  }
  __syncthreads();                                  // cbs reads done; reuse LDS
  unsigned long long* red = (unsigned long long*)cbs;
  #pragma unroll
  for (int i = 0; i < 8; ++i) {
    unsigned long long best = ~0ull;
    #pragma unroll
    for (int j = 0; j < 8; ++j) {
      float dist = cn[j] - 2.f * acc[i][j];
      unsigned u = __float_as_uint(dist);
      u = (u & 0x80000000u) ? ~u : (u | 0x80000000u);  // monotone map
      unsigned long long p =
          ((unsigned long long)u << 32) | (unsigned)(k0 + cg * 8 + j);
      if (p < best) best = p;                       // tie -> smaller k
    }
    red[(rg * 8 + i) * 16 + cg] = best;
  }
  __syncthreads();
  if (tid < 128) {
    unsigned long long best = ~0ull;
    #pragma unroll
    for (int c = 0; c < 16; ++c) {
      unsigned long long p = red[tid * 16 + c];
      if (p < best) best = p;
    }
    partial[(size_t)(n0 + tid) * 8 + chunk] = best;
  }
}

// ---------------- VQ phase 2: reduce 8 chunk candidates per row -------------
__global__ __launch_bounds__(256) void vq2_k(
    const unsigned long long* __restrict__ partial, int* __restrict__ idxArr) {
  int n = blockIdx.x * 256 + threadIdx.x;           // 225 blocks
  unsigned long long best = ~0ull;
  #pragma unroll
  for (int c = 0; c < 8; ++c) {
    unsigned long long p = partial[(size_t)n * 8 + c];
    if (p < best) best = p;
  }
  idxArr[n] = (int)(best & 0xffffffffu);
}

// ---------------- VQ phase 3: scatter quantized (padded) + SSE + hist -------
__global__ __launch_bounds__(256) void vq3_k(const float* __restrict__ z,
    const float* __restrict__ cb, const int* __restrict__ idxArr,
    float* __restrict__ qp, unsigned* __restrict__ hist,
    float* __restrict__ sse) {
  int n = blockIdx.x * 256 + threadIdx.x;           // 225 blocks
  int bidx = idxArr[n];
  int f0 = n * 128;
  int b = f0 / 115200, rem = f0 % 115200;
  int c = rem / 900, s = rem % 900;
  const float4* z4 = (const float4*)z;
  const float4* cb4 = (const float4*)cb;
  float se = 0.f;
  for (int q4 = 0; q4 < 32; ++q4) {
    float4 zv = z4[n * 32 + q4];
    float4 cv = cb4[bidx * 32 + q4];
    float qe[4] = {cv.x, cv.y, cv.z, cv.w};
    float ze[4] = {zv.x, zv.y, zv.z, zv.w};
    #pragma unroll
    for (int e = 0; e < 4; ++e) {
      int h = s / 30, ww = s - h * 30;
      qp[(((size_t)(b * HID_ + c)) << 10) + ((h + 1) << 5) + (ww + 1)] = qe[e];
      float df = qe[e] - ze[e];
      se += df * df;
      if (++s == 900) { s = 0; ++c; }
    }
  }
  atomicAdd(&hist[bidx], 1u);
  __shared__ float red[256];
  red[threadIdx.x] = se;
  __syncthreads();
  #pragma unroll
  for (int t = 128; t > 0; t >>= 1) {
    if (threadIdx.x < t) red[threadIdx.x] += red[threadIdx.x + t];
    __syncthreads();
  }
  if (threadIdx.x == 0) atomicAdd(sse, red[0]);
}

// ---------------- convT1: qp[64,128,32,32] -> relu -> yp[64,128,33,33] ------
// same structure as conv2_k: 1 pos/thread, 32-co group, prefetch pipeline.
__global__ __launch_bounds__(256, 4) void convt1_k(const float* __restrict__ qp,
    const float* __restrict__ w, const float* __restrict__ bias,
    float* __restrict__ yp) {
  __shared__ __align__(16) float qs[8 * 1024];            // 32 KB
  int blk = blockIdx.x;                                   // 64*4*4 = 1024
  int b = blk >> 4, cg = (blk >> 2) & 3, q = blk & 3;
  int co0 = cg * 32;
  int tid = threadIdx.x;
  int pos = q * 256 + tid;
  bool act = pos < 961;
  int bp = act ? (pos / 31) * 32 + (pos % 31) : 0;
  float acc[32];
  #pragma unroll
  for (int c = 0; c < 32; ++c) acc[c] = 0.f;
  const float4* src4 = (const float4*)(qp + ((size_t)(b * HID_) << 10));
  const float4* w4 = (const float4*)w;                    // [ci][co] float4
  float4 pre[8];
  #pragma unroll
  for (int s = 0; s < 8; ++s) pre[s] = src4[s * 256 + tid];
  for (int ch = 0; ch < 16; ++ch) {
    __syncthreads();
    #pragma unroll
    for (int s = 0; s < 8; ++s) ((float4*)qs)[s * 256 + tid] = pre[s];
    __syncthreads();
    if (ch < 15) {
      #pragma unroll
      for (int s = 0; s < 8; ++s)
        pre[s] = src4[(ch + 1) * 2048 + s * 256 + tid];
    }
    #pragma unroll
    for (int cl = 0; cl < 8; ++cl) {
      const float* qq = &qs[cl * 1024 + bp];
      // taps: +33 (w00), +32 (w01), +1 (w10), +0 (w11)  [r2-verified]
      float t0 = qq[33], t1 = qq[32], t2 = qq[1], t3 = qq[0];
      #pragma unroll
      for (int c = 0; c < 32; ++c) {
        float4 wv = w4[(ch * 8 + cl) * HID_ + co0 + c];   // uniform s_load
        acc[c] = fmaf(t0, wv.x, fmaf(t1, wv.y, fmaf(t2, wv.z,
                 fmaf(t3, wv.w, acc[c]))));
      }
    }
  }
  if (act) {
    int oh = pos / 31, ow = pos % 31;
    int oidx = (oh + 1) * 33 + ow + 1;
    #pragma unroll
    for (int c = 0; c < 32; ++c)
      yp[(size_t)(b * HID_ + co0 + c) * 1089 + oidx] =
          fmaxf(acc[c] + bias[co0 + c], 0.f);
  }
}

// ---------------- convT2: yp[64,128,33,33] -> x_recon[64,3,64,64] -----------
// parity-uniform remap: (oh&1, ow&1) constant per block -> weight s_loads
__global__ __launch_bounds__(256) void convt2_k(const float* __restrict__ yp,
    const float* __restrict__ w, const float* __restrict__ bias,
    float* __restrict__ out) {
  int bc = blockIdx.x;                      // b*3 + co, 0..191
  int co = bc % 3, b = bc / 3;
  int yq = blockIdx.y;                      // 0..15
  int ph = (yq >> 1) & 1, pw = yq & 1, qg = yq >> 2;
  int i = qg * 256 + threadIdx.x;           // 0..1023 over 32x32 quadrant
  int qh = i >> 5, qw = i & 31;
  int oh = qh * 2 + ph, ow = qw * 2 + pw;
  int base = (qh + 1) * 33 + qw + 1;
  const float* yb = yp + (size_t)b * HID_ * 1089;
  const float* wp0 = w + co * 16 + ph * 4 + pw;   // + ci*48, block-uniform
  float acc = bias[co];
  for (int ci = 0; ci < HID_; ++ci) {
    const float* yr = yb + ci * 1089;
    const float* wp = wp0 + ci * 48;
    acc += yr[base]      * wp[0]
         + yr[base - 1]  * wp[2]
         + yr[base - 33] * wp[8]
         + yr[base - 34] * wp[10];
  }
  out[(size_t)bc * 4096 + oh * 64 + ow] = acc;
}

// ---------------- finalize: loss + perplexity -------------------------------
__global__ __launch_bounds__(256) void fin_k(const unsigned* __restrict__ hist,
    const float* __restrict__ sse, float* __restrict__ out) {
  __shared__ float red[256];
  float e = 0.f;
  for (int k = threadIdx.x; k < K_; k += 256) {
    float p = (float)hist[k] * (1.0f / (float)NROWS_);
    e += p * logf(p + 1e-10f);
  }
  red[threadIdx.x] = e;
  __syncthreads();
  #pragma unroll
  for (int t = 128; t > 0; t >>= 1) {
    if (threadIdx.x < t) red[threadIdx.x] += red[threadIdx.x + t];
    __syncthreads();
  }
  if (threadIdx.x == 0) {
    out[786432] = 1.25f * (*sse) * (1.0f / (float)NELEM_);
    out[786433] = expf(-red[0]);
  }
}

extern "C" void kernel_launch(void* const* d_in, const int* in_sizes, int n_in,
                              void* d_out, int out_size, void* d_ws,
                              size_t ws_size, hipStream_t stream) {
  (void)in_sizes; (void)n_in; (void)out_size; (void)ws_size;
  const float* x   = (const float*)d_in[0];
  const float* ew1 = (const float*)d_in[1];
  const float* eb1 = (const float*)d_in[2];
  const float* ew2 = (const float*)d_in[3];
  const float* eb2 = (const float*)d_in[4];
  const float* cb  = (const float*)d_in[5];
  const float* dw1 = (const float*)d_in[6];
  const float* db1 = (const float*)d_in[7];
  const float* dw2 = (const float*)d_in[8];
  const float* db2 = (const float*)d_in[9];
  float* out = (float*)d_out;
  char* ws = (char*)d_ws;

  // ws layout (~98.74 MB, aliased by liveness):
  //  [0, 35,684,352)  z1p padded (33.55 MB, dead after conv2)
  //                   -> partial(3.69MB)+idx(0.23MB) -> yp (35.68 MB)
  //  [35,684,352, 65,175,552)  z (29.49 MB, live through vq3)
  //  [65,175,552, 98,729,984)  zT (29.49MB)+cbT (0.5MB) (dead after vq1)
  //                            -> qp padded quantized (33.55 MB)
  //  [98,729,984 ..) hist 4KB | cnorm 4KB | sse
  float*    z1p     = (float*)(ws);
  unsigned long long* partial = (unsigned long long*)(ws);
  int*      idxArr  = (int*)(ws + 3686400);
  float*    yp      = (float*)(ws);
  float*    z       = (float*)(ws + 35684352);
  float*    zT      = (float*)(ws + 65175552);
  float*    cbT     = (float*)(ws + 65175552 + 29491200);
  float*    qp      = (float*)(ws + 65175552);
  unsigned* hist    = (unsigned*)(ws + 98729984);
  float*    cnorm   = (float*)(ws + 98729984 + 4096);
  float*    sse     = (float*)(ws + 98729984 + 8192);

  conv1_k<<<dim3(B_ * HID_), dim3(256), 0, stream>>>(x, ew1, eb1, z1p);
  conv2_k<<<dim3(B_ * 16), dim3(256), 0, stream>>>(z1p, ew2, eb2, z);
  prep_k<<<dim3(4), dim3(256), 0, stream>>>(cb, cnorm, hist, sse);
  tr_k<<<dim3(NROWS_ / 64), dim3(256), 0, stream>>>(z, zT, NROWS_);
  tr_k<<<dim3(K_ / 64), dim3(256), 0, stream>>>(cb, cbT, K_);
  vq1_k<<<dim3(8, 450), dim3(256), 0, stream>>>(zT, cbT, cnorm, partial);
  vq2_k<<<dim3(225), dim3(256), 0, stream>>>(partial, idxArr);
  zero_k<<<dim3(8192), dim3(256), 0, stream>>>((float4*)qp, 2097152);
  vq3_k<<<dim3(225), dim3(256), 0, stream>>>(z, cb, idxArr, qp, hist, sse);
  zero_k<<<dim3(8713), dim3(256), 0, stream>>>((float4*)yp, 2230272);
  convt1_k<<<dim3(B_ * 16), dim3(256), 0, stream>>>(qp, dw1, db1, yp);
  convt2_k<<<dim3(192, 16), dim3(256), 0, stream>>>(yp, dw2, db2, out);
  fin_k<<<dim3(1), dim3(256), 0, stream>>>(hist, sse, out);
}

// Round 5
// 1091.238 us; speedup vs baseline: 1.1192x; 1.1192x over previous
//
#include <hip/hip_runtime.h>

#define B_    64
#define CIN_  3
#define HW_   64
#define HID_  128
#define K_    1024
#define H1_   31      // after conv1 (stride2 k4)
#define H2_   30      // after conv2 (stride1 k2)
#define NROWS_ 57600  // B_*H2_*H2_
#define NELEM_ 7372800

// ---------------- conv1: x[64,3,64,64] -> relu -> z1p[64,128,32,32] (padded)
__global__ __launch_bounds__(256) void conv1_k(const float* __restrict__ x,
    const float* __restrict__ w, const float* __restrict__ bias,
    float* __restrict__ z1p) {
  int blk = blockIdx.x, b = blk >> 7, co = blk & 127;     // grid = 64*128
  const float* wp = w + co * 48;                          // [co][ci][4][4]
  float wr[48];
  #pragma unroll
  for (int i = 0; i < 48; ++i) wr[i] = wp[i];             // uniform -> SGPRs
  const float* xb = x + (size_t)b * CIN_ * HW_ * HW_;
  float* zb = z1p + ((size_t)blk << 10);                  // 32x32 padded plane
  float bv = bias[co];
  for (int j = threadIdx.x; j < H1_ * H1_; j += 256) {
    int oh = j / H1_, ow = j % H1_;
    float acc = bv;
    #pragma unroll
    for (int ci = 0; ci < CIN_; ++ci) {
      const float* xp = xb + ci * HW_ * HW_ + (oh * 2) * HW_ + ow * 2;
      #pragma unroll
      for (int kh = 0; kh < 4; ++kh)
        #pragma unroll
        for (int kw = 0; kw < 4; ++kw)
          acc += xp[kh * HW_ + kw] * wr[ci * 16 + kh * 4 + kw];
    }
    zb[(oh << 5) + ow] = fmaxf(acc, 0.f);                 // pad never read
  }
}

// ---------------- conv2: z1p -> relu -> z[64,128,30,30] (compact) -----------
// block = (b, 16-co group, half); 2 pos/thread, acc[16][2]=32 VGPR.
// 1024 blocks -> 4 blocks/CU; register-prefetch next ci-chunk across barrier.
// NOTE: (256,2) bounds on purpose — (256,4) caused a spill cascade to
// VGPR=52 + 551 MB scratch traffic in r4. Keep live arrays <= ~100 VGPR.
__global__ __launch_bounds__(256, 2) void conv2_k(const float* __restrict__ z1p,
    const float* __restrict__ w, const float* __restrict__ bias,
    float* __restrict__ z) {
  __shared__ __align__(16) float qs[8 * 1024];            // 32 KB
  int blk = blockIdx.x;                                   // 64*8*2 = 1024
  int b = blk >> 4, cg = (blk >> 1) & 7, q = blk & 1;
  int co0 = cg * 16;
  int tid = threadIdx.x;
  int p0 = q * 512 + tid;                                 // always < 900
  int p1 = p0 + 256;
  bool a1 = p1 < 900;
  int bp0 = (p0 / 30) * 32 + (p0 % 30);
  int bp1 = a1 ? (p1 / 30) * 32 + (p1 % 30) : 0;
  float acc[16][2];
  #pragma unroll
  for (int c = 0; c < 16; ++c) { acc[c][0] = 0.f; acc[c][1] = 0.f; }
  const float4* src4 = (const float4*)(z1p + ((size_t)(b * HID_) << 10));
  const float4* w4 = (const float4*)w;                    // [co][ci] float4
  float4 pre[8];
  #pragma unroll
  for (int s = 0; s < 8; ++s) pre[s] = src4[s * 256 + tid];
  for (int ch = 0; ch < 16; ++ch) {
    __syncthreads();
    #pragma unroll
    for (int s = 0; s < 8; ++s) ((float4*)qs)[s * 256 + tid] = pre[s];
    __syncthreads();
    if (ch < 15) {
      #pragma unroll
      for (int s = 0; s < 8; ++s)
        pre[s] = src4[(ch + 1) * 2048 + s * 256 + tid];   // overlap w/ compute
    }
    #pragma unroll
    for (int cl = 0; cl < 8; ++cl) {
      const float* q0 = &qs[cl * 1024 + bp0];
      const float* q1 = &qs[cl * 1024 + bp1];
      float t00 = q0[0], t01 = q0[1], t02 = q0[32], t03 = q0[33];
      float t10 = q1[0], t11 = q1[1], t12 = q1[32], t13 = q1[33];
      #pragma unroll
      for (int c = 0; c < 16; ++c) {
        float4 wv = w4[(co0 + c) * HID_ + ch * 8 + cl];   // uniform s_load
        acc[c][0] = fmaf(t00, wv.x, fmaf(t01, wv.y, fmaf(t02, wv.z,
                    fmaf(t03, wv.w, acc[c][0]))));
        acc[c][1] = fmaf(t10, wv.x, fmaf(t11, wv.y, fmaf(t12, wv.z,
                    fmaf(t13, wv.w, acc[c][1]))));
      }
    }
  }
  #pragma unroll
  for (int c = 0; c < 16; ++c) {
    float bv = bias[co0 + c];
    float* zo = z + (size_t)(b * HID_ + co0 + c) * 900;
    zo[p0] = fmaxf(acc[c][0] + bv, 0.f);
    if (a1) zo[p1] = fmaxf(acc[c][1] + bv, 0.f);
  }
}

// ---------------- prep: codebook norms, zero hist/sse -----------------------
__global__ __launch_bounds__(256) void prep_k(const float* __restrict__ cb,
    float* __restrict__ cnorm, unsigned* __restrict__ hist,
    float* __restrict__ sse) {
  int k = blockIdx.x * 256 + threadIdx.x;
  if (k < K_) {
    float s0 = 0.f;
    #pragma unroll 4
    for (int d = 0; d < HID_; ++d) { float v = cb[k * HID_ + d]; s0 += v * v; }
    cnorm[k] = s0;
    hist[k] = 0u;
  }
  if (k == 0 && blockIdx.x == 0) *sse = 0.f;
}

__global__ __launch_bounds__(256) void zero_k(float4* __restrict__ p, int n4) {
  int i = blockIdx.x * 256 + threadIdx.x;
  if (i < n4) p[i] = make_float4(0.f, 0.f, 0.f, 0.f);
}

// ---------------- transpose: in[N][128] -> out[128][N], N % 64 == 0 ---------
__global__ __launch_bounds__(256) void tr_k(const float* __restrict__ in,
    float* __restrict__ out, int N) {
  __shared__ float t[64 * 133];
  int n0 = blockIdx.x * 64;
  int tid = threadIdx.x;
  const float4* in4 = (const float4*)in;
  #pragma unroll
  for (int s = 0; s < 8; ++s) {
    int flat = s * 256 + tid;          // 0..2047 float4s of the 64x128 tile
    int r = flat >> 5, c4 = flat & 31;
    float4 v = in4[n0 * 32 + flat];    // coalesced
    float* p = &t[r * 133 + c4 * 4];
    p[0] = v.x; p[1] = v.y; p[2] = v.z; p[3] = v.w;
  }
  __syncthreads();
  int w = tid >> 6, n_off = tid & 63;  // wave-uniform d, coalesced n
  #pragma unroll
  for (int s = 0; s < 32; ++s) {
    int d = s * 4 + w;
    out[d * N + n0 + n_off] = t[n_off * 133 + d];
  }
}

// ---------------- VQ phase 1: tiled GEMM-argmin over a 128-code chunk -------
__global__ __launch_bounds__(256, 2) void vq1_k(const float* __restrict__ zt,
    const float* __restrict__ cbt, const float* __restrict__ cnorm,
    unsigned long long* __restrict__ partial) {
  __shared__ __align__(16) float cbs[128 * 128];   // 64 KB -> 2 blocks/CU
  int chunk = blockIdx.x;          // 0..7
  int n0 = blockIdx.y * 128;
  int k0 = chunk * 128;
  int tid = threadIdx.x;
  {
    const float4* cbt4 = (const float4*)cbt;
    #pragma unroll
    for (int s = 0; s < 16; ++s) {
      int flat = s * 256 + tid;            // 0..4095
      int d = flat >> 5, c4 = flat & 31;
      float4 v = cbt4[d * 256 + (k0 >> 2) + c4];   // coalesced
      int pg = (c4 >> 1) ^ (d & 15);
      *(float4*)&cbs[d * 128 + pg * 8 + (c4 & 1) * 4] = v;
    }
  }
  __syncthreads();
  int rg = tid & 15, cg = tid >> 4;        // 16 row-groups x 16 code-groups
  float acc[8][8];
  #pragma unroll
  for (int i = 0; i < 8; ++i)
    #pragma unroll
    for (int j = 0; j < 8; ++j) acc[i][j] = 0.f;
  const float4* zt4 = (const float4*)zt;
  int zbase = (n0 >> 2) + rg * 2;
  #pragma unroll 2
  for (int d = 0; d < 128; ++d) {
    float4 a0 = zt4[d * 14400 + zbase];            // rows (global, coalesced)
    float4 a1 = zt4[d * 14400 + zbase + 1];
    const float4* cp = (const float4*)&cbs[d * 128 + (cg ^ (d & 15)) * 8];
    float4 b0 = cp[0], b1 = cp[1];                 // LDS broadcast, no conflict
    float r_[8] = {a0.x, a0.y, a0.z, a0.w, a1.x, a1.y, a1.z, a1.w};
    float c_[8] = {b0.x, b0.y, b0.z, b0.w, b1.x, b1.y, b1.z, b1.w};
    #pragma unroll
    for (int i = 0; i < 8; ++i)
      #pragma unroll
      for (int j = 0; j < 8; ++j)
        acc[i][j] += r_[i] * c_[j];
  }
  float cn[8];
  {
    const float4* cn4 = (const float4*)cnorm;
    float4 c0 = cn4[(k0 >> 2) + cg * 2];
    float4 c1 = cn4[(k0 >> 2) + cg * 2 + 1];
    cn[0] = c0.x; cn[1] = c0.y; cn[2] = c0.z; cn[3] = c0.w;
    cn[4] = c1.x; cn[5] = c1.y; cn[6] = c1.z; cn[7] = c1.w;
  }
  __syncthreads();                                  // cbs reads done; reuse LDS
  unsigned long long* red = (unsigned long long*)cbs;
  #pragma unroll
  for (int i = 0; i < 8; ++i) {
    unsigned long long best = ~0ull;
    #pragma unroll
    for (int j = 0; j < 8; ++j) {
      float dist = cn[j] - 2.f * acc[i][j];
      unsigned u = __float_as_uint(dist);
      u = (u & 0x80000000u) ? ~u : (u | 0x80000000u);  // monotone map
      unsigned long long p =
          ((unsigned long long)u << 32) | (unsigned)(k0 + cg * 8 + j);
      if (p < best) best = p;                       // tie -> smaller k
    }
    red[(rg * 8 + i) * 16 + cg] = best;
  }
  __syncthreads();
  if (tid < 128) {
    unsigned long long best = ~0ull;
    #pragma unroll
    for (int c = 0; c < 16; ++c) {
      unsigned long long p = red[tid * 16 + c];
      if (p < best) best = p;
    }
    partial[(size_t)(n0 + tid) * 8 + chunk] = best;
  }
}

// ---------------- VQ phase 2: reduce 8 chunk candidates per row -------------
__global__ __launch_bounds__(256) void vq2_k(
    const unsigned long long* __restrict__ partial, int* __restrict__ idxArr) {
  int n = blockIdx.x * 256 + threadIdx.x;           // 225 blocks
  unsigned long long best = ~0ull;
  #pragma unroll
  for (int c = 0; c < 8; ++c) {
    unsigned long long p = partial[(size_t)n * 8 + c];
    if (p < best) best = p;
  }
  idxArr[n] = (int)(best & 0xffffffffu);
}

// ---------------- VQ phase 3: scatter quantized (padded) + SSE + hist -------
__global__ __launch_bounds__(256) void vq3_k(const float* __restrict__ z,
    const float* __restrict__ cb, const int* __restrict__ idxArr,
    float* __restrict__ qp, unsigned* __restrict__ hist,
    float* __restrict__ sse) {
  int n = blockIdx.x * 256 + threadIdx.x;           // 225 blocks
  int bidx = idxArr[n];
  int f0 = n * 128;
  int b = f0 / 115200, rem = f0 % 115200;
  int c = rem / 900, s = rem % 900;
  const float4* z4 = (const float4*)z;
  const float4* cb4 = (const float4*)cb;
  float se = 0.f;
  for (int q4 = 0; q4 < 32; ++q4) {
    float4 zv = z4[n * 32 + q4];
    float4 cv = cb4[bidx * 32 + q4];
    float qe[4] = {cv.x, cv.y, cv.z, cv.w};
    float ze[4] = {zv.x, zv.y, zv.z, zv.w};
    #pragma unroll
    for (int e = 0; e < 4; ++e) {
      int h = s / 30, ww = s - h * 30;
      qp[(((size_t)(b * HID_ + c)) << 10) + ((h + 1) << 5) + (ww + 1)] = qe[e];
      float df = qe[e] - ze[e];
      se += df * df;
      if (++s == 900) { s = 0; ++c; }
    }
  }
  atomicAdd(&hist[bidx], 1u);
  __shared__ float red[256];
  red[threadIdx.x] = se;
  __syncthreads();
  #pragma unroll
  for (int t = 128; t > 0; t >>= 1) {
    if (threadIdx.x < t) red[threadIdx.x] += red[threadIdx.x + t];
    __syncthreads();
  }
  if (threadIdx.x == 0) atomicAdd(sse, red[0]);
}

// ---------------- convT1: qp[64,128,32,32] -> relu -> yp[64,128,33,33] ------
// same structure as conv2_k r5: 2 pos/thread, 16-co group, prefetch pipeline.
__global__ __launch_bounds__(256, 2) void convt1_k(const float* __restrict__ qp,
    const float* __restrict__ w, const float* __restrict__ bias,
    float* __restrict__ yp) {
  __shared__ __align__(16) float qs[8 * 1024];            // 32 KB
  int blk = blockIdx.x;                                   // 64*8*2 = 1024
  int b = blk >> 4, cg = (blk >> 1) & 7, q = blk & 1;
  int co0 = cg * 16;
  int tid = threadIdx.x;
  int p0 = q * 512 + tid;                                 // always < 961
  int p1 = p0 + 256;
  bool a1 = p1 < 961;
  int bp0 = (p0 / 31) * 32 + (p0 % 31);
  int bp1 = a1 ? (p1 / 31) * 32 + (p1 % 31) : 0;
  float acc[16][2];
  #pragma unroll
  for (int c = 0; c < 16; ++c) { acc[c][0] = 0.f; acc[c][1] = 0.f; }
  const float4* src4 = (const float4*)(qp + ((size_t)(b * HID_) << 10));
  const float4* w4 = (const float4*)w;                    // [ci][co] float4
  float4 pre[8];
  #pragma unroll
  for (int s = 0; s < 8; ++s) pre[s] = src4[s * 256 + tid];
  for (int ch = 0; ch < 16; ++ch) {
    __syncthreads();
    #pragma unroll
    for (int s = 0; s < 8; ++s) ((float4*)qs)[s * 256 + tid] = pre[s];
    __syncthreads();
    if (ch < 15) {
      #pragma unroll
      for (int s = 0; s < 8; ++s)
        pre[s] = src4[(ch + 1) * 2048 + s * 256 + tid];
    }
    #pragma unroll
    for (int cl = 0; cl < 8; ++cl) {
      const float* q0 = &qs[cl * 1024 + bp0];
      const float* q1 = &qs[cl * 1024 + bp1];
      // taps: +33 (w00), +32 (w01), +1 (w10), +0 (w11)  [r2-verified]
      float t00 = q0[33], t01 = q0[32], t02 = q0[1], t03 = q0[0];
      float t10 = q1[33], t11 = q1[32], t12 = q1[1], t13 = q1[0];
      #pragma unroll
      for (int c = 0; c < 16; ++c) {
        float4 wv = w4[(ch * 8 + cl) * HID_ + co0 + c];   // uniform s_load
        acc[c][0] = fmaf(t00, wv.x, fmaf(t01, wv.y, fmaf(t02, wv.z,
                    fmaf(t03, wv.w, acc[c][0]))));
        acc[c][1] = fmaf(t10, wv.x, fmaf(t11, wv.y, fmaf(t12, wv.z,
                    fmaf(t13, wv.w, acc[c][1]))));
      }
    }
  }
  int oh0 = p0 / 31, ow0 = p0 % 31;
  int oi0 = (oh0 + 1) * 33 + ow0 + 1;
  int oh1 = a1 ? p1 / 31 : 0, ow1 = a1 ? p1 % 31 : 0;
  int oi1 = (oh1 + 1) * 33 + ow1 + 1;
  #pragma unroll
  for (int c = 0; c < 16; ++c) {
    float bv = bias[co0 + c];
    float* yb = yp + (size_t)(b * HID_ + co0 + c) * 1089;
    yb[oi0] = fmaxf(acc[c][0] + bv, 0.f);
    if (a1) yb[oi1] = fmaxf(acc[c][1] + bv, 0.f);
  }
}

// ---------------- convT2: yp[64,128,33,33] -> x_recon[64,3,64,64] -----------
// parity-uniform remap: (oh&1, ow&1) constant per block -> weight s_loads
__global__ __launch_bounds__(256) void convt2_k(const float* __restrict__ yp,
    const float* __restrict__ w, const float* __restrict__ bias,
    float* __restrict__ out) {
  int bc = blockIdx.x;                      // b*3 + co, 0..191
  int co = bc % 3, b = bc / 3;
  int yq = blockIdx.y;                      // 0..15
  int ph = (yq >> 1) & 1, pw = yq & 1, qg = yq >> 2;
  int i = qg * 256 + threadIdx.x;           // 0..1023 over 32x32 quadrant
  int qh = i >> 5, qw = i & 31;
  int oh = qh * 2 + ph, ow = qw * 2 + pw;
  int base = (qh + 1) * 33 + qw + 1;
  const float* yb = yp + (size_t)b * HID_ * 1089;
  const float* wp0 = w + co * 16 + ph * 4 + pw;   // + ci*48, block-uniform
  float acc = bias[co];
  for (int ci = 0; ci < HID_; ++ci) {
    const float* yr = yb + ci * 1089;
    const float* wp = wp0 + ci * 48;
    acc += yr[base]      * wp[0]
         + yr[base - 1]  * wp[2]
         + yr[base - 33] * wp[8]
         + yr[base - 34] * wp[10];
  }
  out[(size_t)bc * 4096 + oh * 64 + ow] = acc;
}

// ---------------- finalize: loss + perplexity -------------------------------
__global__ __launch_bounds__(256) void fin_k(const unsigned* __restrict__ hist,
    const float* __restrict__ sse, float* __restrict__ out) {
  __shared__ float red[256];
  float e = 0.f;
  for (int k = threadIdx.x; k < K_; k += 256) {
    float p = (float)hist[k] * (1.0f / (float)NROWS_);
    e += p * logf(p + 1e-10f);
  }
  red[threadIdx.x] = e;
  __syncthreads();
  #pragma unroll
  for (int t = 128; t > 0; t >>= 1) {
    if (threadIdx.x < t) red[threadIdx.x] += red[threadIdx.x + t];
    __syncthreads();
  }
  if (threadIdx.x == 0) {
    out[786432] = 1.25f * (*sse) * (1.0f / (float)NELEM_);
    out[786433] = expf(-red[0]);
  }
}

extern "C" void kernel_launch(void* const* d_in, const int* in_sizes, int n_in,
                              void* d_out, int out_size, void* d_ws,
                              size_t ws_size, hipStream_t stream) {
  (void)in_sizes; (void)n_in; (void)out_size; (void)ws_size;
  const float* x   = (const float*)d_in[0];
  const float* ew1 = (const float*)d_in[1];
  const float* eb1 = (const float*)d_in[2];
  const float* ew2 = (const float*)d_in[3];
  const float* eb2 = (const float*)d_in[4];
  const float* cb  = (const float*)d_in[5];
  const float* dw1 = (const float*)d_in[6];
  const float* db1 = (const float*)d_in[7];
  const float* dw2 = (const float*)d_in[8];
  const float* db2 = (const float*)d_in[9];
  float* out = (float*)d_out;
  char* ws = (char*)d_ws;

  // ws layout (~98.74 MB, aliased by liveness):
  //  [0, 35,684,352)  z1p padded (33.55 MB, dead after conv2)
  //                   -> partial(3.69MB)+idx(0.23MB) -> yp (35.68 MB)
  //  [35,684,352, 65,175,552)  z (29.49 MB, live through vq3)
  //  [65,175,552, 98,729,984)  zT (29.49MB)+cbT (0.5MB) (dead after vq1)
  //                            -> qp padded quantized (33.55 MB)
  //  [98,729,984 ..) hist 4KB | cnorm 4KB | sse
  float*    z1p     = (float*)(ws);
  unsigned long long* partial = (unsigned long long*)(ws);
  int*      idxArr  = (int*)(ws + 3686400);
  float*    yp      = (float*)(ws);
  float*    z       = (float*)(ws + 35684352);
  float*    zT      = (float*)(ws + 65175552);
  float*    cbT     = (float*)(ws + 65175552 + 29491200);
  float*    qp      = (float*)(ws + 65175552);
  unsigned* hist    = (unsigned*)(ws + 98729984);
  float*    cnorm   = (float*)(ws + 98729984 + 4096);
  float*    sse     = (float*)(ws + 98729984 + 8192);

  conv1_k<<<dim3(B_ * HID_), dim3(256), 0, stream>>>(x, ew1, eb1, z1p);
  conv2_k<<<dim3(B_ * 16), dim3(256), 0, stream>>>(z1p, ew2, eb2, z);
  prep_k<<<dim3(4), dim3(256), 0, stream>>>(cb, cnorm, hist, sse);
  tr_k<<<dim3(NROWS_ / 64), dim3(256), 0, stream>>>(z, zT, NROWS_);
  tr_k<<<dim3(K_ / 64), dim3(256), 0, stream>>>(cb, cbT, K_);
  vq1_k<<<dim3(8, 450), dim3(256), 0, stream>>>(zT, cbT, cnorm, partial);
  vq2_k<<<dim3(225), dim3(256), 0, stream>>>(partial, idxArr);
  zero_k<<<dim3(8192), dim3(256), 0, stream>>>((float4*)qp, 2097152);
  vq3_k<<<dim3(225), dim3(256), 0, stream>>>(z, cb, idxArr, qp, hist, sse);
  zero_k<<<dim3(8713), dim3(256), 0, stream>>>((float4*)yp, 2230272);
  convt1_k<<<dim3(B_ * 16), dim3(256), 0, stream>>>(qp, dw1, db1, yp);
  convt2_k<<<dim3(192, 16), dim3(256), 0, stream>>>(yp, dw2, db2, out);
  fin_k<<<dim3(1), dim3(256), 0, stream>>>(hist, sse, out);
}

// Round 6
// 790.280 us; speedup vs baseline: 1.5454x; 1.3808x over previous
//
#include <hip/hip_runtime.h>

#define B_    64
#define CIN_  3
#define HW_   64
#define HID_  128
#define K_    1024
#define H1_   31      // after conv1 (stride2 k4)
#define H2_   30      // after conv2 (stride1 k2)
#define NROWS_ 57600  // B_*H2_*H2_
#define NELEM_ 7372800

// ---------------- conv1: x[64,3,64,64] -> relu -> z1p[64,128,32,32] (padded)
__global__ __launch_bounds__(256) void conv1_k(const float* __restrict__ x,
    const float* __restrict__ w, const float* __restrict__ bias,
    float* __restrict__ z1p) {
  int blk = blockIdx.x, b = blk >> 7, co = blk & 127;     // grid = 64*128
  const float* wp = w + co * 48;                          // [co][ci][4][4]
  float wr[48];
  #pragma unroll
  for (int i = 0; i < 48; ++i) wr[i] = wp[i];             // uniform -> SGPRs
  const float* xb = x + (size_t)b * CIN_ * HW_ * HW_;
  float* zb = z1p + ((size_t)blk << 10);                  // 32x32 padded plane
  float bv = bias[co];
  for (int j = threadIdx.x; j < H1_ * H1_; j += 256) {
    int oh = j / H1_, ow = j % H1_;
    float acc = bv;
    #pragma unroll
    for (int ci = 0; ci < CIN_; ++ci) {
      const float* xp = xb + ci * HW_ * HW_ + (oh * 2) * HW_ + ow * 2;
      #pragma unroll
      for (int kh = 0; kh < 4; ++kh)
        #pragma unroll
        for (int kw = 0; kw < 4; ++kw)
          acc += xp[kh * HW_ + kw] * wr[ci * 16 + kh * 4 + kw];
    }
    zb[(oh << 5) + ow] = fmaxf(acc, 0.f);                 // pad never read
  }
}

// ---------------- conv2: z1p -> relu -> z[64,128,30,30] (compact) -----------
// block = (b, 8-co group); thread = 2x2 output tile (225 active of 256).
// 1024 blocks -> 4 blocks/CU. NO register prefetch across the barrier:
// r4/r5 showed pre[8] live across __syncthreads + acc[32] => allocator
// spills acc to scratch (VGPR=52, 550 MB scratch traffic). Direct staging
// (r3 pattern) compiles clean (VGPR~128, zero scratch).
__global__ __launch_bounds__(256, 2) void conv2_k(const float* __restrict__ z1p,
    const float* __restrict__ w, const float* __restrict__ bias,
    float* __restrict__ z) {
  __shared__ __align__(16) float qs[8 * 1024];            // 32 KB
  int b = blockIdx.x >> 4, co0 = (blockIdx.x & 15) * 8;   // grid = 64*16
  int tid = threadIdx.x;
  bool act = tid < 225;                                   // 15x15 2x2-tiles
  int th = act ? tid / 15 : 0, tw = act ? tid % 15 : 0;
  int base = th * 64 + tw * 2;                            // (2th)*32 + 2tw
  float acc[8][4];
  #pragma unroll
  for (int c = 0; c < 8; ++c)
    #pragma unroll
    for (int p = 0; p < 4; ++p) acc[c][p] = 0.f;
  const float4* src4 = (const float4*)(z1p + ((size_t)(b * HID_) << 10));
  const float4* w4 = (const float4*)w;                    // [co][ci] float4
  for (int ch = 0; ch < 16; ++ch) {
    __syncthreads();
    #pragma unroll
    for (int s = 0; s < 8; ++s)
      ((float4*)qs)[s * 256 + tid] = src4[ch * 2048 + s * 256 + tid];
    __syncthreads();
    #pragma unroll
    for (int cl = 0; cl < 8; ++cl) {
      const float* qq = &qs[cl * 1024 + base];
      float t00 = qq[0],  t01 = qq[1],  t02 = qq[2];
      float t10 = qq[32], t11 = qq[33], t12 = qq[34];
      float t20 = qq[64], t21 = qq[65], t22 = qq[66];
      int ci = ch * 8 + cl;
      #pragma unroll
      for (int c = 0; c < 8; ++c) {
        float4 wv = w4[(co0 + c) * HID_ + ci];            // uniform s_load
        acc[c][0] = fmaf(t00, wv.x, fmaf(t01, wv.y, fmaf(t10, wv.z,
                    fmaf(t11, wv.w, acc[c][0]))));
        acc[c][1] = fmaf(t01, wv.x, fmaf(t02, wv.y, fmaf(t11, wv.z,
                    fmaf(t12, wv.w, acc[c][1]))));
        acc[c][2] = fmaf(t10, wv.x, fmaf(t11, wv.y, fmaf(t20, wv.z,
                    fmaf(t21, wv.w, acc[c][2]))));
        acc[c][3] = fmaf(t11, wv.x, fmaf(t12, wv.y, fmaf(t21, wv.z,
                    fmaf(t22, wv.w, acc[c][3]))));
      }
    }
  }
  if (act) {
    int oh = th * 2, ow = tw * 2;
    #pragma unroll
    for (int c = 0; c < 8; ++c) {
      float bv = bias[co0 + c];
      float* zo = z + (size_t)(b * HID_ + co0 + c) * 900;
      zo[oh * 30 + ow]           = fmaxf(acc[c][0] + bv, 0.f);
      zo[oh * 30 + ow + 1]       = fmaxf(acc[c][1] + bv, 0.f);
      zo[(oh + 1) * 30 + ow]     = fmaxf(acc[c][2] + bv, 0.f);
      zo[(oh + 1) * 30 + ow + 1] = fmaxf(acc[c][3] + bv, 0.f);
    }
  }
}

// ---------------- prep: codebook norms, zero hist/sse -----------------------
__global__ __launch_bounds__(256) void prep_k(const float* __restrict__ cb,
    float* __restrict__ cnorm, unsigned* __restrict__ hist,
    float* __restrict__ sse) {
  int k = blockIdx.x * 256 + threadIdx.x;
  if (k < K_) {
    float s0 = 0.f;
    #pragma unroll 4
    for (int d = 0; d < HID_; ++d) { float v = cb[k * HID_ + d]; s0 += v * v; }
    cnorm[k] = s0;
    hist[k] = 0u;
  }
  if (k == 0 && blockIdx.x == 0) *sse = 0.f;
}

__global__ __launch_bounds__(256) void zero_k(float4* __restrict__ p, int n4) {
  int i = blockIdx.x * 256 + threadIdx.x;
  if (i < n4) p[i] = make_float4(0.f, 0.f, 0.f, 0.f);
}

// ---------------- transpose: in[N][128] -> out[128][N], N % 64 == 0 ---------
__global__ __launch_bounds__(256) void tr_k(const float* __restrict__ in,
    float* __restrict__ out, int N) {
  __shared__ float t[64 * 133];
  int n0 = blockIdx.x * 64;
  int tid = threadIdx.x;
  const float4* in4 = (const float4*)in;
  #pragma unroll
  for (int s = 0; s < 8; ++s) {
    int flat = s * 256 + tid;          // 0..2047 float4s of the 64x128 tile
    int r = flat >> 5, c4 = flat & 31;
    float4 v = in4[n0 * 32 + flat];    // coalesced
    float* p = &t[r * 133 + c4 * 4];
    p[0] = v.x; p[1] = v.y; p[2] = v.z; p[3] = v.w;
  }
  __syncthreads();
  int w = tid >> 6, n_off = tid & 63;  // wave-uniform d, coalesced n
  #pragma unroll
  for (int s = 0; s < 32; ++s) {
    int d = s * 4 + w;
    out[d * N + n0 + n_off] = t[n_off * 133 + d];
  }
}

// ---------------- VQ phase 1: tiled GEMM-argmin over a 128-code chunk -------
__global__ __launch_bounds__(256, 2) void vq1_k(const float* __restrict__ zt,
    const float* __restrict__ cbt, const float* __restrict__ cnorm,
    unsigned long long* __restrict__ partial) {
  __shared__ __align__(16) float cbs[128 * 128];   // 64 KB -> 2 blocks/CU
  int chunk = blockIdx.x;          // 0..7
  int n0 = blockIdx.y * 128;
  int k0 = chunk * 128;
  int tid = threadIdx.x;
  {
    const float4* cbt4 = (const float4*)cbt;
    #pragma unroll
    for (int s = 0; s < 16; ++s) {
      int flat = s * 256 + tid;            // 0..4095
      int d = flat >> 5, c4 = flat & 31;
      float4 v = cbt4[d * 256 + (k0 >> 2) + c4];   // coalesced
      int pg = (c4 >> 1) ^ (d & 15);
      *(float4*)&cbs[d * 128 + pg * 8 + (c4 & 1) * 4] = v;
    }
  }
  __syncthreads();
  int rg = tid & 15, cg = tid >> 4;        // 16 row-groups x 16 code-groups
  float acc[8][8];
  #pragma unroll
  for (int i = 0; i < 8; ++i)
    #pragma unroll
    for (int j = 0; j < 8; ++j) acc[i][j] = 0.f;
  const float4* zt4 = (const float4*)zt;
  int zbase = (n0 >> 2) + rg * 2;
  #pragma unroll 2
  for (int d = 0; d < 128; ++d) {
    float4 a0 = zt4[d * 14400 + zbase];            // rows (global, coalesced)
    float4 a1 = zt4[d * 14400 + zbase + 1];
    const float4* cp = (const float4*)&cbs[d * 128 + (cg ^ (d & 15)) * 8];
    float4 b0 = cp[0], b1 = cp[1];                 // LDS broadcast, no conflict
    float r_[8] = {a0.x, a0.y, a0.z, a0.w, a1.x, a1.y, a1.z, a1.w};
    float c_[8] = {b0.x, b0.y, b0.z, b0.w, b1.x, b1.y, b1.z, b1.w};
    #pragma unroll
    for (int i = 0; i < 8; ++i)
      #pragma unroll
      for (int j = 0; j < 8; ++j)
        acc[i][j] += r_[i] * c_[j];
  }
  float cn[8];
  {
    const float4* cn4 = (const float4*)cnorm;
    float4 c0 = cn4[(k0 >> 2) + cg * 2];
    float4 c1 = cn4[(k0 >> 2) + cg * 2 + 1];
    cn[0] = c0.x; cn[1] = c0.y; cn[2] = c0.z; cn[3] = c0.w;
    cn[4] = c1.x; cn[5] = c1.y; cn[6] = c1.z; cn[7] = c1.w;
  }
  __syncthreads();                                  // cbs reads done; reuse LDS
  unsigned long long* red = (unsigned long long*)cbs;
  #pragma unroll
  for (int i = 0; i < 8; ++i) {
    unsigned long long best = ~0ull;
    #pragma unroll
    for (int j = 0; j < 8; ++j) {
      float dist = cn[j] - 2.f * acc[i][j];
      unsigned u = __float_as_uint(dist);
      u = (u & 0x80000000u) ? ~u : (u | 0x80000000u);  // monotone map
      unsigned long long p =
          ((unsigned long long)u << 32) | (unsigned)(k0 + cg * 8 + j);
      if (p < best) best = p;                       // tie -> smaller k
    }
    red[(rg * 8 + i) * 16 + cg] = best;
  }
  __syncthreads();
  if (tid < 128) {
    unsigned long long best = ~0ull;
    #pragma unroll
    for (int c = 0; c < 16; ++c) {
      unsigned long long p = red[tid * 16 + c];
      if (p < best) best = p;
    }
    partial[(size_t)(n0 + tid) * 8 + chunk] = best;
  }
}

// ---------------- VQ phase 2: reduce 8 chunk candidates per row -------------
__global__ __launch_bounds__(256) void vq2_k(
    const unsigned long long* __restrict__ partial, int* __restrict__ idxArr) {
  int n = blockIdx.x * 256 + threadIdx.x;           // 225 blocks
  unsigned long long best = ~0ull;
  #pragma unroll
  for (int c = 0; c < 8; ++c) {
    unsigned long long p = partial[(size_t)n * 8 + c];
    if (p < best) best = p;
  }
  idxArr[n] = (int)(best & 0xffffffffu);
}

// ---------------- VQ phase 3: scatter quantized (padded) + SSE + hist -------
__global__ __launch_bounds__(256) void vq3_k(const float* __restrict__ z,
    const float* __restrict__ cb, const int* __restrict__ idxArr,
    float* __restrict__ qp, unsigned* __restrict__ hist,
    float* __restrict__ sse) {
  int n = blockIdx.x * 256 + threadIdx.x;           // 225 blocks
  int bidx = idxArr[n];
  int f0 = n * 128;
  int b = f0 / 115200, rem = f0 % 115200;
  int c = rem / 900, s = rem % 900;
  const float4* z4 = (const float4*)z;
  const float4* cb4 = (const float4*)cb;
  float se = 0.f;
  for (int q4 = 0; q4 < 32; ++q4) {
    float4 zv = z4[n * 32 + q4];
    float4 cv = cb4[bidx * 32 + q4];
    float qe[4] = {cv.x, cv.y, cv.z, cv.w};
    float ze[4] = {zv.x, zv.y, zv.z, zv.w};
    #pragma unroll
    for (int e = 0; e < 4; ++e) {
      int h = s / 30, ww = s - h * 30;
      qp[(((size_t)(b * HID_ + c)) << 10) + ((h + 1) << 5) + (ww + 1)] = qe[e];
      float df = qe[e] - ze[e];
      se += df * df;
      if (++s == 900) { s = 0; ++c; }
    }
  }
  atomicAdd(&hist[bidx], 1u);
  __shared__ float red[256];
  red[threadIdx.x] = se;
  __syncthreads();
  #pragma unroll
  for (int t = 128; t > 0; t >>= 1) {
    if (threadIdx.x < t) red[threadIdx.x] += red[threadIdx.x + t];
    __syncthreads();
  }
  if (threadIdx.x == 0) atomicAdd(sse, red[0]);
}

// ---------------- convT1: qp[64,128,32,32] -> relu -> yp[64,128,33,33] ------
// block = (b, 8-co group); thread = 2x2 output tile over 31x31 (16x16 tiles,
// edge outputs guarded). Direct staging, no prefetch (see conv2_k note).
__global__ __launch_bounds__(256, 2) void convt1_k(const float* __restrict__ qp,
    const float* __restrict__ w, const float* __restrict__ bias,
    float* __restrict__ yp) {
  __shared__ __align__(16) float qs[8 * 1024 + 68];       // +pad: edge overrun
  int b = blockIdx.x >> 4, co0 = (blockIdx.x & 15) * 8;   // grid = 64*16
  int tid = threadIdx.x;
  int th = tid >> 4, tw = tid & 15;                       // 16x16 tiles
  int base = th * 64 + tw * 2;
  float acc[8][4];
  #pragma unroll
  for (int c = 0; c < 8; ++c)
    #pragma unroll
    for (int p = 0; p < 4; ++p) acc[c][p] = 0.f;
  const float4* src4 = (const float4*)(qp + ((size_t)(b * HID_) << 10));
  const float4* w4 = (const float4*)w;                    // [ci][co] float4
  for (int ch = 0; ch < 16; ++ch) {
    __syncthreads();
    #pragma unroll
    for (int s = 0; s < 8; ++s)
      ((float4*)qs)[s * 256 + tid] = src4[ch * 2048 + s * 256 + tid];
    __syncthreads();
    #pragma unroll
    for (int cl = 0; cl < 8; ++cl) {
      const float* qq = &qs[cl * 1024 + base];
      // T(r,c) = q at (2th+r, 2tw+c); edge overruns only feed guarded outputs
      float t00 = qq[0],  t01 = qq[1],  t02 = qq[2];
      float t10 = qq[32], t11 = qq[33], t12 = qq[34];
      float t20 = qq[64], t21 = qq[65], t22 = qq[66];
      int ci = ch * 8 + cl;
      #pragma unroll
      for (int c = 0; c < 8; ++c) {
        float4 wv = w4[ci * HID_ + co0 + c];              // uniform s_load
        // out(a,b) += T(a+1,b+1)*w00 + T(a+1,b)*w01 + T(a,b+1)*w10 + T(a,b)*w11
        acc[c][0] = fmaf(t11, wv.x, fmaf(t10, wv.y, fmaf(t01, wv.z,
                    fmaf(t00, wv.w, acc[c][0]))));
        acc[c][1] = fmaf(t12, wv.x, fmaf(t11, wv.y, fmaf(t02, wv.z,
                    fmaf(t01, wv.w, acc[c][1]))));
        acc[c][2] = fmaf(t21, wv.x, fmaf(t20, wv.y, fmaf(t11, wv.z,
                    fmaf(t10, wv.w, acc[c][2]))));
        acc[c][3] = fmaf(t22, wv.x, fmaf(t21, wv.y, fmaf(t12, wv.z,
                    fmaf(t11, wv.w, acc[c][3]))));
      }
    }
  }
  int oh = th * 2, ow = tw * 2;                           // 31x31 outputs
  bool eh = (oh + 1) < 31, ew = (ow + 1) < 31;
  #pragma unroll
  for (int c = 0; c < 8; ++c) {
    float bv = bias[co0 + c];
    float* yb = yp + (size_t)(b * HID_ + co0 + c) * 1089 + (oh + 1) * 33 + ow + 1;
    yb[0] = fmaxf(acc[c][0] + bv, 0.f);
    if (ew) yb[1] = fmaxf(acc[c][1] + bv, 0.f);
    if (eh) yb[33] = fmaxf(acc[c][2] + bv, 0.f);
    if (eh && ew) yb[34] = fmaxf(acc[c][3] + bv, 0.f);
  }
}

// ---------------- convT2: yp[64,128,33,33] -> x_recon[64,3,64,64] -----------
// parity-uniform remap: (oh&1, ow&1) constant per block -> weight s_loads
__global__ __launch_bounds__(256) void convt2_k(const float* __restrict__ yp,
    const float* __restrict__ w, const float* __restrict__ bias,
    float* __restrict__ out) {
  int bc = blockIdx.x;                      // b*3 + co, 0..191
  int co = bc % 3, b = bc / 3;
  int yq = blockIdx.y;                      // 0..15
  int ph = (yq >> 1) & 1, pw = yq & 1, qg = yq >> 2;
  int i = qg * 256 + threadIdx.x;           // 0..1023 over 32x32 quadrant
  int qh = i >> 5, qw = i & 31;
  int oh = qh * 2 + ph, ow = qw * 2 + pw;
  int base = (qh + 1) * 33 + qw + 1;
  const float* yb = yp + (size_t)b * HID_ * 1089;
  const float* wp0 = w + co * 16 + ph * 4 + pw;   // + ci*48, block-uniform
  float acc = bias[co];
  for (int ci = 0; ci < HID_; ++ci) {
    const float* yr = yb + ci * 1089;
    const float* wp = wp0 + ci * 48;
    acc += yr[base]      * wp[0]
         + yr[base - 1]  * wp[2]
         + yr[base - 33] * wp[8]
         + yr[base - 34] * wp[10];
  }
  out[(size_t)bc * 4096 + oh * 64 + ow] = acc;
}

// ---------------- finalize: loss + perplexity -------------------------------
__global__ __launch_bounds__(256) void fin_k(const unsigned* __restrict__ hist,
    const float* __restrict__ sse, float* __restrict__ out) {
  __shared__ float red[256];
  float e = 0.f;
  for (int k = threadIdx.x; k < K_; k += 256) {
    float p = (float)hist[k] * (1.0f / (float)NROWS_);
    e += p * logf(p + 1e-10f);
  }
  red[threadIdx.x] = e;
  __syncthreads();
  #pragma unroll
  for (int t = 128; t > 0; t >>= 1) {
    if (threadIdx.x < t) red[threadIdx.x] += red[threadIdx.x + t];
    __syncthreads();
  }
  if (threadIdx.x == 0) {
    out[786432] = 1.25f * (*sse) * (1.0f / (float)NELEM_);
    out[786433] = expf(-red[0]);
  }
}

extern "C" void kernel_launch(void* const* d_in, const int* in_sizes, int n_in,
                              void* d_out, int out_size, void* d_ws,
                              size_t ws_size, hipStream_t stream) {
  (void)in_sizes; (void)n_in; (void)out_size; (void)ws_size;
  const float* x   = (const float*)d_in[0];
  const float* ew1 = (const float*)d_in[1];
  const float* eb1 = (const float*)d_in[2];
  const float* ew2 = (const float*)d_in[3];
  const float* eb2 = (const float*)d_in[4];
  const float* cb  = (const float*)d_in[5];
  const float* dw1 = (const float*)d_in[6];
  const float* db1 = (const float*)d_in[7];
  const float* dw2 = (const float*)d_in[8];
  const float* db2 = (const float*)d_in[9];
  float* out = (float*)d_out;
  char* ws = (char*)d_ws;

  // ws layout (~98.74 MB, aliased by liveness):
  //  [0, 35,684,352)  z1p padded (33.55 MB, dead after conv2)
  //                   -> partial(3.69MB)+idx(0.23MB) -> yp (35.68 MB)
  //  [35,684,352, 65,175,552)  z (29.49 MB, live through vq3)
  //  [65,175,552, 98,729,984)  zT (29.49MB)+cbT (0.5MB) (dead after vq1)
  //                            -> qp padded quantized (33.55 MB)
  //  [98,729,984 ..) hist 4KB | cnorm 4KB | sse
  float*    z1p     = (float*)(ws);
  unsigned long long* partial = (unsigned long long*)(ws);
  int*      idxArr  = (int*)(ws + 3686400);
  float*    yp      = (float*)(ws);
  float*    z       = (float*)(ws + 35684352);
  float*    zT      = (float*)(ws + 65175552);
  float*    cbT     = (float*)(ws + 65175552 + 29491200);
  float*    qp      = (float*)(ws + 65175552);
  unsigned* hist    = (unsigned*)(ws + 98729984);
  float*    cnorm   = (float*)(ws + 98729984 + 4096);
  float*    sse     = (float*)(ws + 98729984 + 8192);

  conv1_k<<<dim3(B_ * HID_), dim3(256), 0, stream>>>(x, ew1, eb1, z1p);
  conv2_k<<<dim3(B_ * 16), dim3(256), 0, stream>>>(z1p, ew2, eb2, z);
  prep_k<<<dim3(4), dim3(256), 0, stream>>>(cb, cnorm, hist, sse);
  tr_k<<<dim3(NROWS_ / 64), dim3(256), 0, stream>>>(z, zT, NROWS_);
  tr_k<<<dim3(K_ / 64), dim3(256), 0, stream>>>(cb, cbT, K_);
  vq1_k<<<dim3(8, 450), dim3(256), 0, stream>>>(zT, cbT, cnorm, partial);
  vq2_k<<<dim3(225), dim3(256), 0, stream>>>(partial, idxArr);
  zero_k<<<dim3(8192), dim3(256), 0, stream>>>((float4*)qp, 2097152);
  vq3_k<<<dim3(225), dim3(256), 0, stream>>>(z, cb, idxArr, qp, hist, sse);
  zero_k<<<dim3(8713), dim3(256), 0, stream>>>((float4*)yp, 2230272);
  convt1_k<<<dim3(B_ * 16), dim3(256), 0, stream>>>(qp, dw1, db1, yp);
  convt2_k<<<dim3(192, 16), dim3(256), 0, stream>>>(yp, dw2, db2, out);
  fin_k<<<dim3(1), dim3(256), 0, stream>>>(hist, sse, out);
}

// Round 7
// 754.954 us; speedup vs baseline: 1.6177x; 1.0468x over previous
//
#include <hip/hip_runtime.h>

#define B_    64
#define CIN_  3
#define HW_   64
#define HID_  128
#define K_    1024
#define H1_   31      // after conv1 (stride2 k4)
#define H2_   30      // after conv2 (stride1 k2)
#define NROWS_ 57600  // B_*H2_*H2_
#define NELEM_ 7372800

// ---------------- conv1: x[64,3,64,64] -> relu -> z1p[64,128,32,32] (padded)
__global__ __launch_bounds__(256) void conv1_k(const float* __restrict__ x,
    const float* __restrict__ w, const float* __restrict__ bias,
    float* __restrict__ z1p) {
  int blk = blockIdx.x, b = blk >> 7, co = blk & 127;     // grid = 64*128
  const float* wp = w + co * 48;                          // [co][ci][4][4]
  float wr[48];
  #pragma unroll
  for (int i = 0; i < 48; ++i) wr[i] = wp[i];             // uniform -> SGPRs
  const float* xb = x + (size_t)b * CIN_ * HW_ * HW_;
  float* zb = z1p + ((size_t)blk << 10);                  // 32x32 padded plane
  float bv = bias[co];
  for (int j = threadIdx.x; j < H1_ * H1_; j += 256) {
    int oh = j / H1_, ow = j % H1_;
    float acc = bv;
    #pragma unroll
    for (int ci = 0; ci < CIN_; ++ci) {
      const float* xp = xb + ci * HW_ * HW_ + (oh * 2) * HW_ + ow * 2;
      #pragma unroll
      for (int kh = 0; kh < 4; ++kh)
        #pragma unroll
        for (int kw = 0; kw < 4; ++kw)
          acc += xp[kh * HW_ + kw] * wr[ci * 16 + kh * 4 + kw];
    }
    zb[(oh << 5) + ow] = fmaxf(acc, 0.f);                 // pad never read
  }
}

// ---------------- conv2: z1p -> relu -> z[64,128,30,30] (compact) -----------
// block = (b, 8-co group); thread = 2x2 output tile (225 active of 256).
// 1024 blocks -> 4 blocks/CU. NO register prefetch across the barrier:
// r4/r5 showed pre[8] live across __syncthreads + acc[32] => allocator
// spills acc to scratch (VGPR=52, 550 MB scratch traffic). Direct staging
// (r3 pattern) compiles clean (VGPR~128, zero scratch).
__global__ __launch_bounds__(256, 2) void conv2_k(const float* __restrict__ z1p,
    const float* __restrict__ w, const float* __restrict__ bias,
    float* __restrict__ z) {
  __shared__ __align__(16) float qs[8 * 1024];            // 32 KB
  int b = blockIdx.x >> 4, co0 = (blockIdx.x & 15) * 8;   // grid = 64*16
  int tid = threadIdx.x;
  bool act = tid < 225;                                   // 15x15 2x2-tiles
  int th = act ? tid / 15 : 0, tw = act ? tid % 15 : 0;
  int base = th * 64 + tw * 2;                            // (2th)*32 + 2tw
  float acc[8][4];
  #pragma unroll
  for (int c = 0; c < 8; ++c)
    #pragma unroll
    for (int p = 0; p < 4; ++p) acc[c][p] = 0.f;
  const float4* src4 = (const float4*)(z1p + ((size_t)(b * HID_) << 10));
  const float4* w4 = (const float4*)w;                    // [co][ci] float4
  for (int ch = 0; ch < 16; ++ch) {
    __syncthreads();
    #pragma unroll
    for (int s = 0; s < 8; ++s)
      ((float4*)qs)[s * 256 + tid] = src4[ch * 2048 + s * 256 + tid];
    __syncthreads();
    #pragma unroll
    for (int cl = 0; cl < 8; ++cl) {
      const float* qq = &qs[cl * 1024 + base];
      float t00 = qq[0],  t01 = qq[1],  t02 = qq[2];
      float t10 = qq[32], t11 = qq[33], t12 = qq[34];
      float t20 = qq[64], t21 = qq[65], t22 = qq[66];
      int ci = ch * 8 + cl;
      #pragma unroll
      for (int c = 0; c < 8; ++c) {
        float4 wv = w4[(co0 + c) * HID_ + ci];            // uniform s_load
        acc[c][0] = fmaf(t00, wv.x, fmaf(t01, wv.y, fmaf(t10, wv.z,
                    fmaf(t11, wv.w, acc[c][0]))));
        acc[c][1] = fmaf(t01, wv.x, fmaf(t02, wv.y, fmaf(t11, wv.z,
                    fmaf(t12, wv.w, acc[c][1]))));
        acc[c][2] = fmaf(t10, wv.x, fmaf(t11, wv.y, fmaf(t20, wv.z,
                    fmaf(t21, wv.w, acc[c][2]))));
        acc[c][3] = fmaf(t11, wv.x, fmaf(t12, wv.y, fmaf(t21, wv.z,
                    fmaf(t22, wv.w, acc[c][3]))));
      }
    }
  }
  if (act) {
    int oh = th * 2, ow = tw * 2;
    #pragma unroll
    for (int c = 0; c < 8; ++c) {
      float bv = bias[co0 + c];
      float* zo = z + (size_t)(b * HID_ + co0 + c) * 900;
      zo[oh * 30 + ow]           = fmaxf(acc[c][0] + bv, 0.f);
      zo[oh * 30 + ow + 1]       = fmaxf(acc[c][1] + bv, 0.f);
      zo[(oh + 1) * 30 + ow]     = fmaxf(acc[c][2] + bv, 0.f);
      zo[(oh + 1) * 30 + ow + 1] = fmaxf(acc[c][3] + bv, 0.f);
    }
  }
}

// ---------------- prep: codebook norms, zero hist/sse -----------------------
__global__ __launch_bounds__(256) void prep_k(const float* __restrict__ cb,
    float* __restrict__ cnorm, unsigned* __restrict__ hist,
    float* __restrict__ sse) {
  int k = blockIdx.x * 256 + threadIdx.x;
  if (k < K_) {
    float s0 = 0.f;
    #pragma unroll 4
    for (int d = 0; d < HID_; ++d) { float v = cb[k * HID_ + d]; s0 += v * v; }
    cnorm[k] = s0;
    hist[k] = 0u;
  }
  if (k == 0 && blockIdx.x == 0) *sse = 0.f;
}

__global__ __launch_bounds__(256) void zero_k(float4* __restrict__ p, int n4) {
  int i = blockIdx.x * 256 + threadIdx.x;
  if (i < n4) p[i] = make_float4(0.f, 0.f, 0.f, 0.f);
}

// ---------------- transpose: in[N][128] -> out[128][N], N % 64 == 0 ---------
__global__ __launch_bounds__(256) void tr_k(const float* __restrict__ in,
    float* __restrict__ out, int N) {
  __shared__ float t[64 * 133];
  int n0 = blockIdx.x * 64;
  int tid = threadIdx.x;
  const float4* in4 = (const float4*)in;
  #pragma unroll
  for (int s = 0; s < 8; ++s) {
    int flat = s * 256 + tid;          // 0..2047 float4s of the 64x128 tile
    int r = flat >> 5, c4 = flat & 31;
    float4 v = in4[n0 * 32 + flat];    // coalesced
    float* p = &t[r * 133 + c4 * 4];
    p[0] = v.x; p[1] = v.y; p[2] = v.z; p[3] = v.w;
  }
  __syncthreads();
  int w = tid >> 6, n_off = tid & 63;  // wave-uniform d, coalesced n
  #pragma unroll
  for (int s = 0; s < 32; ++s) {
    int d = s * 4 + w;
    out[d * N + n0 + n_off] = t[n_off * 133 + d];
  }
}

// ---------------- VQ phase 1: tiled GEMM-argmin over a 128-code chunk -------
// 512 threads, 256 rows x 128 codes per block; 8x8 micro-tile per thread.
// 2 blocks/CU x 8 waves = 16 waves/CU (was 8 at 256-thr): latency hiding.
__global__ __launch_bounds__(512, 2) void vq1_k(const float* __restrict__ zt,
    const float* __restrict__ cbt, const float* __restrict__ cnorm,
    unsigned long long* __restrict__ partial) {
  __shared__ __align__(16) float cbs[128 * 128];   // 64 KB
  int chunk = blockIdx.x;          // 0..7
  int n0 = blockIdx.y * 256;       // 225 row-tiles
  int k0 = chunk * 128;
  int tid = threadIdx.x;
  // stage cbT[0..127][k0..k0+127] with xor-swizzled 8-float groups
  {
    const float4* cbt4 = (const float4*)cbt;
    #pragma unroll
    for (int s = 0; s < 8; ++s) {
      int flat = s * 512 + tid;            // 0..4095
      int d = flat >> 5, c4 = flat & 31;
      float4 v = cbt4[d * 256 + (k0 >> 2) + c4];   // coalesced
      int pg = (c4 >> 1) ^ (d & 15);
      *(float4*)&cbs[d * 128 + pg * 8 + (c4 & 1) * 4] = v;
    }
  }
  __syncthreads();
  int rg = tid & 31, cg = tid >> 5;        // 32 row-groups x 16 code-groups
  float acc[8][8];
  #pragma unroll
  for (int i = 0; i < 8; ++i)
    #pragma unroll
    for (int j = 0; j < 8; ++j) acc[i][j] = 0.f;
  const float4* zt4 = (const float4*)zt;
  int zbase = (n0 >> 2) + rg * 2;
  #pragma unroll 2
  for (int d = 0; d < 128; ++d) {
    float4 a0 = zt4[d * 14400 + zbase];            // rows (global, coalesced)
    float4 a1 = zt4[d * 14400 + zbase + 1];
    const float4* cp = (const float4*)&cbs[d * 128 + (cg ^ (d & 15)) * 8];
    float4 b0 = cp[0], b1 = cp[1];                 // LDS broadcast, no conflict
    float r_[8] = {a0.x, a0.y, a0.z, a0.w, a1.x, a1.y, a1.z, a1.w};
    float c_[8] = {b0.x, b0.y, b0.z, b0.w, b1.x, b1.y, b1.z, b1.w};
    #pragma unroll
    for (int i = 0; i < 8; ++i)
      #pragma unroll
      for (int j = 0; j < 8; ++j)
        acc[i][j] += r_[i] * c_[j];
  }
  float cn[8];
  {
    const float4* cn4 = (const float4*)cnorm;
    float4 c0 = cn4[(k0 >> 2) + cg * 2];
    float4 c1 = cn4[(k0 >> 2) + cg * 2 + 1];
    cn[0] = c0.x; cn[1] = c0.y; cn[2] = c0.z; cn[3] = c0.w;
    cn[4] = c1.x; cn[5] = c1.y; cn[6] = c1.z; cn[7] = c1.w;
  }
  __syncthreads();                                  // cbs reads done; reuse LDS
  unsigned long long* red = (unsigned long long*)cbs;  // 256*16 u64 = 32 KB
  #pragma unroll
  for (int i = 0; i < 8; ++i) {
    unsigned long long best = ~0ull;
    #pragma unroll
    for (int j = 0; j < 8; ++j) {
      float dist = cn[j] - 2.f * acc[i][j];
      unsigned u = __float_as_uint(dist);
      u = (u & 0x80000000u) ? ~u : (u | 0x80000000u);  // monotone map
      unsigned long long p =
          ((unsigned long long)u << 32) | (unsigned)(k0 + cg * 8 + j);
      if (p < best) best = p;                       // tie -> smaller k
    }
    red[(rg * 8 + i) * 16 + cg] = best;
  }
  __syncthreads();
  if (tid < 256) {
    unsigned long long best = ~0ull;
    #pragma unroll
    for (int c = 0; c < 16; ++c) {
      unsigned long long p = red[tid * 16 + c];
      if (p < best) best = p;
    }
    partial[(size_t)(n0 + tid) * 8 + chunk] = best;
  }
}

// ---------------- VQ phase 2: reduce 8 chunk candidates per row -------------
__global__ __launch_bounds__(256) void vq2_k(
    const unsigned long long* __restrict__ partial, int* __restrict__ idxArr) {
  int n = blockIdx.x * 256 + threadIdx.x;           // 225 blocks
  unsigned long long best = ~0ull;
  #pragma unroll
  for (int c = 0; c < 8; ++c) {
    unsigned long long p = partial[(size_t)n * 8 + c];
    if (p < best) best = p;
  }
  idxArr[n] = (int)(best & 0xffffffffu);
}

// ---------------- VQ phase 3: scatter quantized (padded) + SSE + hist -------
__global__ __launch_bounds__(256) void vq3_k(const float* __restrict__ z,
    const float* __restrict__ cb, const int* __restrict__ idxArr,
    float* __restrict__ qp, unsigned* __restrict__ hist,
    float* __restrict__ sse) {
  int n = blockIdx.x * 256 + threadIdx.x;           // 225 blocks
  int bidx = idxArr[n];
  int f0 = n * 128;
  int b = f0 / 115200, rem = f0 % 115200;
  int c = rem / 900, s = rem % 900;
  const float4* z4 = (const float4*)z;
  const float4* cb4 = (const float4*)cb;
  float se = 0.f;
  for (int q4 = 0; q4 < 32; ++q4) {
    float4 zv = z4[n * 32 + q4];
    float4 cv = cb4[bidx * 32 + q4];
    float qe[4] = {cv.x, cv.y, cv.z, cv.w};
    float ze[4] = {zv.x, zv.y, zv.z, zv.w};
    #pragma unroll
    for (int e = 0; e < 4; ++e) {
      int h = s / 30, ww = s - h * 30;
      qp[(((size_t)(b * HID_ + c)) << 10) + ((h + 1) << 5) + (ww + 1)] = qe[e];
      float df = qe[e] - ze[e];
      se += df * df;
      if (++s == 900) { s = 0; ++c; }
    }
  }
  atomicAdd(&hist[bidx], 1u);
  __shared__ float red[256];
  red[threadIdx.x] = se;
  __syncthreads();
  #pragma unroll
  for (int t = 128; t > 0; t >>= 1) {
    if (threadIdx.x < t) red[threadIdx.x] += red[threadIdx.x + t];
    __syncthreads();
  }
  if (threadIdx.x == 0) atomicAdd(sse, red[0]);
}

// ---------------- convT1: qp[64,128,32,32] -> relu -> yp[64,128,33,33] ------
// block = (b, 8-co group); thread = 2x2 output tile over 31x31 (16x16 tiles,
// edge outputs guarded). Direct staging, no prefetch (see conv2_k note).
__global__ __launch_bounds__(256, 2) void convt1_k(const float* __restrict__ qp,
    const float* __restrict__ w, const float* __restrict__ bias,
    float* __restrict__ yp) {
  __shared__ __align__(16) float qs[8 * 1024 + 68];       // +pad: edge overrun
  int b = blockIdx.x >> 4, co0 = (blockIdx.x & 15) * 8;   // grid = 64*16
  int tid = threadIdx.x;
  int th = tid >> 4, tw = tid & 15;                       // 16x16 tiles
  int base = th * 64 + tw * 2;
  float acc[8][4];
  #pragma unroll
  for (int c = 0; c < 8; ++c)
    #pragma unroll
    for (int p = 0; p < 4; ++p) acc[c][p] = 0.f;
  const float4* src4 = (const float4*)(qp + ((size_t)(b * HID_) << 10));
  const float4* w4 = (const float4*)w;                    // [ci][co] float4
  for (int ch = 0; ch < 16; ++ch) {
    __syncthreads();
    #pragma unroll
    for (int s = 0; s < 8; ++s)
      ((float4*)qs)[s * 256 + tid] = src4[ch * 2048 + s * 256 + tid];
    __syncthreads();
    #pragma unroll
    for (int cl = 0; cl < 8; ++cl) {
      const float* qq = &qs[cl * 1024 + base];
      // T(r,c) = q at (2th+r, 2tw+c); edge overruns only feed guarded outputs
      float t00 = qq[0],  t01 = qq[1],  t02 = qq[2];
      float t10 = qq[32], t11 = qq[33], t12 = qq[34];
      float t20 = qq[64], t21 = qq[65], t22 = qq[66];
      int ci = ch * 8 + cl;
      #pragma unroll
      for (int c = 0; c < 8; ++c) {
        float4 wv = w4[ci * HID_ + co0 + c];              // uniform s_load
        // out(a,b) += T(a+1,b+1)*w00 + T(a+1,b)*w01 + T(a,b+1)*w10 + T(a,b)*w11
        acc[c][0] = fmaf(t11, wv.x, fmaf(t10, wv.y, fmaf(t01, wv.z,
                    fmaf(t00, wv.w, acc[c][0]))));
        acc[c][1] = fmaf(t12, wv.x, fmaf(t11, wv.y, fmaf(t02, wv.z,
                    fmaf(t01, wv.w, acc[c][1]))));
        acc[c][2] = fmaf(t21, wv.x, fmaf(t20, wv.y, fmaf(t11, wv.z,
                    fmaf(t10, wv.w, acc[c][2]))));
        acc[c][3] = fmaf(t22, wv.x, fmaf(t21, wv.y, fmaf(t12, wv.z,
                    fmaf(t11, wv.w, acc[c][3]))));
      }
    }
  }
  int oh = th * 2, ow = tw * 2;                           // 31x31 outputs
  bool eh = (oh + 1) < 31, ew = (ow + 1) < 31;
  #pragma unroll
  for (int c = 0; c < 8; ++c) {
    float bv = bias[co0 + c];
    float* yb = yp + (size_t)(b * HID_ + co0 + c) * 1089 + (oh + 1) * 33 + ow + 1;
    yb[0] = fmaxf(acc[c][0] + bv, 0.f);
    if (ew) yb[1] = fmaxf(acc[c][1] + bv, 0.f);
    if (eh) yb[33] = fmaxf(acc[c][2] + bv, 0.f);
    if (eh && ew) yb[34] = fmaxf(acc[c][3] + bv, 0.f);
  }
}

// ---------------- convT2: yp[64,128,33,33] -> x_recon[64,3,64,64] -----------
// parity-uniform remap: (oh&1, ow&1) constant per block -> weight s_loads
__global__ __launch_bounds__(256) void convt2_k(const float* __restrict__ yp,
    const float* __restrict__ w, const float* __restrict__ bias,
    float* __restrict__ out) {
  int bc = blockIdx.x;                      // b*3 + co, 0..191
  int co = bc % 3, b = bc / 3;
  int yq = blockIdx.y;                      // 0..15
  int ph = (yq >> 1) & 1, pw = yq & 1, qg = yq >> 2;
  int i = qg * 256 + threadIdx.x;           // 0..1023 over 32x32 quadrant
  int qh = i >> 5, qw = i & 31;
  int oh = qh * 2 + ph, ow = qw * 2 + pw;
  int base = (qh + 1) * 33 + qw + 1;
  const float* yb = yp + (size_t)b * HID_ * 1089;
  const float* wp0 = w + co * 16 + ph * 4 + pw;   // + ci*48, block-uniform
  float acc = bias[co];
  for (int ci = 0; ci < HID_; ++ci) {
    const float* yr = yb + ci * 1089;
    const float* wp = wp0 + ci * 48;
    acc += yr[base]      * wp[0]
         + yr[base - 1]  * wp[2]
         + yr[base - 33] * wp[8]
         + yr[base - 34] * wp[10];
  }
  out[(size_t)bc * 4096 + oh * 64 + ow] = acc;
}

// ---------------- finalize: loss + perplexity -------------------------------
__global__ __launch_bounds__(256) void fin_k(const unsigned* __restrict__ hist,
    const float* __restrict__ sse, float* __restrict__ out) {
  __shared__ float red[256];
  float e = 0.f;
  for (int k = threadIdx.x; k < K_; k += 256) {
    float p = (float)hist[k] * (1.0f / (float)NROWS_);
    e += p * logf(p + 1e-10f);
  }
  red[threadIdx.x] = e;
  __syncthreads();
  #pragma unroll
  for (int t = 128; t > 0; t >>= 1) {
    if (threadIdx.x < t) red[threadIdx.x] += red[threadIdx.x + t];
    __syncthreads();
  }
  if (threadIdx.x == 0) {
    out[786432] = 1.25f * (*sse) * (1.0f / (float)NELEM_);
    out[786433] = expf(-red[0]);
  }
}

extern "C" void kernel_launch(void* const* d_in, const int* in_sizes, int n_in,
                              void* d_out, int out_size, void* d_ws,
                              size_t ws_size, hipStream_t stream) {
  (void)in_sizes; (void)n_in; (void)out_size; (void)ws_size;
  const float* x   = (const float*)d_in[0];
  const float* ew1 = (const float*)d_in[1];
  const float* eb1 = (const float*)d_in[2];
  const float* ew2 = (const float*)d_in[3];
  const float* eb2 = (const float*)d_in[4];
  const float* cb  = (const float*)d_in[5];
  const float* dw1 = (const float*)d_in[6];
  const float* db1 = (const float*)d_in[7];
  const float* dw2 = (const float*)d_in[8];
  const float* db2 = (const float*)d_in[9];
  float* out = (float*)d_out;
  char* ws = (char*)d_ws;

  // ws layout (~98.74 MB, aliased by liveness):
  //  [0, 35,684,352)  z1p padded (33.55 MB, dead after conv2)
  //                   -> partial(3.69MB)+idx(0.23MB) -> yp (35.68 MB)
  //  [35,684,352, 65,175,552)  z (29.49 MB, live through vq3)
  //  [65,175,552, 98,729,984)  zT (29.49MB)+cbT (0.5MB) (dead after vq1)
  //                            -> qp padded quantized (33.55 MB)
  //  [98,729,984 ..) hist 4KB | cnorm 4KB | sse
  float*    z1p     = (float*)(ws);
  unsigned long long* partial = (unsigned long long*)(ws);
  int*      idxArr  = (int*)(ws + 3686400);
  float*    yp      = (float*)(ws);
  float*    z       = (float*)(ws + 35684352);
  float*    zT      = (float*)(ws + 65175552);
  float*    cbT     = (float*)(ws + 65175552 + 29491200);
  float*    qp      = (float*)(ws + 65175552);
  unsigned* hist    = (unsigned*)(ws + 98729984);
  float*    cnorm   = (float*)(ws + 98729984 + 4096);
  float*    sse     = (float*)(ws + 98729984 + 8192);

  conv1_k<<<dim3(B_ * HID_), dim3(256), 0, stream>>>(x, ew1, eb1, z1p);
  conv2_k<<<dim3(B_ * 16), dim3(256), 0, stream>>>(z1p, ew2, eb2, z);
  prep_k<<<dim3(4), dim3(256), 0, stream>>>(cb, cnorm, hist, sse);
  tr_k<<<dim3(NROWS_ / 64), dim3(256), 0, stream>>>(z, zT, NROWS_);
  tr_k<<<dim3(K_ / 64), dim3(256), 0, stream>>>(cb, cbT, K_);
  vq1_k<<<dim3(8, 225), dim3(512), 0, stream>>>(zT, cbT, cnorm, partial);
  vq2_k<<<dim3(225), dim3(256), 0, stream>>>(partial, idxArr);
  zero_k<<<dim3(8192), dim3(256), 0, stream>>>((float4*)qp, 2097152);
  vq3_k<<<dim3(225), dim3(256), 0, stream>>>(z, cb, idxArr, qp, hist, sse);
  zero_k<<<dim3(8713), dim3(256), 0, stream>>>((float4*)yp, 2230272);
  convt1_k<<<dim3(B_ * 16), dim3(256), 0, stream>>>(qp, dw1, db1, yp);
  convt2_k<<<dim3(192, 16), dim3(256), 0, stream>>>(yp, dw2, db2, out);
  fin_k<<<dim3(1), dim3(256), 0, stream>>>(hist, sse, out);
}

// Round 8
// 585.296 us; speedup vs baseline: 2.0866x; 1.2899x over previous
//
#include <hip/hip_runtime.h>

#define B_    64
#define CIN_  3
#define HW_   64
#define HID_  128
#define K_    1024
#define H1_   31      // after conv1 (stride2 k4)
#define H2_   30      // after conv2 (stride1 k2)
#define NROWS_ 57600  // B_*H2_*H2_
#define NELEM_ 7372800

typedef __bf16 bf16_t;
typedef __attribute__((ext_vector_type(8))) __bf16 bf16x8;
typedef __attribute__((ext_vector_type(4))) float f32x4;

// ---------------- conv1: x[64,3,64,64] -> relu -> z1p[64,128,32,32] (padded)
__global__ __launch_bounds__(256) void conv1_k(const float* __restrict__ x,
    const float* __restrict__ w, const float* __restrict__ bias,
    float* __restrict__ z1p) {
  int blk = blockIdx.x, b = blk >> 7, co = blk & 127;     // grid = 64*128
  const float* wp = w + co * 48;                          // [co][ci][4][4]
  float wr[48];
  #pragma unroll
  for (int i = 0; i < 48; ++i) wr[i] = wp[i];             // uniform -> SGPRs
  const float* xb = x + (size_t)b * CIN_ * HW_ * HW_;
  float* zb = z1p + ((size_t)blk << 10);                  // 32x32 padded plane
  float bv = bias[co];
  for (int j = threadIdx.x; j < H1_ * H1_; j += 256) {
    int oh = j / H1_, ow = j % H1_;
    float acc = bv;
    #pragma unroll
    for (int ci = 0; ci < CIN_; ++ci) {
      const float* xp = xb + ci * HW_ * HW_ + (oh * 2) * HW_ + ow * 2;
      #pragma unroll
      for (int kh = 0; kh < 4; ++kh)
        #pragma unroll
        for (int kw = 0; kw < 4; ++kw)
          acc += xp[kh * HW_ + kw] * wr[ci * 16 + kh * 4 + kw];
    }
    zb[(oh << 5) + ow] = fmaxf(acc, 0.f);                 // pad never read
  }
}

// ---------------- conv2: z1p -> relu -> z[64,128,30,30] (compact) -----------
// block = (b, 8-co group); thread = 2x2 output tile (225 active of 256).
// NO register prefetch across the barrier (r4/r5 spill cascade lesson).
__global__ __launch_bounds__(256, 2) void conv2_k(const float* __restrict__ z1p,
    const float* __restrict__ w, const float* __restrict__ bias,
    float* __restrict__ z) {
  __shared__ __align__(16) float qs[8 * 1024];            // 32 KB
  int b = blockIdx.x >> 4, co0 = (blockIdx.x & 15) * 8;   // grid = 64*16
  int tid = threadIdx.x;
  bool act = tid < 225;                                   // 15x15 2x2-tiles
  int th = act ? tid / 15 : 0, tw = act ? tid % 15 : 0;
  int base = th * 64 + tw * 2;                            // (2th)*32 + 2tw
  float acc[8][4];
  #pragma unroll
  for (int c = 0; c < 8; ++c)
    #pragma unroll
    for (int p = 0; p < 4; ++p) acc[c][p] = 0.f;
  const float4* src4 = (const float4*)(z1p + ((size_t)(b * HID_) << 10));
  const float4* w4 = (const float4*)w;                    // [co][ci] float4
  for (int ch = 0; ch < 16; ++ch) {
    __syncthreads();
    #pragma unroll
    for (int s = 0; s < 8; ++s)
      ((float4*)qs)[s * 256 + tid] = src4[ch * 2048 + s * 256 + tid];
    __syncthreads();
    #pragma unroll
    for (int cl = 0; cl < 8; ++cl) {
      const float* qq = &qs[cl * 1024 + base];
      float t00 = qq[0],  t01 = qq[1],  t02 = qq[2];
      float t10 = qq[32], t11 = qq[33], t12 = qq[34];
      float t20 = qq[64], t21 = qq[65], t22 = qq[66];
      int ci = ch * 8 + cl;
      #pragma unroll
      for (int c = 0; c < 8; ++c) {
        float4 wv = w4[(co0 + c) * HID_ + ci];            // uniform s_load
        acc[c][0] = fmaf(t00, wv.x, fmaf(t01, wv.y, fmaf(t10, wv.z,
                    fmaf(t11, wv.w, acc[c][0]))));
        acc[c][1] = fmaf(t01, wv.x, fmaf(t02, wv.y, fmaf(t11, wv.z,
                    fmaf(t12, wv.w, acc[c][1]))));
        acc[c][2] = fmaf(t10, wv.x, fmaf(t11, wv.y, fmaf(t20, wv.z,
                    fmaf(t21, wv.w, acc[c][2]))));
        acc[c][3] = fmaf(t11, wv.x, fmaf(t12, wv.y, fmaf(t21, wv.z,
                    fmaf(t22, wv.w, acc[c][3]))));
      }
    }
  }
  if (act) {
    int oh = th * 2, ow = tw * 2;
    #pragma unroll
    for (int c = 0; c < 8; ++c) {
      float bv = bias[co0 + c];
      float* zo = z + (size_t)(b * HID_ + co0 + c) * 900;
      zo[oh * 30 + ow]           = fmaxf(acc[c][0] + bv, 0.f);
      zo[oh * 30 + ow + 1]       = fmaxf(acc[c][1] + bv, 0.f);
      zo[(oh + 1) * 30 + ow]     = fmaxf(acc[c][2] + bv, 0.f);
      zo[(oh + 1) * 30 + ow + 1] = fmaxf(acc[c][3] + bv, 0.f);
    }
  }
}

// ---------------- prep: cb -> bf16 copy + bf16-consistent norms + zeros -----
__global__ __launch_bounds__(256) void prep_k(const float* __restrict__ cb,
    bf16_t* __restrict__ cbb, float* __restrict__ cnorm,
    unsigned* __restrict__ hist, float* __restrict__ sse) {
  int k = blockIdx.x * 256 + threadIdx.x;
  if (k < K_) {
    float s0 = 0.f;
    for (int d = 0; d < HID_; d += 4) {
      float4 v = *(const float4*)&cb[k * HID_ + d];
      bf16_t t[4] = {(bf16_t)v.x, (bf16_t)v.y, (bf16_t)v.z, (bf16_t)v.w};
      *(ushort4*)&((ushort*)cbb)[k * HID_ + d] = *(ushort4*)t;
      float f0 = (float)t[0], f1 = (float)t[1];
      float f2 = (float)t[2], f3 = (float)t[3];
      s0 += f0 * f0 + f1 * f1 + f2 * f2 + f3 * f3;
    }
    cnorm[k] = s0;
    hist[k] = 0u;
  }
  if (k == 0 && blockIdx.x == 0) *sse = 0.f;
}

// ---------------- cvt: z fp32 -> zb bf16 (flat) ------------------------------
__global__ __launch_bounds__(256) void cvt_k(const float4* __restrict__ z4,
    ushort4* __restrict__ o, int n4) {
  int i = blockIdx.x * 256 + threadIdx.x;
  if (i < n4) {
    float4 v = z4[i];
    bf16_t t[4] = {(bf16_t)v.x, (bf16_t)v.y, (bf16_t)v.z, (bf16_t)v.w};
    o[i] = *(ushort4*)t;
  }
}

__global__ __launch_bounds__(256) void zero_k(float4* __restrict__ p, int n4) {
  int i = blockIdx.x * 256 + threadIdx.x;
  if (i < n4) p[i] = make_float4(0.f, 0.f, 0.f, 0.f);
}

// ---------------- VQ phase 1 (MFMA): 64 rows x 1024 codes per block ---------
// dist = |c|^2_bf16 - 2*(z_bf16 . c_bf16); argmin-equivalent; ties -> first k.
// A-frag layout A[m=lane&15][k=(lane>>4)*8+j]; C/D col=lane&15,
// row=(lane>>4)*4+reg  [verified per guide m89/m120].
__global__ __launch_bounds__(256) void vq1_k(const bf16_t* __restrict__ zb,
    const bf16_t* __restrict__ cbb, const float* __restrict__ cnorm,
    int* __restrict__ idxArr) {
  __shared__ __align__(16) bf16_t zs[64 * 136];           // 17 KB (+8 pad/row)
  __shared__ __align__(16) bf16_t cbs[128 * 136];         // 34 KB
  __shared__ unsigned long long red[64 * 16];             // 8 KB
  int n0 = blockIdx.x * 64;                               // 900 blocks
  int tid = threadIdx.x;
  int wv = tid >> 6, ln = tid & 63;
  // stage z tile: 64 rows x 128 bf16, row stride 136 (16B-aligned rows)
  {
    const float4* zg4 = (const float4*)(zb + (size_t)n0 * HID_);
    #pragma unroll
    for (int s = 0; s < 4; ++s) {
      int f = s * 256 + tid;                              // 0..1023
      int row = f >> 4, seg = f & 15;
      *(float4*)&zs[row * 136 + seg * 8] = zg4[f];        // 8 bf16 / op
    }
  }
  __syncthreads();
  // A fragments: fixed for whole kernel (16 rows per wave)
  bf16x8 afr[4];
  #pragma unroll
  for (int kk = 0; kk < 4; ++kk)
    afr[kk] = *(const bf16x8*)&zs[(wv * 16 + (ln & 15)) * 136 + kk * 32 +
                                  (ln >> 4) * 8];
  unsigned long long best[4] = {~0ull, ~0ull, ~0ull, ~0ull};
  const float4* cg4 = (const float4*)cbb;
  for (int c0 = 0; c0 < K_; c0 += 128) {
    __syncthreads();                                      // protect cbs reuse
    #pragma unroll
    for (int s = 0; s < 8; ++s) {
      int f = s * 256 + tid;                              // 0..2047
      int code = f >> 4, seg = f & 15;
      *(float4*)&cbs[code * 136 + seg * 8] = cg4[(c0 + code) * 16 + seg];
    }
    __syncthreads();
    #pragma unroll 2
    for (int t = 0; t < 8; ++t) {
      f32x4 acc = {0.f, 0.f, 0.f, 0.f};
      #pragma unroll
      for (int kk = 0; kk < 4; ++kk) {
        bf16x8 bfr = *(const bf16x8*)&cbs[(t * 16 + (ln & 15)) * 136 +
                                          kk * 32 + (ln >> 4) * 8];
        acc = __builtin_amdgcn_mfma_f32_16x16x32_bf16(afr[kk], bfr, acc,
                                                      0, 0, 0);
      }
      int code = c0 + t * 16 + (ln & 15);
      float cn = cnorm[code];
      #pragma unroll
      for (int r = 0; r < 4; ++r) {
        float dist = cn - 2.f * acc[r];
        unsigned u = __float_as_uint(dist);
        u = (u & 0x80000000u) ? ~u : (u | 0x80000000u);   // monotone map
        unsigned long long p = ((unsigned long long)u << 32) | (unsigned)code;
        if (p < best[r]) best[r] = p;                     // tie -> smaller k
      }
    }
  }
  __syncthreads();
  #pragma unroll
  for (int r = 0; r < 4; ++r)
    red[(wv * 16 + (ln >> 4) * 4 + r) * 16 + (ln & 15)] = best[r];
  __syncthreads();
  if (tid < 64) {
    unsigned long long b = ~0ull;
    #pragma unroll
    for (int c = 0; c < 16; ++c) {
      unsigned long long p = red[tid * 16 + c];
      if (p < b) b = p;
    }
    idxArr[n0 + tid] = (int)(b & 0xffffffffu);
  }
}

// ---------------- VQ phase 3: scatter quantized (padded) + SSE + hist -------
// quantized values come from the ORIGINAL fp32 codebook (bf16 only for argmin)
__global__ __launch_bounds__(256) void vq3_k(const float* __restrict__ z,
    const float* __restrict__ cb, const int* __restrict__ idxArr,
    float* __restrict__ qp, unsigned* __restrict__ hist,
    float* __restrict__ sse) {
  int n = blockIdx.x * 256 + threadIdx.x;           // 225 blocks
  int bidx = idxArr[n];
  int f0 = n * 128;
  int b = f0 / 115200, rem = f0 % 115200;
  int c = rem / 900, s = rem % 900;
  const float4* z4 = (const float4*)z;
  const float4* cb4 = (const float4*)cb;
  float se = 0.f;
  for (int q4 = 0; q4 < 32; ++q4) {
    float4 zv = z4[n * 32 + q4];
    float4 cv = cb4[bidx * 32 + q4];
    float qe[4] = {cv.x, cv.y, cv.z, cv.w};
    float ze[4] = {zv.x, zv.y, zv.z, zv.w};
    #pragma unroll
    for (int e = 0; e < 4; ++e) {
      int h = s / 30, ww = s - h * 30;
      qp[(((size_t)(b * HID_ + c)) << 10) + ((h + 1) << 5) + (ww + 1)] = qe[e];
      float df = qe[e] - ze[e];
      se += df * df;
      if (++s == 900) { s = 0; ++c; }
    }
  }
  atomicAdd(&hist[bidx], 1u);
  __shared__ float red[256];
  red[threadIdx.x] = se;
  __syncthreads();
  #pragma unroll
  for (int t = 128; t > 0; t >>= 1) {
    if (threadIdx.x < t) red[threadIdx.x] += red[threadIdx.x + t];
    __syncthreads();
  }
  if (threadIdx.x == 0) atomicAdd(sse, red[0]);
}

// ---------------- convT1: qp[64,128,32,32] -> relu -> yp[64,128,33,33] ------
__global__ __launch_bounds__(256, 2) void convt1_k(const float* __restrict__ qp,
    const float* __restrict__ w, const float* __restrict__ bias,
    float* __restrict__ yp) {
  __shared__ __align__(16) float qs[8 * 1024 + 68];       // +pad: edge overrun
  int b = blockIdx.x >> 4, co0 = (blockIdx.x & 15) * 8;   // grid = 64*16
  int tid = threadIdx.x;
  int th = tid >> 4, tw = tid & 15;                       // 16x16 tiles
  int base = th * 64 + tw * 2;
  float acc[8][4];
  #pragma unroll
  for (int c = 0; c < 8; ++c)
    #pragma unroll
    for (int p = 0; p < 4; ++p) acc[c][p] = 0.f;
  const float4* src4 = (const float4*)(qp + ((size_t)(b * HID_) << 10));
  const float4* w4 = (const float4*)w;                    // [ci][co] float4
  for (int ch = 0; ch < 16; ++ch) {
    __syncthreads();
    #pragma unroll
    for (int s = 0; s < 8; ++s)
      ((float4*)qs)[s * 256 + tid] = src4[ch * 2048 + s * 256 + tid];
    __syncthreads();
    #pragma unroll
    for (int cl = 0; cl < 8; ++cl) {
      const float* qq = &qs[cl * 1024 + base];
      float t00 = qq[0],  t01 = qq[1],  t02 = qq[2];
      float t10 = qq[32], t11 = qq[33], t12 = qq[34];
      float t20 = qq[64], t21 = qq[65], t22 = qq[66];
      int ci = ch * 8 + cl;
      #pragma unroll
      for (int c = 0; c < 8; ++c) {
        float4 wv = w4[ci * HID_ + co0 + c];              // uniform s_load
        acc[c][0] = fmaf(t11, wv.x, fmaf(t10, wv.y, fmaf(t01, wv.z,
                    fmaf(t00, wv.w, acc[c][0]))));
        acc[c][1] = fmaf(t12, wv.x, fmaf(t11, wv.y, fmaf(t02, wv.z,
                    fmaf(t01, wv.w, acc[c][1]))));
        acc[c][2] = fmaf(t21, wv.x, fmaf(t20, wv.y, fmaf(t11, wv.z,
                    fmaf(t10, wv.w, acc[c][2]))));
        acc[c][3] = fmaf(t22, wv.x, fmaf(t21, wv.y, fmaf(t12, wv.z,
                    fmaf(t11, wv.w, acc[c][3]))));
      }
    }
  }
  int oh = th * 2, ow = tw * 2;                           // 31x31 outputs
  bool eh = (oh + 1) < 31, ew = (ow + 1) < 31;
  #pragma unroll
  for (int c = 0; c < 8; ++c) {
    float bv = bias[co0 + c];
    float* yb = yp + (size_t)(b * HID_ + co0 + c) * 1089 + (oh + 1) * 33 + ow + 1;
    yb[0] = fmaxf(acc[c][0] + bv, 0.f);
    if (ew) yb[1] = fmaxf(acc[c][1] + bv, 0.f);
    if (eh) yb[33] = fmaxf(acc[c][2] + bv, 0.f);
    if (eh && ew) yb[34] = fmaxf(acc[c][3] + bv, 0.f);
  }
}

// ---------------- convT2: yp[64,128,33,33] -> x_recon[64,3,64,64] -----------
__global__ __launch_bounds__(256) void convt2_k(const float* __restrict__ yp,
    const float* __restrict__ w, const float* __restrict__ bias,
    float* __restrict__ out) {
  int bc = blockIdx.x;                      // b*3 + co, 0..191
  int co = bc % 3, b = bc / 3;
  int yq = blockIdx.y;                      // 0..15
  int ph = (yq >> 1) & 1, pw = yq & 1, qg = yq >> 2;
  int i = qg * 256 + threadIdx.x;           // 0..1023 over 32x32 quadrant
  int qh = i >> 5, qw = i & 31;
  int oh = qh * 2 + ph, ow = qw * 2 + pw;
  int base = (qh + 1) * 33 + qw + 1;
  const float* yb = yp + (size_t)b * HID_ * 1089;
  const float* wp0 = w + co * 16 + ph * 4 + pw;   // + ci*48, block-uniform
  float acc = bias[co];
  for (int ci = 0; ci < HID_; ++ci) {
    const float* yr = yb + ci * 1089;
    const float* wp = wp0 + ci * 48;
    acc += yr[base]      * wp[0]
         + yr[base - 1]  * wp[2]
         + yr[base - 33] * wp[8]
         + yr[base - 34] * wp[10];
  }
  out[(size_t)bc * 4096 + oh * 64 + ow] = acc;
}

// ---------------- finalize: loss + perplexity -------------------------------
__global__ __launch_bounds__(256) void fin_k(const unsigned* __restrict__ hist,
    const float* __restrict__ sse, float* __restrict__ out) {
  __shared__ float red[256];
  float e = 0.f;
  for (int k = threadIdx.x; k < K_; k += 256) {
    float p = (float)hist[k] * (1.0f / (float)NROWS_);
    e += p * logf(p + 1e-10f);
  }
  red[threadIdx.x] = e;
  __syncthreads();
  #pragma unroll
  for (int t = 128; t > 0; t >>= 1) {
    if (threadIdx.x < t) red[threadIdx.x] += red[threadIdx.x + t];
    __syncthreads();
  }
  if (threadIdx.x == 0) {
    out[786432] = 1.25f * (*sse) * (1.0f / (float)NELEM_);
    out[786433] = expf(-red[0]);
  }
}

extern "C" void kernel_launch(void* const* d_in, const int* in_sizes, int n_in,
                              void* d_out, int out_size, void* d_ws,
                              size_t ws_size, hipStream_t stream) {
  (void)in_sizes; (void)n_in; (void)out_size; (void)ws_size;
  const float* x   = (const float*)d_in[0];
  const float* ew1 = (const float*)d_in[1];
  const float* eb1 = (const float*)d_in[2];
  const float* ew2 = (const float*)d_in[3];
  const float* eb2 = (const float*)d_in[4];
  const float* cb  = (const float*)d_in[5];
  const float* dw1 = (const float*)d_in[6];
  const float* db1 = (const float*)d_in[7];
  const float* dw2 = (const float*)d_in[8];
  const float* db2 = (const float*)d_in[9];
  float* out = (float*)d_out;
  char* ws = (char*)d_ws;

  // ws layout (~98.74 MB, aliased by liveness):
  //  [0, 35,684,352)  z1p padded (33.55 MB, dead after conv2)
  //                   -> idxArr(0.23MB) -> yp (35.68 MB)
  //  [35,684,352, 65,175,552)  z (29.49 MB, live through vq3)
  //  [65,175,552, 98,729,984)  zb bf16 (14.75MB) + cbb bf16 (0.26MB)
  //                            (dead after vq1) -> qp padded (33.55 MB)
  //  [98,729,984 ..) hist 4KB | cnorm 4KB | sse
  float*    z1p     = (float*)(ws);
  int*      idxArr  = (int*)(ws + 3686400);
  float*    yp      = (float*)(ws);
  float*    z       = (float*)(ws + 35684352);
  bf16_t*   zbuf    = (bf16_t*)(ws + 65175552);
  bf16_t*   cbb     = (bf16_t*)(ws + 65175552 + 14745600);
  float*    qp      = (float*)(ws + 65175552);
  unsigned* hist    = (unsigned*)(ws + 98729984);
  float*    cnorm   = (float*)(ws + 98729984 + 4096);
  float*    sse     = (float*)(ws + 98729984 + 8192);

  conv1_k<<<dim3(B_ * HID_), dim3(256), 0, stream>>>(x, ew1, eb1, z1p);
  conv2_k<<<dim3(B_ * 16), dim3(256), 0, stream>>>(z1p, ew2, eb2, z);
  prep_k<<<dim3(4), dim3(256), 0, stream>>>(cb, cbb, cnorm, hist, sse);
  cvt_k<<<dim3(7200), dim3(256), 0, stream>>>((const float4*)z,
                                              (ushort4*)zbuf, NELEM_ / 4);
  vq1_k<<<dim3(NROWS_ / 64), dim3(256), 0, stream>>>(zbuf, cbb, cnorm, idxArr);
  zero_k<<<dim3(8192), dim3(256), 0, stream>>>((float4*)qp, 2097152);
  vq3_k<<<dim3(225), dim3(256), 0, stream>>>(z, cb, idxArr, qp, hist, sse);
  zero_k<<<dim3(8713), dim3(256), 0, stream>>>((float4*)yp, 2230272);
  convt1_k<<<dim3(B_ * 16), dim3(256), 0, stream>>>(qp, dw1, db1, yp);
  convt2_k<<<dim3(192, 16), dim3(256), 0, stream>>>(yp, dw2, db2, out);
  fin_k<<<dim3(1), dim3(256), 0, stream>>>(hist, sse, out);
}

// Round 9
// 553.176 us; speedup vs baseline: 2.2078x; 1.0581x over previous
//
#include <hip/hip_runtime.h>

#define B_    64
#define CIN_  3
#define HW_   64
#define HID_  128
#define K_    1024
#define H1_   31      // after conv1 (stride2 k4)
#define H2_   30      // after conv2 (stride1 k2)
#define NROWS_ 57600  // B_*H2_*H2_
#define NELEM_ 7372800

typedef __bf16 bf16_t;
typedef __attribute__((ext_vector_type(8))) __bf16 bf16x8;
typedef __attribute__((ext_vector_type(4))) float f32x4;

// ---------------- conv1: x[64,3,64,64] -> relu -> z1p[64,128,32,32] (padded)
__global__ __launch_bounds__(256) void conv1_k(const float* __restrict__ x,
    const float* __restrict__ w, const float* __restrict__ bias,
    float* __restrict__ z1p) {
  int blk = blockIdx.x, b = blk >> 7, co = blk & 127;     // grid = 64*128
  const float* wp = w + co * 48;                          // [co][ci][4][4]
  float wr[48];
  #pragma unroll
  for (int i = 0; i < 48; ++i) wr[i] = wp[i];             // uniform -> SGPRs
  const float* xb = x + (size_t)b * CIN_ * HW_ * HW_;
  float* zb = z1p + ((size_t)blk << 10);                  // 32x32 padded plane
  float bv = bias[co];
  for (int j = threadIdx.x; j < H1_ * H1_; j += 256) {
    int oh = j / H1_, ow = j % H1_;
    float acc = bv;
    #pragma unroll
    for (int ci = 0; ci < CIN_; ++ci) {
      const float* xp = xb + ci * HW_ * HW_ + (oh * 2) * HW_ + ow * 2;
      #pragma unroll
      for (int kh = 0; kh < 4; ++kh)
        #pragma unroll
        for (int kw = 0; kw < 4; ++kw)
          acc += xp[kh * HW_ + kw] * wr[ci * 16 + kh * 4 + kw];
    }
    zb[(oh << 5) + ow] = fmaxf(acc, 0.f);                 // pad never read
  }
}

// ---------------- tz: z1p fp32 [b*128][1024] -> z1t bf16 [b][1024][128] -----
__global__ __launch_bounds__(256) void tz_k(const float* __restrict__ z1p,
    bf16_t* __restrict__ z1t) {
  __shared__ bf16_t t[64 * 136];
  int b = blockIdx.x >> 4, pc = blockIdx.x & 15;          // 64-pos chunk
  int tid = threadIdx.x;
  const float4* src = (const float4*)z1p;
  #pragma unroll
  for (int s = 0; s < 8; ++s) {
    int f = s * 256 + tid;                                // 2048 f4s
    int ci = f >> 4, c16 = f & 15;
    float4 v = src[(size_t)(b * HID_ + ci) * 256 + pc * 16 + c16];
    t[(c16 * 4 + 0) * 136 + ci] = (bf16_t)v.x;
    t[(c16 * 4 + 1) * 136 + ci] = (bf16_t)v.y;
    t[(c16 * 4 + 2) * 136 + ci] = (bf16_t)v.z;
    t[(c16 * 4 + 3) * 136 + ci] = (bf16_t)v.w;
  }
  __syncthreads();
  #pragma unroll
  for (int s = 0; s < 4; ++s) {
    int f = s * 256 + tid;                                // 1024 f4s out
    int pos = f >> 4, c16 = f & 15;
    *(float4*)&z1t[((size_t)b * 1024 + pc * 64 + pos) * 128 + c16 * 8] =
        *(float4*)&t[pos * 136 + c16 * 8];
  }
}

// ---------------- wprep: bf16 weight transposes -----------------------------
// wc2[t][co][ci] = ew2[co][ci][t]; wd1[t][co][ci] = dw1[ci][co][3-t]
__global__ __launch_bounds__(256) void wprep_k(const float* __restrict__ ew2,
    const float* __restrict__ dw1, bf16_t* __restrict__ wc2,
    bf16_t* __restrict__ wd1) {
  int id = blockIdx.x * 256 + threadIdx.x;                // grid 256 -> 65536
  int t = id >> 14, co = (id >> 7) & 127, ci = id & 127;
  wc2[id] = (bf16_t)ew2[(co * 128 + ci) * 4 + t];
  wd1[id] = (bf16_t)dw1[(ci * 128 + co) * 4 + (3 - t)];
}

// ---------------- conv2 (MFMA): z1t -> relu -> z fp32 + zbuf bf16 -----------
// block = (b, row-pair rt of 15); A = 128pos x 128ci LDS tile (stride 136),
// B = wc2 from global (L2-resident); 4 taps x 4 k-chunks x 8 co-tiles MFMA.
__global__ __launch_bounds__(256, 2) void conv2m_k(const bf16_t* __restrict__ z1t,
    const bf16_t* __restrict__ wc2, const float* __restrict__ bias,
    float* __restrict__ z, ushort* __restrict__ zbuf) {
  __shared__ __align__(16) bf16_t as_[128 * 136];         // 34.8 KB
  int blk = blockIdx.x;                                   // 64*15
  int b = blk / 15, rt = blk % 15;
  int tid = threadIdx.x, wv = tid >> 6, ln = tid & 63;
  const float4* src = (const float4*)(z1t + ((size_t)b * 1024 + rt * 64) * 128);
  #pragma unroll
  for (int s = 0; s < 8; ++s) {
    int f = s * 256 + tid;                                // 2048 f4 = 32 KB
    int lp = f >> 4, c16 = f & 15;
    *(float4*)&as_[lp * 136 + c16 * 8] = src[f];
  }
  __syncthreads();
  int m = wv * 16 + (ln & 15), q = ln >> 4;
  f32x4 acc8[8];
  #pragma unroll
  for (int c = 0; c < 8; ++c) acc8[c] = (f32x4){0.f, 0.f, 0.f, 0.f};
  #pragma unroll
  for (int t = 0; t < 4; ++t) {
    int off = (t >> 1) * 32 + (t & 1);                    // tap offset in pos
    bf16x8 af[4];
    #pragma unroll
    for (int kk = 0; kk < 4; ++kk)
      af[kk] = *(const bf16x8*)&as_[(m + off) * 136 + kk * 32 + q * 8];
    #pragma unroll
    for (int cot = 0; cot < 8; ++cot) {
      const bf16_t* wp = wc2 + (size_t)(t * 128 + cot * 16 + (ln & 15)) * 128
                         + q * 8;
      #pragma unroll
      for (int kk = 0; kk < 4; ++kk) {
        bf16x8 bf = *(const bf16x8*)(wp + kk * 32);
        acc8[cot] = __builtin_amdgcn_mfma_f32_16x16x32_bf16(af[kk], bf,
                                                            acc8[cot], 0, 0, 0);
      }
    }
  }
  // D[row=q*4+r][col=ln&15]; garbage cols (>=30) discarded
  #pragma unroll
  for (int cot = 0; cot < 8; ++cot) {
    int co = cot * 16 + (ln & 15);
    float bv = bias[co];
    #pragma unroll
    for (int r = 0; r < 4; ++r) {
      int mo = wv * 16 + q * 4 + r;
      int ocol = mo & 31;
      if (ocol < 30) {
        int orow = rt * 2 + (mo >> 5);                    // always < 30
        float v = fmaxf(acc8[cot][r] + bv, 0.f);
        size_t idx = (size_t)(b * HID_ + co) * 900 + orow * 30 + ocol;
        z[idx] = v;
        bf16_t h = (bf16_t)v;
        zbuf[idx] = *(ushort*)&h;                         // fused cvt for vq1
      }
    }
  }
}

// ---------------- prep: cb -> bf16 copy + bf16-consistent norms + zeros -----
__global__ __launch_bounds__(256) void prep_k(const float* __restrict__ cb,
    bf16_t* __restrict__ cbb, float* __restrict__ cnorm,
    unsigned* __restrict__ hist, float* __restrict__ sse) {
  int k = blockIdx.x * 256 + threadIdx.x;
  if (k < K_) {
    float s0 = 0.f;
    for (int d = 0; d < HID_; d += 4) {
      float4 v = *(const float4*)&cb[k * HID_ + d];
      bf16_t t[4] = {(bf16_t)v.x, (bf16_t)v.y, (bf16_t)v.z, (bf16_t)v.w};
      *(ushort4*)&((ushort*)cbb)[k * HID_ + d] = *(ushort4*)t;
      float f0 = (float)t[0], f1 = (float)t[1];
      float f2 = (float)t[2], f3 = (float)t[3];
      s0 += f0 * f0 + f1 * f1 + f2 * f2 + f3 * f3;
    }
    cnorm[k] = s0;
    hist[k] = 0u;
  }
  if (k == 0 && blockIdx.x == 0) *sse = 0.f;
}

__global__ __launch_bounds__(256) void zero_k(float4* __restrict__ p, int n4) {
  int i = blockIdx.x * 256 + threadIdx.x;
  if (i < n4) p[i] = make_float4(0.f, 0.f, 0.f, 0.f);
}

// ---------------- VQ phase 1 (MFMA): 64 rows x 1024 codes per block ---------
__global__ __launch_bounds__(256) void vq1_k(const bf16_t* __restrict__ zb,
    const bf16_t* __restrict__ cbb, const float* __restrict__ cnorm,
    int* __restrict__ idxArr) {
  __shared__ __align__(16) bf16_t zs[64 * 136];           // 17 KB
  __shared__ __align__(16) bf16_t cbs[128 * 136];         // 34 KB
  __shared__ unsigned long long red[64 * 16];             // 8 KB
  int n0 = blockIdx.x * 64;                               // 900 blocks
  int tid = threadIdx.x;
  int wv = tid >> 6, ln = tid & 63;
  {
    const float4* zg4 = (const float4*)(zb + (size_t)n0 * HID_);
    #pragma unroll
    for (int s = 0; s < 4; ++s) {
      int f = s * 256 + tid;
      int row = f >> 4, seg = f & 15;
      *(float4*)&zs[row * 136 + seg * 8] = zg4[f];
    }
  }
  __syncthreads();
  bf16x8 afr[4];
  #pragma unroll
  for (int kk = 0; kk < 4; ++kk)
    afr[kk] = *(const bf16x8*)&zs[(wv * 16 + (ln & 15)) * 136 + kk * 32 +
                                  (ln >> 4) * 8];
  unsigned long long best[4] = {~0ull, ~0ull, ~0ull, ~0ull};
  const float4* cg4 = (const float4*)cbb;
  for (int c0 = 0; c0 < K_; c0 += 128) {
    __syncthreads();
    #pragma unroll
    for (int s = 0; s < 8; ++s) {
      int f = s * 256 + tid;
      int code = f >> 4, seg = f & 15;
      *(float4*)&cbs[code * 136 + seg * 8] = cg4[(c0 + code) * 16 + seg];
    }
    __syncthreads();
    #pragma unroll 2
    for (int t = 0; t < 8; ++t) {
      f32x4 acc = {0.f, 0.f, 0.f, 0.f};
      #pragma unroll
      for (int kk = 0; kk < 4; ++kk) {
        bf16x8 bfr = *(const bf16x8*)&cbs[(t * 16 + (ln & 15)) * 136 +
                                          kk * 32 + (ln >> 4) * 8];
        acc = __builtin_amdgcn_mfma_f32_16x16x32_bf16(afr[kk], bfr, acc,
                                                      0, 0, 0);
      }
      int code = c0 + t * 16 + (ln & 15);
      float cn = cnorm[code];
      #pragma unroll
      for (int r = 0; r < 4; ++r) {
        float dist = cn - 2.f * acc[r];
        unsigned u = __float_as_uint(dist);
        u = (u & 0x80000000u) ? ~u : (u | 0x80000000u);
        unsigned long long p = ((unsigned long long)u << 32) | (unsigned)code;
        if (p < best[r]) best[r] = p;
      }
    }
  }
  __syncthreads();
  #pragma unroll
  for (int r = 0; r < 4; ++r)
    red[(wv * 16 + (ln >> 4) * 4 + r) * 16 + (ln & 15)] = best[r];
  __syncthreads();
  if (tid < 64) {
    unsigned long long b = ~0ull;
    #pragma unroll
    for (int c = 0; c < 16; ++c) {
      unsigned long long p = red[tid * 16 + c];
      if (p < b) b = p;
    }
    idxArr[n0 + tid] = (int)(b & 0xffffffffu);
  }
}

// ---------------- VQ phase 3: scatter quantized -> qt bf16 [b][pos][ci] -----
// qt padded pos = (h+1)*32 + (w+1); SSE/loss from fp32 z & cb (ref semantics)
__global__ __launch_bounds__(256) void vq3_k(const float* __restrict__ z,
    const float* __restrict__ cb, const int* __restrict__ idxArr,
    ushort* __restrict__ qt, unsigned* __restrict__ hist,
    float* __restrict__ sse) {
  int n = blockIdx.x * 256 + threadIdx.x;           // 225 blocks
  int bidx = idxArr[n];
  int f0 = n * 128;
  int b = f0 / 115200, rem = f0 % 115200;
  int c = rem / 900, s = rem % 900;
  const float4* z4 = (const float4*)z;
  const float4* cb4 = (const float4*)cb;
  float se = 0.f;
  for (int q4 = 0; q4 < 32; ++q4) {
    float4 zv = z4[n * 32 + q4];
    float4 cv = cb4[bidx * 32 + q4];
    float qe[4] = {cv.x, cv.y, cv.z, cv.w};
    float ze[4] = {zv.x, zv.y, zv.z, zv.w};
    #pragma unroll
    for (int e = 0; e < 4; ++e) {
      int h = s / 30, ww = s - h * 30;
      int p = ((h + 1) << 5) + (ww + 1);
      bf16_t hq = (bf16_t)qe[e];
      qt[((size_t)(b * 1024 + p)) * 128 + c] = *(ushort*)&hq;
      float df = qe[e] - ze[e];
      se += df * df;
      if (++s == 900) { s = 0; ++c; }
    }
  }
  atomicAdd(&hist[bidx], 1u);
  __shared__ float red[256];
  red[threadIdx.x] = se;
  __syncthreads();
  #pragma unroll
  for (int t = 128; t > 0; t >>= 1) {
    if (threadIdx.x < t) red[threadIdx.x] += red[threadIdx.x + t];
    __syncthreads();
  }
  if (threadIdx.x == 0) atomicAdd(sse, red[0]);
}

// ---------------- convT1 (MFMA): qt -> relu -> yp fp32 [co][33x33] ----------
// identical structure to conv2m; wd1 has the tap flip baked in (wprep).
__global__ __launch_bounds__(256, 2) void convt1m_k(const bf16_t* __restrict__ qt,
    const bf16_t* __restrict__ wd1, const float* __restrict__ bias,
    float* __restrict__ yp) {
  __shared__ __align__(16) bf16_t as_[128 * 136];
  int blk = blockIdx.x;                                   // 64*16
  int b = blk >> 4, rt = blk & 15;
  int tid = threadIdx.x, wv = tid >> 6, ln = tid & 63;
  const float4* src = (const float4*)(qt + ((size_t)b * 1024 + rt * 64) * 128);
  #pragma unroll
  for (int s = 0; s < 8; ++s) {
    int f = s * 256 + tid;
    int lp = f >> 4, c16 = f & 15;
    *(float4*)&as_[lp * 136 + c16 * 8] = src[f];          // rt=15 reads slack
  }
  __syncthreads();
  int m = wv * 16 + (ln & 15), q = ln >> 4;
  f32x4 acc8[8];
  #pragma unroll
  for (int c = 0; c < 8; ++c) acc8[c] = (f32x4){0.f, 0.f, 0.f, 0.f};
  #pragma unroll
  for (int t = 0; t < 4; ++t) {
    int off = (t >> 1) * 32 + (t & 1);
    bf16x8 af[4];
    #pragma unroll
    for (int kk = 0; kk < 4; ++kk)
      af[kk] = *(const bf16x8*)&as_[(m + off) * 136 + kk * 32 + q * 8];
    #pragma unroll
    for (int cot = 0; cot < 8; ++cot) {
      const bf16_t* wp = wd1 + (size_t)(t * 128 + cot * 16 + (ln & 15)) * 128
                         + q * 8;
      #pragma unroll
      for (int kk = 0; kk < 4; ++kk) {
        bf16x8 bf = *(const bf16x8*)(wp + kk * 32);
        acc8[cot] = __builtin_amdgcn_mfma_f32_16x16x32_bf16(af[kk], bf,
                                                            acc8[cot], 0, 0, 0);
      }
    }
  }
  #pragma unroll
  for (int cot = 0; cot < 8; ++cot) {
    int co = cot * 16 + (ln & 15);
    float bv = bias[co];
    #pragma unroll
    for (int r = 0; r < 4; ++r) {
      int mo = wv * 16 + q * 4 + r;
      int orow = rt * 2 + (mo >> 5), ocol = mo & 31;
      if (orow < 31 && ocol < 31) {
        float v = fmaxf(acc8[cot][r] + bv, 0.f);
        yp[(size_t)(b * HID_ + co) * 1089 + (orow + 1) * 33 + (ocol + 1)] = v;
      }
    }
  }
}

// ---------------- convT2: yp[64,128,33,33] -> x_recon[64,3,64,64] -----------
__global__ __launch_bounds__(256) void convt2_k(const float* __restrict__ yp,
    const float* __restrict__ w, const float* __restrict__ bias,
    float* __restrict__ out) {
  int bc = blockIdx.x;                      // b*3 + co, 0..191
  int co = bc % 3, b = bc / 3;
  int yq = blockIdx.y;                      // 0..15
  int ph = (yq >> 1) & 1, pw = yq & 1, qg = yq >> 2;
  int i = qg * 256 + threadIdx.x;           // 0..1023 over 32x32 quadrant
  int qh = i >> 5, qw = i & 31;
  int oh = qh * 2 + ph, ow = qw * 2 + pw;
  int base = (qh + 1) * 33 + qw + 1;
  const float* yb = yp + (size_t)b * HID_ * 1089;
  const float* wp0 = w + co * 16 + ph * 4 + pw;   // + ci*48, block-uniform
  float acc = bias[co];
  for (int ci = 0; ci < HID_; ++ci) {
    const float* yr = yb + ci * 1089;
    const float* wp = wp0 + ci * 48;
    acc += yr[base]      * wp[0]
         + yr[base - 1]  * wp[2]
         + yr[base - 33] * wp[8]
         + yr[base - 34] * wp[10];
  }
  out[(size_t)bc * 4096 + oh * 64 + ow] = acc;
}

// ---------------- finalize: loss + perplexity -------------------------------
__global__ __launch_bounds__(256) void fin_k(const unsigned* __restrict__ hist,
    const float* __restrict__ sse, float* __restrict__ out) {
  __shared__ float red[256];
  float e = 0.f;
  for (int k = threadIdx.x; k < K_; k += 256) {
    float p = (float)hist[k] * (1.0f / (float)NROWS_);
    e += p * logf(p + 1e-10f);
  }
  red[threadIdx.x] = e;
  __syncthreads();
  #pragma unroll
  for (int t = 128; t > 0; t >>= 1) {
    if (threadIdx.x < t) red[threadIdx.x] += red[threadIdx.x + t];
    __syncthreads();
  }
  if (threadIdx.x == 0) {
    out[786432] = 1.25f * (*sse) * (1.0f / (float)NELEM_);
    out[786433] = expf(-red[0]);
  }
}

extern "C" void kernel_launch(void* const* d_in, const int* in_sizes, int n_in,
                              void* d_out, int out_size, void* d_ws,
                              size_t ws_size, hipStream_t stream) {
  (void)in_sizes; (void)n_in; (void)out_size; (void)ws_size;
  const float* x   = (const float*)d_in[0];
  const float* ew1 = (const float*)d_in[1];
  const float* eb1 = (const float*)d_in[2];
  const float* ew2 = (const float*)d_in[3];
  const float* eb2 = (const float*)d_in[4];
  const float* cb  = (const float*)d_in[5];
  const float* dw1 = (const float*)d_in[6];
  const float* db1 = (const float*)d_in[7];
  const float* dw2 = (const float*)d_in[8];
  const float* db2 = (const float*)d_in[9];
  float* out = (float*)d_out;
  char* ws = (char*)d_ws;

  // ws layout (~97.5 MB, aliased by liveness):
  //  [0, 35,684,352)            z1p (conv1->tz) then yp (zeroed, convt1m->convt2)
  //  [35,684,352, 65,175,552)   z fp32 (conv2m->vq3)
  //  [65,175,552, 81,985,536)   z1t bf16 +slack (tz->conv2m) then qt bf16
  //  [81,985,536, 96,731,136)   zbuf bf16 (conv2m->vq1)
  //  [96,731,136 ..)            cbb | wc2 | wd1 | idxArr | hist | cnorm | sse
  float*    z1p   = (float*)(ws);
  float*    yp    = (float*)(ws);
  float*    z     = (float*)(ws + 35684352);
  bf16_t*   z1t   = (bf16_t*)(ws + 65175552);
  bf16_t*   qt    = (bf16_t*)(ws + 65175552);
  ushort*   zbuf  = (ushort*)(ws + 81985536);
  bf16_t*   cbb   = (bf16_t*)(ws + 96731136);
  bf16_t*   wc2   = (bf16_t*)(ws + 96993280);
  bf16_t*   wd1   = (bf16_t*)(ws + 97124352);
  int*      idxArr= (int*)(ws + 97255424);
  unsigned* hist  = (unsigned*)(ws + 97485824);
  float*    cnorm = (float*)(ws + 97489920);
  float*    sse   = (float*)(ws + 97494016);

  conv1_k<<<dim3(B_ * HID_), dim3(256), 0, stream>>>(x, ew1, eb1, z1p);
  tz_k<<<dim3(1024), dim3(256), 0, stream>>>(z1p, z1t);
  wprep_k<<<dim3(256), dim3(256), 0, stream>>>(ew2, dw1, wc2, wd1);
  conv2m_k<<<dim3(960), dim3(256), 0, stream>>>(z1t, wc2, eb2, z, zbuf);
  prep_k<<<dim3(4), dim3(256), 0, stream>>>(cb, cbb, cnorm, hist, sse);
  vq1_k<<<dim3(900), dim3(256), 0, stream>>>((const bf16_t*)zbuf, cbb, cnorm,
                                             idxArr);
  zero_k<<<dim3(4104), dim3(256), 0, stream>>>((float4*)qt, 1050624);
  vq3_k<<<dim3(225), dim3(256), 0, stream>>>(z, cb, idxArr, (ushort*)qt,
                                             hist, sse);
  zero_k<<<dim3(8713), dim3(256), 0, stream>>>((float4*)yp, 2230272);
  convt1m_k<<<dim3(1024), dim3(256), 0, stream>>>(qt, wd1, db1, yp);
  convt2_k<<<dim3(192, 16), dim3(256), 0, stream>>>(yp, dw2, db2, out);
  fin_k<<<dim3(1), dim3(256), 0, stream>>>(hist, sse, out);
}

// Round 10
// 549.341 us; speedup vs baseline: 2.2232x; 1.0070x over previous
//
#include <hip/hip_runtime.h>

#define B_    64
#define CIN_  3
#define HW_   64
#define HID_  128
#define K_    1024
#define H1_   31      // after conv1 (stride2 k4)
#define H2_   30      // after conv2 (stride1 k2)
#define NROWS_ 57600  // B_*H2_*H2_
#define NELEM_ 7372800

typedef __bf16 bf16_t;
typedef __attribute__((ext_vector_type(8))) __bf16 bf16x8;
typedef __attribute__((ext_vector_type(4))) float f32x4;

// ---------------- conv1: x[64,3,64,64] -> relu -> z1p[64,128,32,32] (padded)
__global__ __launch_bounds__(256) void conv1_k(const float* __restrict__ x,
    const float* __restrict__ w, const float* __restrict__ bias,
    float* __restrict__ z1p) {
  int blk = blockIdx.x, b = blk >> 7, co = blk & 127;     // grid = 64*128
  const float* wp = w + co * 48;                          // [co][ci][4][4]
  float wr[48];
  #pragma unroll
  for (int i = 0; i < 48; ++i) wr[i] = wp[i];             // uniform -> SGPRs
  const float* xb = x + (size_t)b * CIN_ * HW_ * HW_;
  float* zb = z1p + ((size_t)blk << 10);                  // 32x32 padded plane
  float bv = bias[co];
  for (int j = threadIdx.x; j < H1_ * H1_; j += 256) {
    int oh = j / H1_, ow = j % H1_;
    float acc = bv;
    #pragma unroll
    for (int ci = 0; ci < CIN_; ++ci) {
      const float* xp = xb + ci * HW_ * HW_ + (oh * 2) * HW_ + ow * 2;
      #pragma unroll
      for (int kh = 0; kh < 4; ++kh)
        #pragma unroll
        for (int kw = 0; kw < 4; ++kw)
          acc += xp[kh * HW_ + kw] * wr[ci * 16 + kh * 4 + kw];
    }
    zb[(oh << 5) + ow] = fmaxf(acc, 0.f);                 // pad never read
  }
}

// ---------------- tz: z1p fp32 [b*128][1024] -> z1t bf16 [b][1024][128] -----
__global__ __launch_bounds__(256) void tz_k(const float* __restrict__ z1p,
    bf16_t* __restrict__ z1t) {
  __shared__ bf16_t t[64 * 136];
  int b = blockIdx.x >> 4, pc = blockIdx.x & 15;          // 64-pos chunk
  int tid = threadIdx.x;
  const float4* src = (const float4*)z1p;
  #pragma unroll
  for (int s = 0; s < 8; ++s) {
    int f = s * 256 + tid;                                // 2048 f4s
    int ci = f >> 4, c16 = f & 15;
    float4 v = src[(size_t)(b * HID_ + ci) * 256 + pc * 16 + c16];
    t[(c16 * 4 + 0) * 136 + ci] = (bf16_t)v.x;
    t[(c16 * 4 + 1) * 136 + ci] = (bf16_t)v.y;
    t[(c16 * 4 + 2) * 136 + ci] = (bf16_t)v.z;
    t[(c16 * 4 + 3) * 136 + ci] = (bf16_t)v.w;
  }
  __syncthreads();
  #pragma unroll
  for (int s = 0; s < 4; ++s) {
    int f = s * 256 + tid;                                // 1024 f4s out
    int pos = f >> 4, c16 = f & 15;
    *(float4*)&z1t[((size_t)b * 1024 + pc * 64 + pos) * 128 + c16 * 8] =
        *(float4*)&t[pos * 136 + c16 * 8];
  }
}

// ---------------- wprep: bf16 weight transposes -----------------------------
// wc2[t][co][ci] = ew2[co][ci][t]; wd1[t][co][ci] = dw1[ci][co][3-t]
__global__ __launch_bounds__(256) void wprep_k(const float* __restrict__ ew2,
    const float* __restrict__ dw1, bf16_t* __restrict__ wc2,
    bf16_t* __restrict__ wd1) {
  int id = blockIdx.x * 256 + threadIdx.x;                // grid 256 -> 65536
  int t = id >> 14, co = (id >> 7) & 127, ci = id & 127;
  wc2[id] = (bf16_t)ew2[(co * 128 + ci) * 4 + t];
  wd1[id] = (bf16_t)dw1[(ci * 128 + co) * 4 + (3 - t)];
}

// ---------------- conv2 (MFMA): z1t -> relu -> z fp32 + zbuf bf16 -----------
__global__ __launch_bounds__(256, 2) void conv2m_k(const bf16_t* __restrict__ z1t,
    const bf16_t* __restrict__ wc2, const float* __restrict__ bias,
    float* __restrict__ z, ushort* __restrict__ zbuf) {
  __shared__ __align__(16) bf16_t as_[128 * 136];         // 34.8 KB
  int blk = blockIdx.x;                                   // 64*15
  int b = blk / 15, rt = blk % 15;
  int tid = threadIdx.x, wv = tid >> 6, ln = tid & 63;
  const float4* src = (const float4*)(z1t + ((size_t)b * 1024 + rt * 64) * 128);
  #pragma unroll
  for (int s = 0; s < 8; ++s) {
    int f = s * 256 + tid;                                // 2048 f4 = 32 KB
    int lp = f >> 4, c16 = f & 15;
    *(float4*)&as_[lp * 136 + c16 * 8] = src[f];
  }
  __syncthreads();
  int m = wv * 16 + (ln & 15), q = ln >> 4;
  f32x4 acc8[8];
  #pragma unroll
  for (int c = 0; c < 8; ++c) acc8[c] = (f32x4){0.f, 0.f, 0.f, 0.f};
  #pragma unroll
  for (int t = 0; t < 4; ++t) {
    int off = (t >> 1) * 32 + (t & 1);                    // tap offset in pos
    bf16x8 af[4];
    #pragma unroll
    for (int kk = 0; kk < 4; ++kk)
      af[kk] = *(const bf16x8*)&as_[(m + off) * 136 + kk * 32 + q * 8];
    #pragma unroll
    for (int cot = 0; cot < 8; ++cot) {
      const bf16_t* wp = wc2 + (size_t)(t * 128 + cot * 16 + (ln & 15)) * 128
                         + q * 8;
      #pragma unroll
      for (int kk = 0; kk < 4; ++kk) {
        bf16x8 bf = *(const bf16x8*)(wp + kk * 32);
        acc8[cot] = __builtin_amdgcn_mfma_f32_16x16x32_bf16(af[kk], bf,
                                                            acc8[cot], 0, 0, 0);
      }
    }
  }
  #pragma unroll
  for (int cot = 0; cot < 8; ++cot) {
    int co = cot * 16 + (ln & 15);
    float bv = bias[co];
    #pragma unroll
    for (int r = 0; r < 4; ++r) {
      int mo = wv * 16 + q * 4 + r;
      int ocol = mo & 31;
      if (ocol < 30) {
        int orow = rt * 2 + (mo >> 5);                    // always < 30
        float v = fmaxf(acc8[cot][r] + bv, 0.f);
        size_t idx = (size_t)(b * HID_ + co) * 900 + orow * 30 + ocol;
        z[idx] = v;
        bf16_t h = (bf16_t)v;
        zbuf[idx] = *(ushort*)&h;                         // fused cvt for vq1
      }
    }
  }
}

// ---------------- prep: cb -> bf16 copy + bf16-consistent norms + zeros -----
__global__ __launch_bounds__(256) void prep_k(const float* __restrict__ cb,
    bf16_t* __restrict__ cbb, float* __restrict__ cnorm,
    unsigned* __restrict__ hist, float* __restrict__ sse) {
  int k = blockIdx.x * 256 + threadIdx.x;
  if (k < K_) {
    float s0 = 0.f;
    for (int d = 0; d < HID_; d += 4) {
      float4 v = *(const float4*)&cb[k * HID_ + d];
      bf16_t t[4] = {(bf16_t)v.x, (bf16_t)v.y, (bf16_t)v.z, (bf16_t)v.w};
      *(ushort4*)&((ushort*)cbb)[k * HID_ + d] = *(ushort4*)t;
      float f0 = (float)t[0], f1 = (float)t[1];
      float f2 = (float)t[2], f3 = (float)t[3];
      s0 += f0 * f0 + f1 * f1 + f2 * f2 + f3 * f3;
    }
    cnorm[k] = s0;
    hist[k] = 0u;
  }
  if (k == 0 && blockIdx.x == 0) *sse = 0.f;
}

__global__ __launch_bounds__(256) void zero_k(float4* __restrict__ p, int n4) {
  int i = blockIdx.x * 256 + threadIdx.x;
  if (i < n4) p[i] = make_float4(0.f, 0.f, 0.f, 0.f);
}

// ---------------- VQ phase 1 (MFMA): 64 rows x 1024 codes + hist ------------
__global__ __launch_bounds__(256) void vq1_k(const bf16_t* __restrict__ zb,
    const bf16_t* __restrict__ cbb, const float* __restrict__ cnorm,
    int* __restrict__ idxArr, unsigned* __restrict__ hist) {
  __shared__ __align__(16) bf16_t zs[64 * 136];           // 17 KB
  __shared__ __align__(16) bf16_t cbs[128 * 136];         // 34 KB
  __shared__ unsigned long long red[64 * 16];             // 8 KB
  int n0 = blockIdx.x * 64;                               // 900 blocks
  int tid = threadIdx.x;
  int wv = tid >> 6, ln = tid & 63;
  {
    const float4* zg4 = (const float4*)(zb + (size_t)n0 * HID_);
    #pragma unroll
    for (int s = 0; s < 4; ++s) {
      int f = s * 256 + tid;
      int row = f >> 4, seg = f & 15;
      *(float4*)&zs[row * 136 + seg * 8] = zg4[f];
    }
  }
  __syncthreads();
  bf16x8 afr[4];
  #pragma unroll
  for (int kk = 0; kk < 4; ++kk)
    afr[kk] = *(const bf16x8*)&zs[(wv * 16 + (ln & 15)) * 136 + kk * 32 +
                                  (ln >> 4) * 8];
  unsigned long long best[4] = {~0ull, ~0ull, ~0ull, ~0ull};
  const float4* cg4 = (const float4*)cbb;
  for (int c0 = 0; c0 < K_; c0 += 128) {
    __syncthreads();
    #pragma unroll
    for (int s = 0; s < 8; ++s) {
      int f = s * 256 + tid;
      int code = f >> 4, seg = f & 15;
      *(float4*)&cbs[code * 136 + seg * 8] = cg4[(c0 + code) * 16 + seg];
    }
    __syncthreads();
    #pragma unroll 2
    for (int t = 0; t < 8; ++t) {
      f32x4 acc = {0.f, 0.f, 0.f, 0.f};
      #pragma unroll
      for (int kk = 0; kk < 4; ++kk) {
        bf16x8 bfr = *(const bf16x8*)&cbs[(t * 16 + (ln & 15)) * 136 +
                                          kk * 32 + (ln >> 4) * 8];
        acc = __builtin_amdgcn_mfma_f32_16x16x32_bf16(afr[kk], bfr, acc,
                                                      0, 0, 0);
      }
      int code = c0 + t * 16 + (ln & 15);
      float cn = cnorm[code];
      #pragma unroll
      for (int r = 0; r < 4; ++r) {
        float dist = cn - 2.f * acc[r];
        unsigned u = __float_as_uint(dist);
        u = (u & 0x80000000u) ? ~u : (u | 0x80000000u);
        unsigned long long p = ((unsigned long long)u << 32) | (unsigned)code;
        if (p < best[r]) best[r] = p;
      }
    }
  }
  __syncthreads();
  #pragma unroll
  for (int r = 0; r < 4; ++r)
    red[(wv * 16 + (ln >> 4) * 4 + r) * 16 + (ln & 15)] = best[r];
  __syncthreads();
  if (tid < 64) {
    unsigned long long b = ~0ull;
    #pragma unroll
    for (int c = 0; c < 16; ++c) {
      unsigned long long p = red[tid * 16 + c];
      if (p < b) b = p;
    }
    int bi = (int)(b & 0xffffffffu);
    idxArr[n0 + tid] = bi;
    atomicAdd(&hist[bi], 1u);                             // hist fused here
  }
}

// ---------------- tq: gather cbb rows -> qt bf16 [b][pos][ci], coalesced ----
// replaces the r9 vq3 scatter (262 MB write-amplification -> ~17 MB).
__global__ __launch_bounds__(256) void tq_k(const bf16_t* __restrict__ cbb,
    const int* __restrict__ idxArr, ushort* __restrict__ qt) {
  __shared__ ushort t[60 * 128];                          // 15 KB
  int b = blockIdx.x / 15, st = blockIdx.x % 15;          // 60-s tile
  int tid = threadIdx.x;
  int s0 = st * 60;
  #pragma unroll
  for (int it = 0; it < 8; ++it) {
    int task = it * 256 + tid;                            // sc*128 + c
    if (task < 1920) {
      int sc = task >> 7, c = task & 127;
      int f = b * 115200 + c * 900 + s0 + sc * 4;
      int n = f >> 7, d = f & 127;                        // d%4==0, no wrap
      int k = idxArr[n];
      ushort4 v = *(const ushort4*)((const ushort*)cbb + k * 128 + d);
      t[(sc * 4 + 0) * 128 + c] = v.x;
      t[(sc * 4 + 1) * 128 + c] = v.y;
      t[(sc * 4 + 2) * 128 + c] = v.z;
      t[(sc * 4 + 3) * 128 + c] = v.w;
    }
  }
  __syncthreads();
  #pragma unroll
  for (int it = 0; it < 4; ++it) {
    int task = it * 256 + tid;                            // sl*16 + c16
    if (task < 960) {
      int sl = task >> 4, c16 = task & 15;
      int s = s0 + sl;
      int h = s / 30, w = s - h * 30;
      int p = (h + 1) * 32 + (w + 1);
      *(uint4*)&qt[((size_t)(b * 1024 + p)) * 128 + c16 * 8] =
          *(uint4*)&t[sl * 128 + c16 * 8];
    }
  }
}

// ---------------- sse: elementwise fp32 SSE over flat f, coalesced ----------
__global__ __launch_bounds__(256) void sse_k(const float4* __restrict__ z4,
    const float* __restrict__ cb, const int* __restrict__ idxArr,
    float* __restrict__ sse) {
  int i = blockIdx.x * 256 + threadIdx.x;                 // 7200*256 = exact
  int f = i * 4;
  int n = f >> 7, d = f & 127;
  int k = idxArr[n];
  float4 zv = z4[i];
  float4 cv = *(const float4*)&cb[k * 128 + d];
  float dx = cv.x - zv.x, dy = cv.y - zv.y;
  float dz = cv.z - zv.z, dw = cv.w - zv.w;
  float se = dx * dx + dy * dy + dz * dz + dw * dw;
  __shared__ float red[256];
  red[threadIdx.x] = se;
  __syncthreads();
  #pragma unroll
  for (int t = 128; t > 0; t >>= 1) {
    if (threadIdx.x < t) red[threadIdx.x] += red[threadIdx.x + t];
    __syncthreads();
  }
  if (threadIdx.x == 0) atomicAdd(sse, red[0]);
}

// ---------------- convT1 (MFMA): qt -> relu -> yp fp32 [co][33x33] ----------
__global__ __launch_bounds__(256, 2) void convt1m_k(const bf16_t* __restrict__ qt,
    const bf16_t* __restrict__ wd1, const float* __restrict__ bias,
    float* __restrict__ yp) {
  __shared__ __align__(16) bf16_t as_[128 * 136];
  int blk = blockIdx.x;                                   // 64*16
  int b = blk >> 4, rt = blk & 15;
  int tid = threadIdx.x, wv = tid >> 6, ln = tid & 63;
  const float4* src = (const float4*)(qt + ((size_t)b * 1024 + rt * 64) * 128);
  #pragma unroll
  for (int s = 0; s < 8; ++s) {
    int f = s * 256 + tid;
    int lp = f >> 4, c16 = f & 15;
    *(float4*)&as_[lp * 136 + c16 * 8] = src[f];          // rt=15 reads slack
  }
  __syncthreads();
  int m = wv * 16 + (ln & 15), q = ln >> 4;
  f32x4 acc8[8];
  #pragma unroll
  for (int c = 0; c < 8; ++c) acc8[c] = (f32x4){0.f, 0.f, 0.f, 0.f};
  #pragma unroll
  for (int t = 0; t < 4; ++t) {
    int off = (t >> 1) * 32 + (t & 1);
    bf16x8 af[4];
    #pragma unroll
    for (int kk = 0; kk < 4; ++kk)
      af[kk] = *(const bf16x8*)&as_[(m + off) * 136 + kk * 32 + q * 8];
    #pragma unroll
    for (int cot = 0; cot < 8; ++cot) {
      const bf16_t* wp = wd1 + (size_t)(t * 128 + cot * 16 + (ln & 15)) * 128
                         + q * 8;
      #pragma unroll
      for (int kk = 0; kk < 4; ++kk) {
        bf16x8 bf = *(const bf16x8*)(wp + kk * 32);
        acc8[cot] = __builtin_amdgcn_mfma_f32_16x16x32_bf16(af[kk], bf,
                                                            acc8[cot], 0, 0, 0);
      }
    }
  }
  #pragma unroll
  for (int cot = 0; cot < 8; ++cot) {
    int co = cot * 16 + (ln & 15);
    float bv = bias[co];
    #pragma unroll
    for (int r = 0; r < 4; ++r) {
      int mo = wv * 16 + q * 4 + r;
      int orow = rt * 2 + (mo >> 5), ocol = mo & 31;
      if (orow < 31 && ocol < 31) {
        float v = fmaxf(acc8[cot][r] + bv, 0.f);
        yp[(size_t)(b * HID_ + co) * 1089 + (orow + 1) * 33 + (ocol + 1)] = v;
      }
    }
  }
}

// ---------------- convT2: yp[64,128,33,33] -> x_recon[64,3,64,64] -----------
__global__ __launch_bounds__(256) void convt2_k(const float* __restrict__ yp,
    const float* __restrict__ w, const float* __restrict__ bias,
    float* __restrict__ out) {
  int bc = blockIdx.x;                      // b*3 + co, 0..191
  int co = bc % 3, b = bc / 3;
  int yq = blockIdx.y;                      // 0..15
  int ph = (yq >> 1) & 1, pw = yq & 1, qg = yq >> 2;
  int i = qg * 256 + threadIdx.x;           // 0..1023 over 32x32 quadrant
  int qh = i >> 5, qw = i & 31;
  int oh = qh * 2 + ph, ow = qw * 2 + pw;
  int base = (qh + 1) * 33 + qw + 1;
  const float* yb = yp + (size_t)b * HID_ * 1089;
  const float* wp0 = w + co * 16 + ph * 4 + pw;   // + ci*48, block-uniform
  float acc = bias[co];
  for (int ci = 0; ci < HID_; ++ci) {
    const float* yr = yb + ci * 1089;
    const float* wp = wp0 + ci * 48;
    acc += yr[base]      * wp[0]
         + yr[base - 1]  * wp[2]
         + yr[base - 33] * wp[8]
         + yr[base - 34] * wp[10];
  }
  out[(size_t)bc * 4096 + oh * 64 + ow] = acc;
}

// ---------------- finalize: loss + perplexity -------------------------------
__global__ __launch_bounds__(256) void fin_k(const unsigned* __restrict__ hist,
    const float* __restrict__ sse, float* __restrict__ out) {
  __shared__ float red[256];
  float e = 0.f;
  for (int k = threadIdx.x; k < K_; k += 256) {
    float p = (float)hist[k] * (1.0f / (float)NROWS_);
    e += p * logf(p + 1e-10f);
  }
  red[threadIdx.x] = e;
  __syncthreads();
  #pragma unroll
  for (int t = 128; t > 0; t >>= 1) {
    if (threadIdx.x < t) red[threadIdx.x] += red[threadIdx.x + t];
    __syncthreads();
  }
  if (threadIdx.x == 0) {
    out[786432] = 1.25f * (*sse) * (1.0f / (float)NELEM_);
    out[786433] = expf(-red[0]);
  }
}

extern "C" void kernel_launch(void* const* d_in, const int* in_sizes, int n_in,
                              void* d_out, int out_size, void* d_ws,
                              size_t ws_size, hipStream_t stream) {
  (void)in_sizes; (void)n_in; (void)out_size; (void)ws_size;
  const float* x   = (const float*)d_in[0];
  const float* ew1 = (const float*)d_in[1];
  const float* eb1 = (const float*)d_in[2];
  const float* ew2 = (const float*)d_in[3];
  const float* eb2 = (const float*)d_in[4];
  const float* cb  = (const float*)d_in[5];
  const float* dw1 = (const float*)d_in[6];
  const float* db1 = (const float*)d_in[7];
  const float* dw2 = (const float*)d_in[8];
  const float* db2 = (const float*)d_in[9];
  float* out = (float*)d_out;
  char* ws = (char*)d_ws;

  // ws layout (~97.5 MB, aliased by liveness):
  //  [0, 35,684,352)            z1p (conv1->tz) then yp (zeroed, convt1m->convt2)
  //  [35,684,352, 65,175,552)   z fp32 (conv2m->sse)
  //  [65,175,552, 81,985,536)   z1t bf16 +slack (tz->conv2m) then qt bf16
  //  [81,985,536, 96,731,136)   zbuf bf16 (conv2m->vq1)
  //  [96,731,136 ..)            cbb | wc2 | wd1 | idxArr | hist | cnorm | sse
  float*    z1p   = (float*)(ws);
  float*    yp    = (float*)(ws);
  float*    z     = (float*)(ws + 35684352);
  bf16_t*   z1t   = (bf16_t*)(ws + 65175552);
  bf16_t*   qt    = (bf16_t*)(ws + 65175552);
  ushort*   zbuf  = (ushort*)(ws + 81985536);
  bf16_t*   cbb   = (bf16_t*)(ws + 96731136);
  bf16_t*   wc2   = (bf16_t*)(ws + 96993280);
  bf16_t*   wd1   = (bf16_t*)(ws + 97124352);
  int*      idxArr= (int*)(ws + 97255424);
  unsigned* hist  = (unsigned*)(ws + 97485824);
  float*    cnorm = (float*)(ws + 97489920);
  float*    sse   = (float*)(ws + 97494016);

  conv1_k<<<dim3(B_ * HID_), dim3(256), 0, stream>>>(x, ew1, eb1, z1p);
  tz_k<<<dim3(1024), dim3(256), 0, stream>>>(z1p, z1t);
  wprep_k<<<dim3(256), dim3(256), 0, stream>>>(ew2, dw1, wc2, wd1);
  conv2m_k<<<dim3(960), dim3(256), 0, stream>>>(z1t, wc2, eb2, z, zbuf);
  prep_k<<<dim3(4), dim3(256), 0, stream>>>(cb, cbb, cnorm, hist, sse);
  vq1_k<<<dim3(900), dim3(256), 0, stream>>>((const bf16_t*)zbuf, cbb, cnorm,
                                             idxArr, hist);
  zero_k<<<dim3(4104), dim3(256), 0, stream>>>((float4*)qt, 1050624);
  tq_k<<<dim3(960), dim3(256), 0, stream>>>(cbb, idxArr, (ushort*)qt);
  sse_k<<<dim3(7200), dim3(256), 0, stream>>>((const float4*)z, cb, idxArr,
                                              sse);
  zero_k<<<dim3(8713), dim3(256), 0, stream>>>((float4*)yp, 2230272);
  convt1m_k<<<dim3(1024), dim3(256), 0, stream>>>(qt, wd1, db1, yp);
  convt2_k<<<dim3(192, 16), dim3(256), 0, stream>>>(yp, dw2, db2, out);
  fin_k<<<dim3(1), dim3(256), 0, stream>>>(hist, sse, out);
}

// Round 11
// 471.575 us; speedup vs baseline: 2.5898x; 1.1649x over previous
//
#include <hip/hip_runtime.h>

#define B_    64
#define CIN_  3
#define HW_   64
#define HID_  128
#define K_    1024
#define H1_   31      // after conv1 (stride2 k4)
#define H2_   30      // after conv2 (stride1 k2)
#define NROWS_ 57600  // B_*H2_*H2_
#define NELEM_ 7372800

typedef __bf16 bf16_t;
typedef __attribute__((ext_vector_type(8))) __bf16 bf16x8;
typedef __attribute__((ext_vector_type(4))) float f32x4;

// ---------------- conv1: x[64,3,64,64] -> relu -> z1p[64,128,32,32] (padded)
__global__ __launch_bounds__(256) void conv1_k(const float* __restrict__ x,
    const float* __restrict__ w, const float* __restrict__ bias,
    float* __restrict__ z1p) {
  int blk = blockIdx.x, b = blk >> 7, co = blk & 127;     // grid = 64*128
  const float* wp = w + co * 48;                          // [co][ci][4][4]
  float wr[48];
  #pragma unroll
  for (int i = 0; i < 48; ++i) wr[i] = wp[i];             // uniform -> SGPRs
  const float* xb = x + (size_t)b * CIN_ * HW_ * HW_;
  float* zb = z1p + ((size_t)blk << 10);                  // 32x32 padded plane
  float bv = bias[co];
  for (int j = threadIdx.x; j < H1_ * H1_; j += 256) {
    int oh = j / H1_, ow = j % H1_;
    float acc = bv;
    #pragma unroll
    for (int ci = 0; ci < CIN_; ++ci) {
      const float* xp = xb + ci * HW_ * HW_ + (oh * 2) * HW_ + ow * 2;
      #pragma unroll
      for (int kh = 0; kh < 4; ++kh)
        #pragma unroll
        for (int kw = 0; kw < 4; ++kw)
          acc += xp[kh * HW_ + kw] * wr[ci * 16 + kh * 4 + kw];
    }
    zb[(oh << 5) + ow] = fmaxf(acc, 0.f);                 // pad never read
  }
}

// ---------------- tz: z1p fp32 [b*128][1024] -> z1t bf16 [b][1024][128] -----
__global__ __launch_bounds__(256) void tz_k(const float* __restrict__ z1p,
    bf16_t* __restrict__ z1t) {
  __shared__ bf16_t t[64 * 136];
  int b = blockIdx.x >> 4, pc = blockIdx.x & 15;          // 64-pos chunk
  int tid = threadIdx.x;
  const float4* src = (const float4*)z1p;
  #pragma unroll
  for (int s = 0; s < 8; ++s) {
    int f = s * 256 + tid;                                // 2048 f4s
    int ci = f >> 4, c16 = f & 15;
    float4 v = src[(size_t)(b * HID_ + ci) * 256 + pc * 16 + c16];
    t[(c16 * 4 + 0) * 136 + ci] = (bf16_t)v.x;
    t[(c16 * 4 + 1) * 136 + ci] = (bf16_t)v.y;
    t[(c16 * 4 + 2) * 136 + ci] = (bf16_t)v.z;
    t[(c16 * 4 + 3) * 136 + ci] = (bf16_t)v.w;
  }
  __syncthreads();
  #pragma unroll
  for (int s = 0; s < 4; ++s) {
    int f = s * 256 + tid;                                // 1024 f4s out
    int pos = f >> 4, c16 = f & 15;
    *(float4*)&z1t[((size_t)b * 1024 + pc * 64 + pos) * 128 + c16 * 8] =
        *(float4*)&t[pos * 136 + c16 * 8];
  }
}

// ---------------- wprep: bf16 weight transposes -----------------------------
// wc2[t][co][ci] = ew2[co][ci][t]; wd1[t][co][ci] = dw1[ci][co][3-t]
__global__ __launch_bounds__(256) void wprep_k(const float* __restrict__ ew2,
    const float* __restrict__ dw1, bf16_t* __restrict__ wc2,
    bf16_t* __restrict__ wd1) {
  int id = blockIdx.x * 256 + threadIdx.x;                // grid 256 -> 65536
  int t = id >> 14, co = (id >> 7) & 127, ci = id & 127;
  wc2[id] = (bf16_t)ew2[(co * 128 + ci) * 4 + t];
  wd1[id] = (bf16_t)dw1[(ci * 128 + co) * 4 + (3 - t)];
}

// ---------------- conv2 (MFMA): z1t -> relu -> z fp32 + zbuf bf16 -----------
__global__ __launch_bounds__(256, 2) void conv2m_k(const bf16_t* __restrict__ z1t,
    const bf16_t* __restrict__ wc2, const float* __restrict__ bias,
    float* __restrict__ z, ushort* __restrict__ zbuf) {
  __shared__ __align__(16) bf16_t as_[128 * 136];         // 34.8 KB
  int blk = blockIdx.x;                                   // 64*15
  int b = blk / 15, rt = blk % 15;
  int tid = threadIdx.x, wv = tid >> 6, ln = tid & 63;
  const float4* src = (const float4*)(z1t + ((size_t)b * 1024 + rt * 64) * 128);
  #pragma unroll
  for (int s = 0; s < 8; ++s) {
    int f = s * 256 + tid;                                // 2048 f4 = 32 KB
    int lp = f >> 4, c16 = f & 15;
    *(float4*)&as_[lp * 136 + c16 * 8] = src[f];
  }
  __syncthreads();
  int m = wv * 16 + (ln & 15), q = ln >> 4;
  f32x4 acc8[8];
  #pragma unroll
  for (int c = 0; c < 8; ++c) acc8[c] = (f32x4){0.f, 0.f, 0.f, 0.f};
  #pragma unroll
  for (int t = 0; t < 4; ++t) {
    int off = (t >> 1) * 32 + (t & 1);                    // tap offset in pos
    bf16x8 af[4];
    #pragma unroll
    for (int kk = 0; kk < 4; ++kk)
      af[kk] = *(const bf16x8*)&as_[(m + off) * 136 + kk * 32 + q * 8];
    #pragma unroll
    for (int cot = 0; cot < 8; ++cot) {
      const bf16_t* wp = wc2 + (size_t)(t * 128 + cot * 16 + (ln & 15)) * 128
                         + q * 8;
      #pragma unroll
      for (int kk = 0; kk < 4; ++kk) {
        bf16x8 bf = *(const bf16x8*)(wp + kk * 32);
        acc8[cot] = __builtin_amdgcn_mfma_f32_16x16x32_bf16(af[kk], bf,
                                                            acc8[cot], 0, 0, 0);
      }
    }
  }
  #pragma unroll
  for (int cot = 0; cot < 8; ++cot) {
    int co = cot * 16 + (ln & 15);
    float bv = bias[co];
    #pragma unroll
    for (int r = 0; r < 4; ++r) {
      int mo = wv * 16 + q * 4 + r;
      int ocol = mo & 31;
      if (ocol < 30) {
        int orow = rt * 2 + (mo >> 5);                    // always < 30
        float v = fmaxf(acc8[cot][r] + bv, 0.f);
        size_t idx = (size_t)(b * HID_ + co) * 900 + orow * 30 + ocol;
        z[idx] = v;
        bf16_t h = (bf16_t)v;
        zbuf[idx] = *(ushort*)&h;                         // fused cvt for vq1
      }
    }
  }
}

// ---------------- prep: cb -> bf16 copy + bf16-consistent norms + zeros -----
__global__ __launch_bounds__(256) void prep_k(const float* __restrict__ cb,
    bf16_t* __restrict__ cbb, float* __restrict__ cnorm,
    unsigned* __restrict__ hist, float* __restrict__ sse) {
  int k = blockIdx.x * 256 + threadIdx.x;
  if (k < K_) {
    float s0 = 0.f;
    for (int d = 0; d < HID_; d += 4) {
      float4 v = *(const float4*)&cb[k * HID_ + d];
      bf16_t t[4] = {(bf16_t)v.x, (bf16_t)v.y, (bf16_t)v.z, (bf16_t)v.w};
      *(ushort4*)&((ushort*)cbb)[k * HID_ + d] = *(ushort4*)t;
      float f0 = (float)t[0], f1 = (float)t[1];
      float f2 = (float)t[2], f3 = (float)t[3];
      s0 += f0 * f0 + f1 * f1 + f2 * f2 + f3 * f3;
    }
    cnorm[k] = s0;
    hist[k] = 0u;
  }
  if (k == 0 && blockIdx.x == 0) *sse = 0.f;
}

__global__ __launch_bounds__(256) void zero_k(float4* __restrict__ p, int n4) {
  int i = blockIdx.x * 256 + threadIdx.x;
  if (i < n4) p[i] = make_float4(0.f, 0.f, 0.f, 0.f);
}

// ---------------- VQ phase 1 (MFMA): 64 rows x 1024 codes + hist ------------
__global__ __launch_bounds__(256) void vq1_k(const bf16_t* __restrict__ zb,
    const bf16_t* __restrict__ cbb, const float* __restrict__ cnorm,
    int* __restrict__ idxArr, unsigned* __restrict__ hist) {
  __shared__ __align__(16) bf16_t zs[64 * 136];           // 17 KB
  __shared__ __align__(16) bf16_t cbs[128 * 136];         // 34 KB
  __shared__ unsigned long long red[64 * 16];             // 8 KB
  int n0 = blockIdx.x * 64;                               // 900 blocks
  int tid = threadIdx.x;
  int wv = tid >> 6, ln = tid & 63;
  {
    const float4* zg4 = (const float4*)(zb + (size_t)n0 * HID_);
    #pragma unroll
    for (int s = 0; s < 4; ++s) {
      int f = s * 256 + tid;
      int row = f >> 4, seg = f & 15;
      *(float4*)&zs[row * 136 + seg * 8] = zg4[f];
    }
  }
  __syncthreads();
  bf16x8 afr[4];
  #pragma unroll
  for (int kk = 0; kk < 4; ++kk)
    afr[kk] = *(const bf16x8*)&zs[(wv * 16 + (ln & 15)) * 136 + kk * 32 +
                                  (ln >> 4) * 8];
  unsigned long long best[4] = {~0ull, ~0ull, ~0ull, ~0ull};
  const float4* cg4 = (const float4*)cbb;
  for (int c0 = 0; c0 < K_; c0 += 128) {
    __syncthreads();
    #pragma unroll
    for (int s = 0; s < 8; ++s) {
      int f = s * 256 + tid;
      int code = f >> 4, seg = f & 15;
      *(float4*)&cbs[code * 136 + seg * 8] = cg4[(c0 + code) * 16 + seg];
    }
    __syncthreads();
    #pragma unroll 2
    for (int t = 0; t < 8; ++t) {
      f32x4 acc = {0.f, 0.f, 0.f, 0.f};
      #pragma unroll
      for (int kk = 0; kk < 4; ++kk) {
        bf16x8 bfr = *(const bf16x8*)&cbs[(t * 16 + (ln & 15)) * 136 +
                                          kk * 32 + (ln >> 4) * 8];
        acc = __builtin_amdgcn_mfma_f32_16x16x32_bf16(afr[kk], bfr, acc,
                                                      0, 0, 0);
      }
      int code = c0 + t * 16 + (ln & 15);
      float cn = cnorm[code];
      #pragma unroll
      for (int r = 0; r < 4; ++r) {
        float dist = cn - 2.f * acc[r];
        unsigned u = __float_as_uint(dist);
        u = (u & 0x80000000u) ? ~u : (u | 0x80000000u);
        unsigned long long p = ((unsigned long long)u << 32) | (unsigned)code;
        if (p < best[r]) best[r] = p;
      }
    }
  }
  __syncthreads();
  #pragma unroll
  for (int r = 0; r < 4; ++r)
    red[(wv * 16 + (ln >> 4) * 4 + r) * 16 + (ln & 15)] = best[r];
  __syncthreads();
  if (tid < 64) {
    unsigned long long b = ~0ull;
    #pragma unroll
    for (int c = 0; c < 16; ++c) {
      unsigned long long p = red[tid * 16 + c];
      if (p < b) b = p;
    }
    int bi = (int)(b & 0xffffffffu);
    idxArr[n0 + tid] = bi;
    atomicAdd(&hist[bi], 1u);                             // hist fused here
  }
}

// ---------------- tq: gather cbb rows -> qt bf16 [b][pos][ci], coalesced ----
__global__ __launch_bounds__(256) void tq_k(const bf16_t* __restrict__ cbb,
    const int* __restrict__ idxArr, ushort* __restrict__ qt) {
  __shared__ ushort t[60 * 128];                          // 15 KB
  int b = blockIdx.x / 15, st = blockIdx.x % 15;          // 60-s tile
  int tid = threadIdx.x;
  int s0 = st * 60;
  #pragma unroll
  for (int it = 0; it < 8; ++it) {
    int task = it * 256 + tid;                            // sc*128 + c
    if (task < 1920) {
      int sc = task >> 7, c = task & 127;
      int f = b * 115200 + c * 900 + s0 + sc * 4;
      int n = f >> 7, d = f & 127;                        // d%4==0, no wrap
      int k = idxArr[n];
      ushort4 v = *(const ushort4*)((const ushort*)cbb + k * 128 + d);
      t[(sc * 4 + 0) * 128 + c] = v.x;
      t[(sc * 4 + 1) * 128 + c] = v.y;
      t[(sc * 4 + 2) * 128 + c] = v.z;
      t[(sc * 4 + 3) * 128 + c] = v.w;
    }
  }
  __syncthreads();
  #pragma unroll
  for (int it = 0; it < 4; ++it) {
    int task = it * 256 + tid;                            // sl*16 + c16
    if (task < 960) {
      int sl = task >> 4, c16 = task & 15;
      int s = s0 + sl;
      int h = s / 30, w = s - h * 30;
      int p = (h + 1) * 32 + (w + 1);
      *(uint4*)&qt[((size_t)(b * 1024 + p)) * 128 + c16 * 8] =
          *(uint4*)&t[sl * 128 + c16 * 8];
    }
  }
}

// ---------------- sse: fp32 SSE, 8 float4/thread, wave-shuffle reduce -------
// r10's 7200-tiny-block version was latency/atomic-bound (95 us, VALUBusy
// 1.3%): 1 f4/thread, 8 barriers, 7200 same-address atomics. Now: 900 blocks,
// 8 independent load chains/thread (ILP), 1 barrier, 900 atomics.
__global__ __launch_bounds__(256) void sse_k(const float4* __restrict__ z4,
    const float* __restrict__ cb, const int* __restrict__ idxArr,
    float* __restrict__ sse) {
  int base = blockIdx.x * 2048 + threadIdx.x;             // 900 blocks exact
  float se = 0.f;
  #pragma unroll
  for (int it = 0; it < 8; ++it) {
    int i = base + it * 256;
    int f = i * 4;
    int n = f >> 7, d = f & 127;
    int k = idxArr[n];
    float4 zv = z4[i];
    float4 cv = *(const float4*)&cb[k * 128 + d];
    float dx = cv.x - zv.x, dy = cv.y - zv.y;
    float dz = cv.z - zv.z, dw = cv.w - zv.w;
    se += dx * dx + dy * dy + dz * dz + dw * dw;
  }
  #pragma unroll
  for (int o = 32; o > 0; o >>= 1) se += __shfl_down(se, o, 64);
  __shared__ float red[4];
  if ((threadIdx.x & 63) == 0) red[threadIdx.x >> 6] = se;
  __syncthreads();
  if (threadIdx.x == 0)
    atomicAdd(sse, red[0] + red[1] + red[2] + red[3]);
}

// ---------------- convT1 (MFMA): qt -> relu -> yp fp32 [co][33x33] ----------
__global__ __launch_bounds__(256, 2) void convt1m_k(const bf16_t* __restrict__ qt,
    const bf16_t* __restrict__ wd1, const float* __restrict__ bias,
    float* __restrict__ yp) {
  __shared__ __align__(16) bf16_t as_[128 * 136];
  int blk = blockIdx.x;                                   // 64*16
  int b = blk >> 4, rt = blk & 15;
  int tid = threadIdx.x, wv = tid >> 6, ln = tid & 63;
  const float4* src = (const float4*)(qt + ((size_t)b * 1024 + rt * 64) * 128);
  #pragma unroll
  for (int s = 0; s < 8; ++s) {
    int f = s * 256 + tid;
    int lp = f >> 4, c16 = f & 15;
    *(float4*)&as_[lp * 136 + c16 * 8] = src[f];          // rt=15 reads slack
  }
  __syncthreads();
  int m = wv * 16 + (ln & 15), q = ln >> 4;
  f32x4 acc8[8];
  #pragma unroll
  for (int c = 0; c < 8; ++c) acc8[c] = (f32x4){0.f, 0.f, 0.f, 0.f};
  #pragma unroll
  for (int t = 0; t < 4; ++t) {
    int off = (t >> 1) * 32 + (t & 1);
    bf16x8 af[4];
    #pragma unroll
    for (int kk = 0; kk < 4; ++kk)
      af[kk] = *(const bf16x8*)&as_[(m + off) * 136 + kk * 32 + q * 8];
    #pragma unroll
    for (int cot = 0; cot < 8; ++cot) {
      const bf16_t* wp = wd1 + (size_t)(t * 128 + cot * 16 + (ln & 15)) * 128
                         + q * 8;
      #pragma unroll
      for (int kk = 0; kk < 4; ++kk) {
        bf16x8 bf = *(const bf16x8*)(wp + kk * 32);
        acc8[cot] = __builtin_amdgcn_mfma_f32_16x16x32_bf16(af[kk], bf,
                                                            acc8[cot], 0, 0, 0);
      }
    }
  }
  #pragma unroll
  for (int cot = 0; cot < 8; ++cot) {
    int co = cot * 16 + (ln & 15);
    float bv = bias[co];
    #pragma unroll
    for (int r = 0; r < 4; ++r) {
      int mo = wv * 16 + q * 4 + r;
      int orow = rt * 2 + (mo >> 5), ocol = mo & 31;
      if (orow < 31 && ocol < 31) {
        float v = fmaxf(acc8[cot][r] + bv, 0.f);
        yp[(size_t)(b * HID_ + co) * 1089 + (orow + 1) * 33 + (ocol + 1)] = v;
      }
    }
  }
}

// ---------------- convT2: yp[64,128,33,33] -> x_recon[64,3,64,64] -----------
__global__ __launch_bounds__(256) void convt2_k(const float* __restrict__ yp,
    const float* __restrict__ w, const float* __restrict__ bias,
    float* __restrict__ out) {
  int bc = blockIdx.x;                      // b*3 + co, 0..191
  int co = bc % 3, b = bc / 3;
  int yq = blockIdx.y;                      // 0..15
  int ph = (yq >> 1) & 1, pw = yq & 1, qg = yq >> 2;
  int i = qg * 256 + threadIdx.x;           // 0..1023 over 32x32 quadrant
  int qh = i >> 5, qw = i & 31;
  int oh = qh * 2 + ph, ow = qw * 2 + pw;
  int base = (qh + 1) * 33 + qw + 1;
  const float* yb = yp + (size_t)b * HID_ * 1089;
  const float* wp0 = w + co * 16 + ph * 4 + pw;   // + ci*48, block-uniform
  float acc = bias[co];
  for (int ci = 0; ci < HID_; ++ci) {
    const float* yr = yb + ci * 1089;
    const float* wp = wp0 + ci * 48;
    acc += yr[base]      * wp[0]
         + yr[base - 1]  * wp[2]
         + yr[base - 33] * wp[8]
         + yr[base - 34] * wp[10];
  }
  out[(size_t)bc * 4096 + oh * 64 + ow] = acc;
}

// ---------------- finalize: loss + perplexity -------------------------------
__global__ __launch_bounds__(256) void fin_k(const unsigned* __restrict__ hist,
    const float* __restrict__ sse, float* __restrict__ out) {
  __shared__ float red[256];
  float e = 0.f;
  for (int k = threadIdx.x; k < K_; k += 256) {
    float p = (float)hist[k] * (1.0f / (float)NROWS_);
    e += p * logf(p + 1e-10f);
  }
  red[threadIdx.x] = e;
  __syncthreads();
  #pragma unroll
  for (int t = 128; t > 0; t >>= 1) {
    if (threadIdx.x < t) red[threadIdx.x] += red[threadIdx.x + t];
    __syncthreads();
  }
  if (threadIdx.x == 0) {
    out[786432] = 1.25f * (*sse) * (1.0f / (float)NELEM_);
    out[786433] = expf(-red[0]);
  }
}

extern "C" void kernel_launch(void* const* d_in, const int* in_sizes, int n_in,
                              void* d_out, int out_size, void* d_ws,
                              size_t ws_size, hipStream_t stream) {
  (void)in_sizes; (void)n_in; (void)out_size; (void)ws_size;
  const float* x   = (const float*)d_in[0];
  const float* ew1 = (const float*)d_in[1];
  const float* eb1 = (const float*)d_in[2];
  const float* ew2 = (const float*)d_in[3];
  const float* eb2 = (const float*)d_in[4];
  const float* cb  = (const float*)d_in[5];
  const float* dw1 = (const float*)d_in[6];
  const float* db1 = (const float*)d_in[7];
  const float* dw2 = (const float*)d_in[8];
  const float* db2 = (const float*)d_in[9];
  float* out = (float*)d_out;
  char* ws = (char*)d_ws;

  // ws layout (~97.5 MB, aliased by liveness):
  //  [0, 35,684,352)            z1p (conv1->tz) then yp (zeroed, convt1m->convt2)
  //  [35,684,352, 65,175,552)   z fp32 (conv2m->sse)
  //  [65,175,552, 81,985,536)   z1t bf16 +slack (tz->conv2m) then qt bf16
  //  [81,985,536, 96,731,136)   zbuf bf16 (conv2m->vq1)
  //  [96,731,136 ..)            cbb | wc2 | wd1 | idxArr | hist | cnorm | sse
  float*    z1p   = (float*)(ws);
  float*    yp    = (float*)(ws);
  float*    z     = (float*)(ws + 35684352);
  bf16_t*   z1t   = (bf16_t*)(ws + 65175552);
  bf16_t*   qt    = (bf16_t*)(ws + 65175552);
  ushort*   zbuf  = (ushort*)(ws + 81985536);
  bf16_t*   cbb   = (bf16_t*)(ws + 96731136);
  bf16_t*   wc2   = (bf16_t*)(ws + 96993280);
  bf16_t*   wd1   = (bf16_t*)(ws + 97124352);
  int*      idxArr= (int*)(ws + 97255424);
  unsigned* hist  = (unsigned*)(ws + 97485824);
  float*    cnorm = (float*)(ws + 97489920);
  float*    sse   = (float*)(ws + 97494016);

  conv1_k<<<dim3(B_ * HID_), dim3(256), 0, stream>>>(x, ew1, eb1, z1p);
  tz_k<<<dim3(1024), dim3(256), 0, stream>>>(z1p, z1t);
  wprep_k<<<dim3(256), dim3(256), 0, stream>>>(ew2, dw1, wc2, wd1);
  conv2m_k<<<dim3(960), dim3(256), 0, stream>>>(z1t, wc2, eb2, z, zbuf);
  prep_k<<<dim3(4), dim3(256), 0, stream>>>(cb, cbb, cnorm, hist, sse);
  vq1_k<<<dim3(900), dim3(256), 0, stream>>>((const bf16_t*)zbuf, cbb, cnorm,
                                             idxArr, hist);
  zero_k<<<dim3(4104), dim3(256), 0, stream>>>((float4*)qt, 1050624);
  tq_k<<<dim3(960), dim3(256), 0, stream>>>(cbb, idxArr, (ushort*)qt);
  sse_k<<<dim3(900), dim3(256), 0, stream>>>((const float4*)z, cb, idxArr,
                                             sse);
  zero_k<<<dim3(8713), dim3(256), 0, stream>>>((float4*)yp, 2230272);
  convt1m_k<<<dim3(1024), dim3(256), 0, stream>>>(qt, wd1, db1, yp);
  convt2_k<<<dim3(192, 16), dim3(256), 0, stream>>>(yp, dw2, db2, out);
  fin_k<<<dim3(1), dim3(256), 0, stream>>>(hist, sse, out);
}

// Round 12
// 403.038 us; speedup vs baseline: 3.0302x; 1.1701x over previous
//
#include <hip/hip_runtime.h>

#define B_    64
#define CIN_  3
#define HW_   64
#define HID_  128
#define K_    1024
#define H1_   31      // after conv1 (stride2 k4)
#define H2_   30      // after conv2 (stride1 k2)
#define NROWS_ 57600  // B_*H2_*H2_
#define NELEM_ 7372800

typedef __bf16 bf16_t;
typedef __attribute__((ext_vector_type(8))) __bf16 bf16x8;
typedef __attribute__((ext_vector_type(4))) float f32x4;

// ---------------- conv1: x[64,3,64,64] -> relu -> z1p[64,128,32,32] (padded)
__global__ __launch_bounds__(256) void conv1_k(const float* __restrict__ x,
    const float* __restrict__ w, const float* __restrict__ bias,
    float* __restrict__ z1p) {
  int blk = blockIdx.x, b = blk >> 7, co = blk & 127;     // grid = 64*128
  const float* wp = w + co * 48;                          // [co][ci][4][4]
  float wr[48];
  #pragma unroll
  for (int i = 0; i < 48; ++i) wr[i] = wp[i];             // uniform -> SGPRs
  const float* xb = x + (size_t)b * CIN_ * HW_ * HW_;
  float* zb = z1p + ((size_t)blk << 10);                  // 32x32 padded plane
  float bv = bias[co];
  for (int j = threadIdx.x; j < H1_ * H1_; j += 256) {
    int oh = j / H1_, ow = j % H1_;
    float acc = bv;
    #pragma unroll
    for (int ci = 0; ci < CIN_; ++ci) {
      const float* xp = xb + ci * HW_ * HW_ + (oh * 2) * HW_ + ow * 2;
      #pragma unroll
      for (int kh = 0; kh < 4; ++kh)
        #pragma unroll
        for (int kw = 0; kw < 4; ++kw)
          acc += xp[kh * HW_ + kw] * wr[ci * 16 + kh * 4 + kw];
    }
    zb[(oh << 5) + ow] = fmaxf(acc, 0.f);                 // pad never read
  }
}

// ---------------- tz: z1p fp32 [b*128][1024] -> z1t bf16 [b][1024][128] -----
__global__ __launch_bounds__(256) void tz_k(const float* __restrict__ z1p,
    bf16_t* __restrict__ z1t) {
  __shared__ bf16_t t[64 * 136];
  int b = blockIdx.x >> 4, pc = blockIdx.x & 15;          // 64-pos chunk
  int tid = threadIdx.x;
  const float4* src = (const float4*)z1p;
  #pragma unroll
  for (int s = 0; s < 8; ++s) {
    int f = s * 256 + tid;                                // 2048 f4s
    int ci = f >> 4, c16 = f & 15;
    float4 v = src[(size_t)(b * HID_ + ci) * 256 + pc * 16 + c16];
    t[(c16 * 4 + 0) * 136 + ci] = (bf16_t)v.x;
    t[(c16 * 4 + 1) * 136 + ci] = (bf16_t)v.y;
    t[(c16 * 4 + 2) * 136 + ci] = (bf16_t)v.z;
    t[(c16 * 4 + 3) * 136 + ci] = (bf16_t)v.w;
  }
  __syncthreads();
  #pragma unroll
  for (int s = 0; s < 4; ++s) {
    int f = s * 256 + tid;                                // 1024 f4s out
    int pos = f >> 4, c16 = f & 15;
    *(float4*)&z1t[((size_t)b * 1024 + pc * 64 + pos) * 128 + c16 * 8] =
        *(float4*)&t[pos * 136 + c16 * 8];
  }
}

// ---------------- wprep: bf16 weight transposes -----------------------------
// wc2[t][co][ci] = ew2[co][ci][t]; wd1[t][co][ci] = dw1[ci][co][3-t]
// wt2[n][tap*128+ci] = dw2[ci][co][tapoff], n = co*4+ph*2+pw (n>=12 zero)
__global__ __launch_bounds__(256) void wprep_k(const float* __restrict__ ew2,
    const float* __restrict__ dw1, const float* __restrict__ dw2,
    bf16_t* __restrict__ wc2, bf16_t* __restrict__ wd1,
    bf16_t* __restrict__ wt2) {
  int id = blockIdx.x * 256 + threadIdx.x;                // grid 256 -> 65536
  int t = id >> 14, co = (id >> 7) & 127, ci = id & 127;
  wc2[id] = (bf16_t)ew2[(co * 128 + ci) * 4 + t];
  wd1[id] = (bf16_t)dw1[(ci * 128 + co) * 4 + (3 - t)];
  if (id < 8192) {
    int n = id >> 9, k = id & 511;
    int tap = k >> 7, c = k & 127;
    if (n < 12) {
      int nco = n >> 2, ph = (n >> 1) & 1, pw = n & 1;
      int off = (tap >> 1) * 8 + (tap & 1) * 2;           // 0,2,8,10
      wt2[id] = (bf16_t)dw2[c * 48 + nco * 16 + ph * 4 + pw + off];
    } else {
      wt2[id] = (bf16_t)0.f;
    }
  }
}

// ---------------- conv2 (MFMA): z1t -> relu -> z fp32 + zbuf bf16 -----------
__global__ __launch_bounds__(256, 2) void conv2m_k(const bf16_t* __restrict__ z1t,
    const bf16_t* __restrict__ wc2, const float* __restrict__ bias,
    float* __restrict__ z, ushort* __restrict__ zbuf) {
  __shared__ __align__(16) bf16_t as_[128 * 136];         // 34.8 KB
  int blk = blockIdx.x;                                   // 64*15
  int b = blk / 15, rt = blk % 15;
  int tid = threadIdx.x, wv = tid >> 6, ln = tid & 63;
  const float4* src = (const float4*)(z1t + ((size_t)b * 1024 + rt * 64) * 128);
  #pragma unroll
  for (int s = 0; s < 8; ++s) {
    int f = s * 256 + tid;                                // 2048 f4 = 32 KB
    int lp = f >> 4, c16 = f & 15;
    *(float4*)&as_[lp * 136 + c16 * 8] = src[f];
  }
  __syncthreads();
  int m = wv * 16 + (ln & 15), q = ln >> 4;
  f32x4 acc8[8];
  #pragma unroll
  for (int c = 0; c < 8; ++c) acc8[c] = (f32x4){0.f, 0.f, 0.f, 0.f};
  #pragma unroll
  for (int t = 0; t < 4; ++t) {
    int off = (t >> 1) * 32 + (t & 1);                    // tap offset in pos
    bf16x8 af[4];
    #pragma unroll
    for (int kk = 0; kk < 4; ++kk)
      af[kk] = *(const bf16x8*)&as_[(m + off) * 136 + kk * 32 + q * 8];
    #pragma unroll
    for (int cot = 0; cot < 8; ++cot) {
      const bf16_t* wp = wc2 + (size_t)(t * 128 + cot * 16 + (ln & 15)) * 128
                         + q * 8;
      #pragma unroll
      for (int kk = 0; kk < 4; ++kk) {
        bf16x8 bf = *(const bf16x8*)(wp + kk * 32);
        acc8[cot] = __builtin_amdgcn_mfma_f32_16x16x32_bf16(af[kk], bf,
                                                            acc8[cot], 0, 0, 0);
      }
    }
  }
  #pragma unroll
  for (int cot = 0; cot < 8; ++cot) {
    int co = cot * 16 + (ln & 15);
    float bv = bias[co];
    #pragma unroll
    for (int r = 0; r < 4; ++r) {
      int mo = wv * 16 + q * 4 + r;
      int ocol = mo & 31;
      if (ocol < 30) {
        int orow = rt * 2 + (mo >> 5);                    // always < 30
        float v = fmaxf(acc8[cot][r] + bv, 0.f);
        size_t idx = (size_t)(b * HID_ + co) * 900 + orow * 30 + ocol;
        z[idx] = v;
        bf16_t h = (bf16_t)v;
        zbuf[idx] = *(ushort*)&h;                         // fused cvt for vq1
      }
    }
  }
}

// ---------------- prep: cb -> bf16 copy + bf16-consistent norms + zeros -----
__global__ __launch_bounds__(256) void prep_k(const float* __restrict__ cb,
    bf16_t* __restrict__ cbb, float* __restrict__ cnorm,
    unsigned* __restrict__ hist, float* __restrict__ sse) {
  int k = blockIdx.x * 256 + threadIdx.x;
  if (k < K_) {
    float s0 = 0.f;
    for (int d = 0; d < HID_; d += 4) {
      float4 v = *(const float4*)&cb[k * HID_ + d];
      bf16_t t[4] = {(bf16_t)v.x, (bf16_t)v.y, (bf16_t)v.z, (bf16_t)v.w};
      *(ushort4*)&((ushort*)cbb)[k * HID_ + d] = *(ushort4*)t;
      float f0 = (float)t[0], f1 = (float)t[1];
      float f2 = (float)t[2], f3 = (float)t[3];
      s0 += f0 * f0 + f1 * f1 + f2 * f2 + f3 * f3;
    }
    cnorm[k] = s0;
    hist[k] = 0u;
  }
  if (k == 0 && blockIdx.x == 0) *sse = 0.f;
}

__global__ __launch_bounds__(256) void zero_k(float4* __restrict__ p, int n4) {
  int i = blockIdx.x * 256 + threadIdx.x;
  if (i < n4) p[i] = make_float4(0.f, 0.f, 0.f, 0.f);
}

// ---------------- VQ phase 1 (MFMA): 64 rows x 1024 codes + hist ------------
__global__ __launch_bounds__(256) void vq1_k(const bf16_t* __restrict__ zb,
    const bf16_t* __restrict__ cbb, const float* __restrict__ cnorm,
    int* __restrict__ idxArr, unsigned* __restrict__ hist) {
  __shared__ __align__(16) bf16_t zs[64 * 136];           // 17 KB
  __shared__ __align__(16) bf16_t cbs[128 * 136];         // 34 KB
  __shared__ unsigned long long red[64 * 16];             // 8 KB
  int n0 = blockIdx.x * 64;                               // 900 blocks
  int tid = threadIdx.x;
  int wv = tid >> 6, ln = tid & 63;
  {
    const float4* zg4 = (const float4*)(zb + (size_t)n0 * HID_);
    #pragma unroll
    for (int s = 0; s < 4; ++s) {
      int f = s * 256 + tid;
      int row = f >> 4, seg = f & 15;
      *(float4*)&zs[row * 136 + seg * 8] = zg4[f];
    }
  }
  __syncthreads();
  bf16x8 afr[4];
  #pragma unroll
  for (int kk = 0; kk < 4; ++kk)
    afr[kk] = *(const bf16x8*)&zs[(wv * 16 + (ln & 15)) * 136 + kk * 32 +
                                  (ln >> 4) * 8];
  unsigned long long best[4] = {~0ull, ~0ull, ~0ull, ~0ull};
  const float4* cg4 = (const float4*)cbb;
  for (int c0 = 0; c0 < K_; c0 += 128) {
    __syncthreads();
    #pragma unroll
    for (int s = 0; s < 8; ++s) {
      int f = s * 256 + tid;
      int code = f >> 4, seg = f & 15;
      *(float4*)&cbs[code * 136 + seg * 8] = cg4[(c0 + code) * 16 + seg];
    }
    __syncthreads();
    #pragma unroll 2
    for (int t = 0; t < 8; ++t) {
      f32x4 acc = {0.f, 0.f, 0.f, 0.f};
      #pragma unroll
      for (int kk = 0; kk < 4; ++kk) {
        bf16x8 bfr = *(const bf16x8*)&cbs[(t * 16 + (ln & 15)) * 136 +
                                          kk * 32 + (ln >> 4) * 8];
        acc = __builtin_amdgcn_mfma_f32_16x16x32_bf16(afr[kk], bfr, acc,
                                                      0, 0, 0);
      }
      int code = c0 + t * 16 + (ln & 15);
      float cn = cnorm[code];
      #pragma unroll
      for (int r = 0; r < 4; ++r) {
        float dist = cn - 2.f * acc[r];
        unsigned u = __float_as_uint(dist);
        u = (u & 0x80000000u) ? ~u : (u | 0x80000000u);
        unsigned long long p = ((unsigned long long)u << 32) | (unsigned)code;
        if (p < best[r]) best[r] = p;
      }
    }
  }
  __syncthreads();
  #pragma unroll
  for (int r = 0; r < 4; ++r)
    red[(wv * 16 + (ln >> 4) * 4 + r) * 16 + (ln & 15)] = best[r];
  __syncthreads();
  if (tid < 64) {
    unsigned long long b = ~0ull;
    #pragma unroll
    for (int c = 0; c < 16; ++c) {
      unsigned long long p = red[tid * 16 + c];
      if (p < b) b = p;
    }
    int bi = (int)(b & 0xffffffffu);
    idxArr[n0 + tid] = bi;
    atomicAdd(&hist[bi], 1u);                             // hist fused here
  }
}

// ---------------- tq: gather cbb rows -> qt bf16 [b][pos][ci], coalesced ----
__global__ __launch_bounds__(256) void tq_k(const bf16_t* __restrict__ cbb,
    const int* __restrict__ idxArr, ushort* __restrict__ qt) {
  __shared__ ushort t[60 * 128];                          // 15 KB
  int b = blockIdx.x / 15, st = blockIdx.x % 15;          // 60-s tile
  int tid = threadIdx.x;
  int s0 = st * 60;
  #pragma unroll
  for (int it = 0; it < 8; ++it) {
    int task = it * 256 + tid;                            // sc*128 + c
    if (task < 1920) {
      int sc = task >> 7, c = task & 127;
      int f = b * 115200 + c * 900 + s0 + sc * 4;
      int n = f >> 7, d = f & 127;                        // d%4==0, no wrap
      int k = idxArr[n];
      ushort4 v = *(const ushort4*)((const ushort*)cbb + k * 128 + d);
      t[(sc * 4 + 0) * 128 + c] = v.x;
      t[(sc * 4 + 1) * 128 + c] = v.y;
      t[(sc * 4 + 2) * 128 + c] = v.z;
      t[(sc * 4 + 3) * 128 + c] = v.w;
    }
  }
  __syncthreads();
  #pragma unroll
  for (int it = 0; it < 4; ++it) {
    int task = it * 256 + tid;                            // sl*16 + c16
    if (task < 960) {
      int sl = task >> 4, c16 = task & 15;
      int s = s0 + sl;
      int h = s / 30, w = s - h * 30;
      int p = (h + 1) * 32 + (w + 1);
      *(uint4*)&qt[((size_t)(b * 1024 + p)) * 128 + c16 * 8] =
          *(uint4*)&t[sl * 128 + c16 * 8];
    }
  }
}

// ---------------- sse: fp32 SSE, 8 float4/thread, wave-shuffle reduce -------
__global__ __launch_bounds__(256) void sse_k(const float4* __restrict__ z4,
    const float* __restrict__ cb, const int* __restrict__ idxArr,
    float* __restrict__ sse) {
  int base = blockIdx.x * 2048 + threadIdx.x;             // 900 blocks exact
  float se = 0.f;
  #pragma unroll
  for (int it = 0; it < 8; ++it) {
    int i = base + it * 256;
    int f = i * 4;
    int n = f >> 7, d = f & 127;
    int k = idxArr[n];
    float4 zv = z4[i];
    float4 cv = *(const float4*)&cb[k * 128 + d];
    float dx = cv.x - zv.x, dy = cv.y - zv.y;
    float dz = cv.z - zv.z, dw = cv.w - zv.w;
    se += dx * dx + dy * dy + dz * dz + dw * dw;
  }
  #pragma unroll
  for (int o = 32; o > 0; o >>= 1) se += __shfl_down(se, o, 64);
  __shared__ float red[4];
  if ((threadIdx.x & 63) == 0) red[threadIdx.x >> 6] = se;
  __syncthreads();
  if (threadIdx.x == 0)
    atomicAdd(sse, red[0] + red[1] + red[2] + red[3]);
}

// ---------------- convT1 (MFMA): qt -> relu -> yt bf16 [b][pos34][ci] -------
// yt is zero-padded 34x34; y (31x31) lands at rows/cols 1..31.
__global__ __launch_bounds__(256, 2) void convt1m_k(const bf16_t* __restrict__ qt,
    const bf16_t* __restrict__ wd1, const float* __restrict__ bias,
    ushort* __restrict__ yt) {
  __shared__ __align__(16) bf16_t as_[128 * 136];
  int blk = blockIdx.x;                                   // 64*16
  int b = blk >> 4, rt = blk & 15;
  int tid = threadIdx.x, wv = tid >> 6, ln = tid & 63;
  const float4* src = (const float4*)(qt + ((size_t)b * 1024 + rt * 64) * 128);
  #pragma unroll
  for (int s = 0; s < 8; ++s) {
    int f = s * 256 + tid;
    int lp = f >> 4, c16 = f & 15;
    *(float4*)&as_[lp * 136 + c16 * 8] = src[f];          // rt=15 reads slack
  }
  __syncthreads();
  int m = wv * 16 + (ln & 15), q = ln >> 4;
  f32x4 acc8[8];
  #pragma unroll
  for (int c = 0; c < 8; ++c) acc8[c] = (f32x4){0.f, 0.f, 0.f, 0.f};
  #pragma unroll
  for (int t = 0; t < 4; ++t) {
    int off = (t >> 1) * 32 + (t & 1);
    bf16x8 af[4];
    #pragma unroll
    for (int kk = 0; kk < 4; ++kk)
      af[kk] = *(const bf16x8*)&as_[(m + off) * 136 + kk * 32 + q * 8];
    #pragma unroll
    for (int cot = 0; cot < 8; ++cot) {
      const bf16_t* wp = wd1 + (size_t)(t * 128 + cot * 16 + (ln & 15)) * 128
                         + q * 8;
      #pragma unroll
      for (int kk = 0; kk < 4; ++kk) {
        bf16x8 bf = *(const bf16x8*)(wp + kk * 32);
        acc8[cot] = __builtin_amdgcn_mfma_f32_16x16x32_bf16(af[kk], bf,
                                                            acc8[cot], 0, 0, 0);
      }
    }
  }
  #pragma unroll
  for (int cot = 0; cot < 8; ++cot) {
    int co = cot * 16 + (ln & 15);
    float bv = bias[co];
    #pragma unroll
    for (int r = 0; r < 4; ++r) {
      int mo = wv * 16 + q * 4 + r;
      int orow = rt * 2 + (mo >> 5), ocol = mo & 31;
      if (orow < 31 && ocol < 31) {
        float v = fmaxf(acc8[cot][r] + bv, 0.f);
        bf16_t h = (bf16_t)v;
        yt[((size_t)b * 1156 + (orow + 1) * 34 + (ocol + 1)) * 128 + co] =
            *(ushort*)&h;
      }
    }
  }
}

// ---------------- convT2 (MFMA): yt -> out fp32 ------------------------------
// GEMM: M=64 qpos/block, N=16 (12 used: co*4+ph*2+pw), K=512 (4 tap x 128 ci).
// All 12 outputs of a quadrant position share the same 4 y-taps.
__global__ __launch_bounds__(256, 2) void convt2m_k(const bf16_t* __restrict__ yt,
    const bf16_t* __restrict__ wt2, const float* __restrict__ bias,
    float* __restrict__ out) {
  __shared__ __align__(16) bf16_t as_[128 * 136];         // 34.8 KB
  int b = blockIdx.x >> 4, rt = blockIdx.x & 15;          // grid = 64*16
  int tid = threadIdx.x, wv = tid >> 6, ln = tid & 63;
  // stage pos34 window [rt*68, rt*68+128) x 128 ci (rt=15: 1020+128<=1156)
  const float4* src = (const float4*)(yt + ((size_t)b * 1156 + rt * 68) * 128);
  #pragma unroll
  for (int s = 0; s < 8; ++s) {
    int f = s * 256 + tid;
    int lp = f >> 4, c16 = f & 15;
    *(float4*)&as_[lp * 136 + c16 * 8] = src[f];
  }
  __syncthreads();
  int mloc = wv * 16 + (ln & 15), q = ln >> 4;
  int qh = mloc >> 5, qw = mloc & 31;                     // local quadrant pos
  int base = (qh + 1) * 34 + qw + 1;                      // in staged window
  f32x4 acc = {0.f, 0.f, 0.f, 0.f};
  #pragma unroll
  for (int kc = 0; kc < 16; ++kc) {
    int tap = kc >> 2;
    int toff = (tap & 1) + (tap >> 1) * 34;               // 0,1,34,35
    bf16x8 af = *(const bf16x8*)&as_[(base - toff) * 136 +
                                     (kc & 3) * 32 + q * 8];
    bf16x8 bf = *(const bf16x8*)&wt2[(size_t)(ln & 15) * 512 + kc * 32 + q * 8];
    acc = __builtin_amdgcn_mfma_f32_16x16x32_bf16(af, bf, acc, 0, 0, 0);
  }
  __syncthreads();                                        // as_ reads done
  float* bb = (float*)as_;                                // bounce: 64x16 f32
  #pragma unroll
  for (int r = 0; r < 4; ++r)
    bb[(wv * 16 + q * 4 + r) * 16 + (ln & 15)] = acc[r];
  __syncthreads();
  if (tid < 192) {
    int row_id = tid >> 4;                                // co*4 + ohoff
    int co = row_id >> 2, ohoff = row_id & 3;
    int qhl = ohoff >> 1, ph = ohoff & 1;
    float bv = bias[co];
    int ow0 = (tid & 15) * 4;
    float tmp[4];
    #pragma unroll
    for (int e = 0; e < 4; ++e) {
      int ow = ow0 + e;
      tmp[e] = bb[(qhl * 32 + (ow >> 1)) * 16 + co * 4 + ph * 2 + (ow & 1)]
               + bv;
    }
    *(float4*)&out[((size_t)(b * 3 + co)) * 4096 + (rt * 4 + ohoff) * 64 + ow0]
        = *(float4*)tmp;
  }
}

// ---------------- finalize: loss + perplexity -------------------------------
__global__ __launch_bounds__(256) void fin_k(const unsigned* __restrict__ hist,
    const float* __restrict__ sse, float* __restrict__ out) {
  __shared__ float red[256];
  float e = 0.f;
  for (int k = threadIdx.x; k < K_; k += 256) {
    float p = (float)hist[k] * (1.0f / (float)NROWS_);
    e += p * logf(p + 1e-10f);
  }
  red[threadIdx.x] = e;
  __syncthreads();
  #pragma unroll
  for (int t = 128; t > 0; t >>= 1) {
    if (threadIdx.x < t) red[threadIdx.x] += red[threadIdx.x + t];
    __syncthreads();
  }
  if (threadIdx.x == 0) {
    out[786432] = 1.25f * (*sse) * (1.0f / (float)NELEM_);
    out[786433] = expf(-red[0]);
  }
}

extern "C" void kernel_launch(void* const* d_in, const int* in_sizes, int n_in,
                              void* d_out, int out_size, void* d_ws,
                              size_t ws_size, hipStream_t stream) {
  (void)in_sizes; (void)n_in; (void)out_size; (void)ws_size;
  const float* x   = (const float*)d_in[0];
  const float* ew1 = (const float*)d_in[1];
  const float* eb1 = (const float*)d_in[2];
  const float* ew2 = (const float*)d_in[3];
  const float* eb2 = (const float*)d_in[4];
  const float* cb  = (const float*)d_in[5];
  const float* dw1 = (const float*)d_in[6];
  const float* db1 = (const float*)d_in[7];
  const float* dw2 = (const float*)d_in[8];
  const float* db2 = (const float*)d_in[9];
  float* out = (float*)d_out;
  char* ws = (char*)d_ws;

  // ws layout (~97.5 MB, aliased by liveness):
  //  [0, 35,684,352)            z1p fp32 (conv1->tz) then yt bf16 18.94 MB
  //                             (zeroed after tz; convt1m->convt2m)
  //  [35,684,352, 65,175,552)   z fp32 (conv2m->sse)
  //  [65,175,552, 81,985,536)   z1t bf16 +slack (tz->conv2m) then qt bf16
  //  [81,985,536, 96,731,136)   zbuf bf16 (conv2m->vq1)
  //  [96,731,136 ..)            cbb | wc2 | wd1 | idxArr | hist | cnorm | sse | wt2
  float*    z1p   = (float*)(ws);
  ushort*   yt    = (ushort*)(ws);
  float*    z     = (float*)(ws + 35684352);
  bf16_t*   z1t   = (bf16_t*)(ws + 65175552);
  bf16_t*   qt    = (bf16_t*)(ws + 65175552);
  ushort*   zbuf  = (ushort*)(ws + 81985536);
  bf16_t*   cbb   = (bf16_t*)(ws + 96731136);
  bf16_t*   wc2   = (bf16_t*)(ws + 96993280);
  bf16_t*   wd1   = (bf16_t*)(ws + 97124352);
  int*      idxArr= (int*)(ws + 97255424);
  unsigned* hist  = (unsigned*)(ws + 97485824);
  float*    cnorm = (float*)(ws + 97489920);
  float*    sse   = (float*)(ws + 97494016);
  bf16_t*   wt2   = (bf16_t*)(ws + 97497088);

  conv1_k<<<dim3(B_ * HID_), dim3(256), 0, stream>>>(x, ew1, eb1, z1p);
  tz_k<<<dim3(1024), dim3(256), 0, stream>>>(z1p, z1t);
  wprep_k<<<dim3(256), dim3(256), 0, stream>>>(ew2, dw1, dw2, wc2, wd1, wt2);
  conv2m_k<<<dim3(960), dim3(256), 0, stream>>>(z1t, wc2, eb2, z, zbuf);
  prep_k<<<dim3(4), dim3(256), 0, stream>>>(cb, cbb, cnorm, hist, sse);
  vq1_k<<<dim3(900), dim3(256), 0, stream>>>((const bf16_t*)zbuf, cbb, cnorm,
                                             idxArr, hist);
  zero_k<<<dim3(4624), dim3(256), 0, stream>>>((float4*)yt, 1183744);
  zero_k<<<dim3(4104), dim3(256), 0, stream>>>((float4*)qt, 1050624);
  tq_k<<<dim3(960), dim3(256), 0, stream>>>(cbb, idxArr, (ushort*)qt);
  sse_k<<<dim3(900), dim3(256), 0, stream>>>((const float4*)z, cb, idxArr,
                                             sse);
  convt1m_k<<<dim3(1024), dim3(256), 0, stream>>>(qt, wd1, db1, yt);
  convt2m_k<<<dim3(1024), dim3(256), 0, stream>>>((const bf16_t*)yt, wt2, db2,
                                                  out);
  fin_k<<<dim3(1), dim3(256), 0, stream>>>(hist, sse, out);
}

// Round 13
// 320.698 us; speedup vs baseline: 3.8082x; 1.2568x over previous
//
#include <hip/hip_runtime.h>

#define B_    64
#define CIN_  3
#define HW_   64
#define HID_  128
#define K_    1024
#define H1_   31      // after conv1 (stride2 k4)
#define H2_   30      // after conv2 (stride1 k2)
#define NROWS_ 57600  // B_*H2_*H2_
#define NELEM_ 7372800

typedef __bf16 bf16_t;
typedef __attribute__((ext_vector_type(8))) __bf16 bf16x8;
typedef __attribute__((ext_vector_type(4))) float f32x4;

// ---------------- conv1: x[64,3,64,64] -> relu -> z1p[64,128,32,32] (padded)
__global__ __launch_bounds__(256) void conv1_k(const float* __restrict__ x,
    const float* __restrict__ w, const float* __restrict__ bias,
    float* __restrict__ z1p) {
  int blk = blockIdx.x, b = blk >> 7, co = blk & 127;     // grid = 64*128
  const float* wp = w + co * 48;                          // [co][ci][4][4]
  float wr[48];
  #pragma unroll
  for (int i = 0; i < 48; ++i) wr[i] = wp[i];             // uniform -> SGPRs
  const float* xb = x + (size_t)b * CIN_ * HW_ * HW_;
  float* zb = z1p + ((size_t)blk << 10);                  // 32x32 padded plane
  float bv = bias[co];
  for (int j = threadIdx.x; j < H1_ * H1_; j += 256) {
    int oh = j / H1_, ow = j % H1_;
    float acc = bv;
    #pragma unroll
    for (int ci = 0; ci < CIN_; ++ci) {
      const float* xp = xb + ci * HW_ * HW_ + (oh * 2) * HW_ + ow * 2;
      #pragma unroll
      for (int kh = 0; kh < 4; ++kh)
        #pragma unroll
        for (int kw = 0; kw < 4; ++kw)
          acc += xp[kh * HW_ + kw] * wr[ci * 16 + kh * 4 + kw];
    }
    zb[(oh << 5) + ow] = fmaxf(acc, 0.f);                 // pad never read
  }
}

// ---------------- tz: z1p fp32 [b*128][1024] -> z1t bf16 [b][1024][128] -----
__global__ __launch_bounds__(256) void tz_k(const float* __restrict__ z1p,
    bf16_t* __restrict__ z1t) {
  __shared__ bf16_t t[64 * 136];
  int b = blockIdx.x >> 4, pc = blockIdx.x & 15;          // 64-pos chunk
  int tid = threadIdx.x;
  const float4* src = (const float4*)z1p;
  #pragma unroll
  for (int s = 0; s < 8; ++s) {
    int f = s * 256 + tid;                                // 2048 f4s
    int ci = f >> 4, c16 = f & 15;
    float4 v = src[(size_t)(b * HID_ + ci) * 256 + pc * 16 + c16];
    t[(c16 * 4 + 0) * 136 + ci] = (bf16_t)v.x;
    t[(c16 * 4 + 1) * 136 + ci] = (bf16_t)v.y;
    t[(c16 * 4 + 2) * 136 + ci] = (bf16_t)v.z;
    t[(c16 * 4 + 3) * 136 + ci] = (bf16_t)v.w;
  }
  __syncthreads();
  #pragma unroll
  for (int s = 0; s < 4; ++s) {
    int f = s * 256 + tid;                                // 1024 f4s out
    int pos = f >> 4, c16 = f & 15;
    *(float4*)&z1t[((size_t)b * 1024 + pc * 64 + pos) * 128 + c16 * 8] =
        *(float4*)&t[pos * 136 + c16 * 8];
  }
}

// ---------------- wprep: bf16 weight transposes -----------------------------
// wc2[t][co][ci] = ew2[co][ci][t]; wd1[t][co][ci] = dw1[ci][co][3-t]
// wt2[n][tap*128+ci] = dw2[ci][co][tapoff], n = co*4+ph*2+pw (n>=12 zero)
__global__ __launch_bounds__(256) void wprep_k(const float* __restrict__ ew2,
    const float* __restrict__ dw1, const float* __restrict__ dw2,
    bf16_t* __restrict__ wc2, bf16_t* __restrict__ wd1,
    bf16_t* __restrict__ wt2) {
  int id = blockIdx.x * 256 + threadIdx.x;                // grid 256 -> 65536
  int t = id >> 14, co = (id >> 7) & 127, ci = id & 127;
  wc2[id] = (bf16_t)ew2[(co * 128 + ci) * 4 + t];
  wd1[id] = (bf16_t)dw1[(ci * 128 + co) * 4 + (3 - t)];
  if (id < 8192) {
    int n = id >> 9, k = id & 511;
    int tap = k >> 7, c = k & 127;
    if (n < 12) {
      int nco = n >> 2, ph = (n >> 1) & 1, pw = n & 1;
      int off = (tap >> 1) * 8 + (tap & 1) * 2;           // 0,2,8,10
      wt2[id] = (bf16_t)dw2[c * 48 + nco * 16 + ph * 4 + pw + off];
    } else {
      wt2[id] = (bf16_t)0.f;
    }
  }
}

// ---------------- conv2 (MFMA, B in LDS): z1t -> relu -> z + zbuf -----------
// r12 version read B-frags from global L2 (128 divergent 16B loads/wave,
// VGPR=52, MfmaUtil 3.6% -> latency-serialized, 81 us). Now tap-major loop
// stages each 128co x 128ci B tile in LDS (vq1's proven pattern).
// LDS: A 98x136 (26.7 KB) + B 128x136 (34.8 KB) = 61.5 KB.
__global__ __launch_bounds__(256, 2) void conv2m_k(const bf16_t* __restrict__ z1t,
    const bf16_t* __restrict__ wc2, const float* __restrict__ bias,
    float* __restrict__ z, ushort* __restrict__ zbuf) {
  __shared__ __align__(16) bf16_t as_[98 * 136];          // rows m+off, off<=33
  __shared__ __align__(16) bf16_t bs_[128 * 136];
  int blk = blockIdx.x;                                   // 64*15
  int b = blk / 15, rt = blk % 15;
  int tid = threadIdx.x, wv = tid >> 6, ln = tid & 63;
  const float4* src = (const float4*)(z1t + ((size_t)b * 1024 + rt * 64) * 128);
  #pragma unroll
  for (int s = 0; s < 7; ++s) {
    int f = s * 256 + tid;                                // 98*16 = 1568 f4s
    if (f < 1568) {
      int lp = f >> 4, c16 = f & 15;                      // max row 993 < 1024
      *(float4*)&as_[lp * 136 + c16 * 8] = src[f];
    }
  }
  int m = wv * 16 + (ln & 15), q = ln >> 4;
  f32x4 acc8[8];
  #pragma unroll
  for (int c = 0; c < 8; ++c) acc8[c] = (f32x4){0.f, 0.f, 0.f, 0.f};
  const float4* w4 = (const float4*)wc2;
  #pragma unroll
  for (int t = 0; t < 4; ++t) {
    __syncthreads();                                      // bs_ reuse (+A 1st)
    #pragma unroll
    for (int s = 0; s < 8; ++s) {
      int f = s * 256 + tid;                              // 2048 f4s
      int co = f >> 4, c16 = f & 15;
      *(float4*)&bs_[co * 136 + c16 * 8] = w4[t * 2048 + f];
    }
    __syncthreads();
    int off = (t >> 1) * 32 + (t & 1);                    // tap offset in pos
    bf16x8 af[4];
    #pragma unroll
    for (int kk = 0; kk < 4; ++kk)
      af[kk] = *(const bf16x8*)&as_[(m + off) * 136 + kk * 32 + q * 8];
    #pragma unroll
    for (int cot = 0; cot < 8; ++cot) {
      #pragma unroll
      for (int kk = 0; kk < 4; ++kk) {
        bf16x8 bf = *(const bf16x8*)&bs_[(cot * 16 + (ln & 15)) * 136 +
                                         kk * 32 + q * 8];
        acc8[cot] = __builtin_amdgcn_mfma_f32_16x16x32_bf16(af[kk], bf,
                                                            acc8[cot], 0, 0, 0);
      }
    }
  }
  #pragma unroll
  for (int cot = 0; cot < 8; ++cot) {
    int co = cot * 16 + (ln & 15);
    float bv = bias[co];
    #pragma unroll
    for (int r = 0; r < 4; ++r) {
      int mo = wv * 16 + q * 4 + r;
      int ocol = mo & 31;
      if (ocol < 30) {
        int orow = rt * 2 + (mo >> 5);                    // always < 30
        float v = fmaxf(acc8[cot][r] + bv, 0.f);
        size_t idx = (size_t)(b * HID_ + co) * 900 + orow * 30 + ocol;
        z[idx] = v;
        bf16_t h = (bf16_t)v;
        zbuf[idx] = *(ushort*)&h;                         // fused cvt for vq1
      }
    }
  }
}

// ---------------- prep: cb -> bf16 copy + bf16-consistent norms + zeros -----
__global__ __launch_bounds__(256) void prep_k(const float* __restrict__ cb,
    bf16_t* __restrict__ cbb, float* __restrict__ cnorm,
    unsigned* __restrict__ hist, float* __restrict__ sse) {
  int k = blockIdx.x * 256 + threadIdx.x;
  if (k < K_) {
    float s0 = 0.f;
    for (int d = 0; d < HID_; d += 4) {
      float4 v = *(const float4*)&cb[k * HID_ + d];
      bf16_t t[4] = {(bf16_t)v.x, (bf16_t)v.y, (bf16_t)v.z, (bf16_t)v.w};
      *(ushort4*)&((ushort*)cbb)[k * HID_ + d] = *(ushort4*)t;
      float f0 = (float)t[0], f1 = (float)t[1];
      float f2 = (float)t[2], f3 = (float)t[3];
      s0 += f0 * f0 + f1 * f1 + f2 * f2 + f3 * f3;
    }
    cnorm[k] = s0;
    hist[k] = 0u;
  }
  if (k == 0 && blockIdx.x == 0) *sse = 0.f;
}

__global__ __launch_bounds__(256) void zero_k(float4* __restrict__ p, int n4) {
  int i = blockIdx.x * 256 + threadIdx.x;
  if (i < n4) p[i] = make_float4(0.f, 0.f, 0.f, 0.f);
}

// ---------------- VQ phase 1 (MFMA): 64 rows x 1024 codes + hist ------------
__global__ __launch_bounds__(256) void vq1_k(const bf16_t* __restrict__ zb,
    const bf16_t* __restrict__ cbb, const float* __restrict__ cnorm,
    int* __restrict__ idxArr, unsigned* __restrict__ hist) {
  __shared__ __align__(16) bf16_t zs[64 * 136];           // 17 KB
  __shared__ __align__(16) bf16_t cbs[128 * 136];         // 34 KB
  __shared__ unsigned long long red[64 * 16];             // 8 KB
  int n0 = blockIdx.x * 64;                               // 900 blocks
  int tid = threadIdx.x;
  int wv = tid >> 6, ln = tid & 63;
  {
    const float4* zg4 = (const float4*)(zb + (size_t)n0 * HID_);
    #pragma unroll
    for (int s = 0; s < 4; ++s) {
      int f = s * 256 + tid;
      int row = f >> 4, seg = f & 15;
      *(float4*)&zs[row * 136 + seg * 8] = zg4[f];
    }
  }
  __syncthreads();
  bf16x8 afr[4];
  #pragma unroll
  for (int kk = 0; kk < 4; ++kk)
    afr[kk] = *(const bf16x8*)&zs[(wv * 16 + (ln & 15)) * 136 + kk * 32 +
                                  (ln >> 4) * 8];
  unsigned long long best[4] = {~0ull, ~0ull, ~0ull, ~0ull};
  const float4* cg4 = (const float4*)cbb;
  for (int c0 = 0; c0 < K_; c0 += 128) {
    __syncthreads();
    #pragma unroll
    for (int s = 0; s < 8; ++s) {
      int f = s * 256 + tid;
      int code = f >> 4, seg = f & 15;
      *(float4*)&cbs[code * 136 + seg * 8] = cg4[(c0 + code) * 16 + seg];
    }
    __syncthreads();
    #pragma unroll 2
    for (int t = 0; t < 8; ++t) {
      f32x4 acc = {0.f, 0.f, 0.f, 0.f};
      #pragma unroll
      for (int kk = 0; kk < 4; ++kk) {
        bf16x8 bfr = *(const bf16x8*)&cbs[(t * 16 + (ln & 15)) * 136 +
                                          kk * 32 + (ln >> 4) * 8];
        acc = __builtin_amdgcn_mfma_f32_16x16x32_bf16(afr[kk], bfr, acc,
                                                      0, 0, 0);
      }
      int code = c0 + t * 16 + (ln & 15);
      float cn = cnorm[code];
      #pragma unroll
      for (int r = 0; r < 4; ++r) {
        float dist = cn - 2.f * acc[r];
        unsigned u = __float_as_uint(dist);
        u = (u & 0x80000000u) ? ~u : (u | 0x80000000u);
        unsigned long long p = ((unsigned long long)u << 32) | (unsigned)code;
        if (p < best[r]) best[r] = p;
      }
    }
  }
  __syncthreads();
  #pragma unroll
  for (int r = 0; r < 4; ++r)
    red[(wv * 16 + (ln >> 4) * 4 + r) * 16 + (ln & 15)] = best[r];
  __syncthreads();
  if (tid < 64) {
    unsigned long long b = ~0ull;
    #pragma unroll
    for (int c = 0; c < 16; ++c) {
      unsigned long long p = red[tid * 16 + c];
      if (p < b) b = p;
    }
    int bi = (int)(b & 0xffffffffu);
    idxArr[n0 + tid] = bi;
    atomicAdd(&hist[bi], 1u);                             // hist fused here
  }
}

// ---------------- tq: gather cbb rows -> qt bf16 [b][pos][ci], coalesced ----
__global__ __launch_bounds__(256) void tq_k(const bf16_t* __restrict__ cbb,
    const int* __restrict__ idxArr, ushort* __restrict__ qt) {
  __shared__ ushort t[60 * 128];                          // 15 KB
  int b = blockIdx.x / 15, st = blockIdx.x % 15;          // 60-s tile
  int tid = threadIdx.x;
  int s0 = st * 60;
  #pragma unroll
  for (int it = 0; it < 8; ++it) {
    int task = it * 256 + tid;                            // sc*128 + c
    if (task < 1920) {
      int sc = task >> 7, c = task & 127;
      int f = b * 115200 + c * 900 + s0 + sc * 4;
      int n = f >> 7, d = f & 127;                        // d%4==0, no wrap
      int k = idxArr[n];
      ushort4 v = *(const ushort4*)((const ushort*)cbb + k * 128 + d);
      t[(sc * 4 + 0) * 128 + c] = v.x;
      t[(sc * 4 + 1) * 128 + c] = v.y;
      t[(sc * 4 + 2) * 128 + c] = v.z;
      t[(sc * 4 + 3) * 128 + c] = v.w;
    }
  }
  __syncthreads();
  #pragma unroll
  for (int it = 0; it < 4; ++it) {
    int task = it * 256 + tid;                            // sl*16 + c16
    if (task < 960) {
      int sl = task >> 4, c16 = task & 15;
      int s = s0 + sl;
      int h = s / 30, w = s - h * 30;
      int p = (h + 1) * 32 + (w + 1);
      *(uint4*)&qt[((size_t)(b * 1024 + p)) * 128 + c16 * 8] =
          *(uint4*)&t[sl * 128 + c16 * 8];
    }
  }
}

// ---------------- sse: fp32 SSE, 8 float4/thread, wave-shuffle reduce -------
__global__ __launch_bounds__(256) void sse_k(const float4* __restrict__ z4,
    const float* __restrict__ cb, const int* __restrict__ idxArr,
    float* __restrict__ sse) {
  int base = blockIdx.x * 2048 + threadIdx.x;             // 900 blocks exact
  float se = 0.f;
  #pragma unroll
  for (int it = 0; it < 8; ++it) {
    int i = base + it * 256;
    int f = i * 4;
    int n = f >> 7, d = f & 127;
    int k = idxArr[n];
    float4 zv = z4[i];
    float4 cv = *(const float4*)&cb[k * 128 + d];
    float dx = cv.x - zv.x, dy = cv.y - zv.y;
    float dz = cv.z - zv.z, dw = cv.w - zv.w;
    se += dx * dx + dy * dy + dz * dz + dw * dw;
  }
  #pragma unroll
  for (int o = 32; o > 0; o >>= 1) se += __shfl_down(se, o, 64);
  __shared__ float red[4];
  if ((threadIdx.x & 63) == 0) red[threadIdx.x >> 6] = se;
  __syncthreads();
  if (threadIdx.x == 0)
    atomicAdd(sse, red[0] + red[1] + red[2] + red[3]);
}

// ---------------- convT1 (MFMA, B in LDS): qt -> relu -> yt bf16 ------------
// Same restructure as conv2m. rt=15 rows clamp to 1023: clamped rows only
// feed outputs guarded out by orow<31 / ocol<31 (verified).
__global__ __launch_bounds__(256, 2) void convt1m_k(const bf16_t* __restrict__ qt,
    const bf16_t* __restrict__ wd1, const float* __restrict__ bias,
    ushort* __restrict__ yt) {
  __shared__ __align__(16) bf16_t as_[98 * 136];
  __shared__ __align__(16) bf16_t bs_[128 * 136];
  int blk = blockIdx.x;                                   // 64*16
  int b = blk >> 4, rt = blk & 15;
  int tid = threadIdx.x, wv = tid >> 6, ln = tid & 63;
  const float4* src = (const float4*)(qt + (size_t)b * 1024 * 128);
  #pragma unroll
  for (int s = 0; s < 7; ++s) {
    int f = s * 256 + tid;                                // 1568 f4s
    if (f < 1568) {
      int lp = f >> 4, c16 = f & 15;
      int gr = rt * 64 + lp;
      if (gr > 1023) gr = 1023;                           // rt=15 guard
      *(float4*)&as_[lp * 136 + c16 * 8] = src[gr * 16 + c16];
    }
  }
  int m = wv * 16 + (ln & 15), q = ln >> 4;
  f32x4 acc8[8];
  #pragma unroll
  for (int c = 0; c < 8; ++c) acc8[c] = (f32x4){0.f, 0.f, 0.f, 0.f};
  const float4* w4 = (const float4*)wd1;
  #pragma unroll
  for (int t = 0; t < 4; ++t) {
    __syncthreads();
    #pragma unroll
    for (int s = 0; s < 8; ++s) {
      int f = s * 256 + tid;
      int co = f >> 4, c16 = f & 15;
      *(float4*)&bs_[co * 136 + c16 * 8] = w4[t * 2048 + f];
    }
    __syncthreads();
    int off = (t >> 1) * 32 + (t & 1);
    bf16x8 af[4];
    #pragma unroll
    for (int kk = 0; kk < 4; ++kk)
      af[kk] = *(const bf16x8*)&as_[(m + off) * 136 + kk * 32 + q * 8];
    #pragma unroll
    for (int cot = 0; cot < 8; ++cot) {
      #pragma unroll
      for (int kk = 0; kk < 4; ++kk) {
        bf16x8 bf = *(const bf16x8*)&bs_[(cot * 16 + (ln & 15)) * 136 +
                                         kk * 32 + q * 8];
        acc8[cot] = __builtin_amdgcn_mfma_f32_16x16x32_bf16(af[kk], bf,
                                                            acc8[cot], 0, 0, 0);
      }
    }
  }
  #pragma unroll
  for (int cot = 0; cot < 8; ++cot) {
    int co = cot * 16 + (ln & 15);
    float bv = bias[co];
    #pragma unroll
    for (int r = 0; r < 4; ++r) {
      int mo = wv * 16 + q * 4 + r;
      int orow = rt * 2 + (mo >> 5), ocol = mo & 31;
      if (orow < 31 && ocol < 31) {
        float v = fmaxf(acc8[cot][r] + bv, 0.f);
        bf16_t h = (bf16_t)v;
        yt[((size_t)b * 1156 + (orow + 1) * 34 + (ocol + 1)) * 128 + co] =
            *(ushort*)&h;
      }
    }
  }
}

// ---------------- convT2 (MFMA): yt -> out fp32 ------------------------------
__global__ __launch_bounds__(256, 2) void convt2m_k(const bf16_t* __restrict__ yt,
    const bf16_t* __restrict__ wt2, const float* __restrict__ bias,
    float* __restrict__ out) {
  __shared__ __align__(16) bf16_t as_[128 * 136];         // 34.8 KB
  int b = blockIdx.x >> 4, rt = blockIdx.x & 15;          // grid = 64*16
  int tid = threadIdx.x, wv = tid >> 6, ln = tid & 63;
  const float4* src = (const float4*)(yt + ((size_t)b * 1156 + rt * 68) * 128);
  #pragma unroll
  for (int s = 0; s < 8; ++s) {
    int f = s * 256 + tid;
    int lp = f >> 4, c16 = f & 15;
    *(float4*)&as_[lp * 136 + c16 * 8] = src[f];
  }
  __syncthreads();
  int mloc = wv * 16 + (ln & 15), q = ln >> 4;
  int qh = mloc >> 5, qw = mloc & 31;                     // local quadrant pos
  int base = (qh + 1) * 34 + qw + 1;                      // in staged window
  f32x4 acc = {0.f, 0.f, 0.f, 0.f};
  #pragma unroll
  for (int kc = 0; kc < 16; ++kc) {
    int tap = kc >> 2;
    int toff = (tap & 1) + (tap >> 1) * 34;               // 0,1,34,35
    bf16x8 af = *(const bf16x8*)&as_[(base - toff) * 136 +
                                     (kc & 3) * 32 + q * 8];
    bf16x8 bf = *(const bf16x8*)&wt2[(size_t)(ln & 15) * 512 + kc * 32 + q * 8];
    acc = __builtin_amdgcn_mfma_f32_16x16x32_bf16(af, bf, acc, 0, 0, 0);
  }
  __syncthreads();                                        // as_ reads done
  float* bb = (float*)as_;                                // bounce: 64x16 f32
  #pragma unroll
  for (int r = 0; r < 4; ++r)
    bb[(wv * 16 + q * 4 + r) * 16 + (ln & 15)] = acc[r];
  __syncthreads();
  if (tid < 192) {
    int row_id = tid >> 4;                                // co*4 + ohoff
    int co = row_id >> 2, ohoff = row_id & 3;
    int qhl = ohoff >> 1, ph = ohoff & 1;
    float bv = bias[co];
    int ow0 = (tid & 15) * 4;
    float tmp[4];
    #pragma unroll
    for (int e = 0; e < 4; ++e) {
      int ow = ow0 + e;
      tmp[e] = bb[(qhl * 32 + (ow >> 1)) * 16 + co * 4 + ph * 2 + (ow & 1)]
               + bv;
    }
    *(float4*)&out[((size_t)(b * 3 + co)) * 4096 + (rt * 4 + ohoff) * 64 + ow0]
        = *(float4*)tmp;
  }
}

// ---------------- finalize: loss + perplexity -------------------------------
__global__ __launch_bounds__(256) void fin_k(const unsigned* __restrict__ hist,
    const float* __restrict__ sse, float* __restrict__ out) {
  __shared__ float red[256];
  float e = 0.f;
  for (int k = threadIdx.x; k < K_; k += 256) {
    float p = (float)hist[k] * (1.0f / (float)NROWS_);
    e += p * logf(p + 1e-10f);
  }
  red[threadIdx.x] = e;
  __syncthreads();
  #pragma unroll
  for (int t = 128; t > 0; t >>= 1) {
    if (threadIdx.x < t) red[threadIdx.x] += red[threadIdx.x + t];
    __syncthreads();
  }
  if (threadIdx.x == 0) {
    out[786432] = 1.25f * (*sse) * (1.0f / (float)NELEM_);
    out[786433] = expf(-red[0]);
  }
}

extern "C" void kernel_launch(void* const* d_in, const int* in_sizes, int n_in,
                              void* d_out, int out_size, void* d_ws,
                              size_t ws_size, hipStream_t stream) {
  (void)in_sizes; (void)n_in; (void)out_size; (void)ws_size;
  const float* x   = (const float*)d_in[0];
  const float* ew1 = (const float*)d_in[1];
  const float* eb1 = (const float*)d_in[2];
  const float* ew2 = (const float*)d_in[3];
  const float* eb2 = (const float*)d_in[4];
  const float* cb  = (const float*)d_in[5];
  const float* dw1 = (const float*)d_in[6];
  const float* db1 = (const float*)d_in[7];
  const float* dw2 = (const float*)d_in[8];
  const float* db2 = (const float*)d_in[9];
  float* out = (float*)d_out;
  char* ws = (char*)d_ws;

  // ws layout (~97.5 MB, aliased by liveness):
  //  [0, 35,684,352)            z1p fp32 (conv1->tz) then yt bf16 18.94 MB
  //                             (zeroed after tz; convt1m->convt2m)
  //  [35,684,352, 65,175,552)   z fp32 (conv2m->sse)
  //  [65,175,552, 81,985,536)   z1t bf16 +slack (tz->conv2m) then qt bf16
  //  [81,985,536, 96,731,136)   zbuf bf16 (conv2m->vq1)
  //  [96,731,136 ..)            cbb | wc2 | wd1 | idxArr | hist | cnorm | sse | wt2
  float*    z1p   = (float*)(ws);
  ushort*   yt    = (ushort*)(ws);
  float*    z     = (float*)(ws + 35684352);
  bf16_t*   z1t   = (bf16_t*)(ws + 65175552);
  bf16_t*   qt    = (bf16_t*)(ws + 65175552);
  ushort*   zbuf  = (ushort*)(ws + 81985536);
  bf16_t*   cbb   = (bf16_t*)(ws + 96731136);
  bf16_t*   wc2   = (bf16_t*)(ws + 96993280);
  bf16_t*   wd1   = (bf16_t*)(ws + 97124352);
  int*      idxArr= (int*)(ws + 97255424);
  unsigned* hist  = (unsigned*)(ws + 97485824);
  float*    cnorm = (float*)(ws + 97489920);
  float*    sse   = (float*)(ws + 97494016);
  bf16_t*   wt2   = (bf16_t*)(ws + 97497088);

  conv1_k<<<dim3(B_ * HID_), dim3(256), 0, stream>>>(x, ew1, eb1, z1p);
  tz_k<<<dim3(1024), dim3(256), 0, stream>>>(z1p, z1t);
  wprep_k<<<dim3(256), dim3(256), 0, stream>>>(ew2, dw1, dw2, wc2, wd1, wt2);
  conv2m_k<<<dim3(960), dim3(256), 0, stream>>>(z1t, wc2, eb2, z, zbuf);
  prep_k<<<dim3(4), dim3(256), 0, stream>>>(cb, cbb, cnorm, hist, sse);
  vq1_k<<<dim3(900), dim3(256), 0, stream>>>((const bf16_t*)zbuf, cbb, cnorm,
                                             idxArr, hist);
  zero_k<<<dim3(4624), dim3(256), 0, stream>>>((float4*)yt, 1183744);
  zero_k<<<dim3(4104), dim3(256), 0, stream>>>((float4*)qt, 1050624);
  tq_k<<<dim3(960), dim3(256), 0, stream>>>(cbb, idxArr, (ushort*)qt);
  sse_k<<<dim3(900), dim3(256), 0, stream>>>((const float4*)z, cb, idxArr,
                                             sse);
  convt1m_k<<<dim3(1024), dim3(256), 0, stream>>>(qt, wd1, db1, yt);
  convt2m_k<<<dim3(1024), dim3(256), 0, stream>>>((const bf16_t*)yt, wt2, db2,
                                                  out);
  fin_k<<<dim3(1), dim3(256), 0, stream>>>(hist, sse, out);
}